// Round 7
// baseline (222.150 us; speedup 1.0000x reference)
//
#include <hip/hip_runtime.h>
#include <hip/hip_bf16.h>
#include <cstdint>

#define FEAT    128
#define NRBF    20
#define NATOMS  8192
#define NEDGES  262144
#define NGRAPH  128
#define APG     64
#define PI_F    3.14159265358979323846f
#define CUTOFF_F 5.0f

typedef unsigned int uint_t;
typedef unsigned short ushort_t;
typedef __attribute__((ext_vector_type(4))) float f32x4;
typedef __attribute__((ext_vector_type(4))) short short4v;
typedef __attribute__((ext_vector_type(8))) short short8;

__device__ __forceinline__ float bflo(uint_t u) { return __uint_as_float(u << 16); }
__device__ __forceinline__ float bfhi(uint_t u) { return __uint_as_float(u & 0xffff0000u); }
__device__ __forceinline__ float bfus(ushort_t u) { return __uint_as_float((uint_t)u << 16); }
__device__ __forceinline__ ushort_t f2bf(float f) {
  uint_t u = __float_as_uint(f);
  return (ushort_t)((u + 0x7fffu + ((u >> 16) & 1u)) >> 16);
}
__device__ __forceinline__ float pick4(float a0, float a1, float a2, float a3, int g) {
  return (g == 0) ? a0 : (g == 1) ? a1 : (g == 2) ? a2 : a3;
}

// ---------------------------------------------------------------- prep
// V-pack: Vpack[j][l] = 6 bf16 {v(2l,c0),v(2l,c1) | v(2l,c2),v(2l+1,c0) | v(2l+1,c1),v(2l+1,c2)}
// + frag-order swizzled bf16 weights for the three dense GEMMs.
__device__ __forceinline__ ushort_t swz_elem(const float* __restrict__ W, int N,
                                             int NT, int i) {
  int jj = i & 7, lane = (i >> 3) & 63, tile = i >> 9;
  int ks = tile / NT, ctg = tile - ks * NT;
  int g = lane >> 4, q = lane & 15;
  int k = 32 * ks + 4 * g + (jj & 3) + 16 * (jj >> 2);
  int c = 16 * ctg + q;
  return f2bf(W[(size_t)k * N + c]);
}

__global__ void prep_kernel(const float* __restrict__ v_j, const float* __restrict__ W1,
                            const float* __restrict__ W2, const float* __restrict__ Wd,
                            uint4* __restrict__ Vpack, ushort_t* __restrict__ w1s,
                            ushort_t* __restrict__ w2s, ushort_t* __restrict__ wds) {
  int i = blockIdx.x * 256 + threadIdx.x;
  if (i < NATOMS * 64) {
    const float* vp = v_j + (size_t)i * 6;   // i = j*64+l -> v_j[j][2l][0]
    float2 a = *reinterpret_cast<const float2*>(vp);
    float2 b = *reinterpret_cast<const float2*>(vp + 2);
    float2 c = *reinterpret_cast<const float2*>(vp + 4);
    uint4 u;
    u.x = ((uint_t)f2bf(a.y) << 16) | (uint_t)f2bf(a.x);
    u.y = ((uint_t)f2bf(b.y) << 16) | (uint_t)f2bf(b.x);
    u.z = ((uint_t)f2bf(c.y) << 16) | (uint_t)f2bf(c.x);
    u.w = 0u;
    Vpack[i] = u;
    return;
  }
  i -= NATOMS * 64;
  if (i < 16384) { w1s[i] = swz_elem(W1, 128, 8, i); return; }
  i -= 16384;
  if (i < 49152) { w2s[i] = swz_elem(W2, 384, 24, i); return; }
  i -= 49152;
  if (i < 49152) { wds[i] = swz_elem(Wd, 384, 24, i); return; }
}

// Wr/br -> frag-order bf16: 24 col-tiles x 64 lanes x 8 (k=20 row is br; k>20 zero).
// Launched AFTER gemm2 (its output region aliases dead h_bf).
__global__ void prep2_kernel(const float* __restrict__ Wr, const float* __restrict__ br,
                             ushort_t* __restrict__ wrs) {
  int i = blockIdx.x * 256 + threadIdx.x;
  if (i < 12288) {
    int jj = i & 7, lane = (i >> 3) & 63, ct = i >> 9;
    int g = lane >> 4, q = lane & 15;
    int k = 4 * g + (jj & 3) + 16 * (jj >> 2);
    int f = 16 * ct + q;
    float v = (k < NRBF) ? Wr[k * 384 + f] : (k == NRBF ? br[f] : 0.f);
    wrs[i] = f2bf(v);
  }
}

// ---------------------------------------------------------------- MFMA GEMM
// C[8192 x N] = act(A[8192 x 128] @ W + b). Tile 64x64, 4 waves, 16 MFMA/wave.
// Fragment maps HW-verified (rounds 3-6). omode: 1 = bf16 row out (p0),
// 2 = phi Ppack (p0: [row][64] uint4, ushort slot s*2+(f&1)), 3 = qkv-split.
__global__ __launch_bounds__(256) void gemm_mfma(
    const void* __restrict__ Asrc, int a_f32, const ushort_t* __restrict__ Wswz,
    const float* __restrict__ bias, int N, int NT, int silu, int omode,
    void* __restrict__ p0, void* __restrict__ p1) {
  __shared__ ushort_t As[64][136];
  const int t = threadIdx.x;
  const int r0 = blockIdx.x * 64, c0 = blockIdx.y * 64;
  const int w = t >> 6, l = t & 63, g = l >> 4, q = l & 15;

  short8 bf[4][4];
  #pragma unroll
  for (int ks = 0; ks < 4; ++ks)
    #pragma unroll
    for (int ct = 0; ct < 4; ++ct)
      bf[ks][ct] = *reinterpret_cast<const short8*>(
          Wswz + ((size_t)(ks * NT + (c0 >> 4) + ct) * 64 + l) * 8);

  if (a_f32) {
    const float* Af = (const float*)Asrc;
    for (int i = t; i < 64 * 32; i += 256) {
      int r = i >> 5, k4 = i & 31;
      float4 v = *reinterpret_cast<const float4*>(Af + (size_t)(r0 + r) * 128 + 4 * k4);
      ushort4 o = {f2bf(v.x), f2bf(v.y), f2bf(v.z), f2bf(v.w)};
      *reinterpret_cast<ushort4*>(&As[r][4 * k4]) = o;
    }
  } else {
    const ushort_t* Ab = (const ushort_t*)Asrc;
    for (int i = t; i < 64 * 16; i += 256) {
      int r = i >> 4, g8 = i & 15;
      short8 v = *reinterpret_cast<const short8*>(Ab + (size_t)(r0 + r) * 128 + 8 * g8);
      *reinterpret_cast<short8*>(&As[r][8 * g8]) = v;
    }
  }
  __syncthreads();

  f32x4 acc[4] = {};
  #pragma unroll
  for (int ks = 0; ks < 4; ++ks) {
    const ushort_t* ap = &As[16 * w + q][32 * ks + 4 * g];
    short4v alo = *reinterpret_cast<const short4v*>(ap);
    short4v ahi = *reinterpret_cast<const short4v*>(ap + 16);
    short8 af;
    af[0] = alo[0]; af[1] = alo[1]; af[2] = alo[2]; af[3] = alo[3];
    af[4] = ahi[0]; af[5] = ahi[1]; af[6] = ahi[2]; af[7] = ahi[3];
    #pragma unroll
    for (int ct = 0; ct < 4; ++ct)
      acc[ct] = __builtin_amdgcn_mfma_f32_16x16x32_bf16(af, bf[ks][ct], acc[ct], 0, 0, 0);
  }

  #pragma unroll
  for (int ct = 0; ct < 4; ++ct) {
    int col = c0 + 16 * ct + q;
    float bb = bias[col];
    #pragma unroll
    for (int r = 0; r < 4; ++r) {
      float o = acc[ct][r] + bb;
      if (silu) o = o / (1.f + __expf(-o));
      int row = r0 + 16 * w + 4 * g + r;
      if (omode == 1) {
        ((ushort_t*)p0)[(size_t)row * N + col] = f2bf(o);
      } else if (omode == 2) {
        int f = col & 127, s = col >> 7;
        ((ushort_t*)p0)[((size_t)row * 64 + (f >> 1)) * 8 + s * 2 + (f & 1)] = f2bf(o);
      } else {
        if (col < 128) ((float*)p0)[(size_t)row * 128 + col] = o;
        else           ((ushort_t*)p1)[(size_t)row * 256 + col - 128] = f2bf(o);
      }
    }
  }
}

// ---------------------------------------------------------------- sort helpers
__global__ void zero_kernel(int* __restrict__ p, int n) {
  int i = blockIdx.x * blockDim.x + threadIdx.x;
  if (i < n) p[i] = 0;
}

__global__ void hist_kernel(const int* __restrict__ nbrs, int* __restrict__ counts) {
  int e = blockIdx.x * blockDim.x + threadIdx.x;
  if (e < NEDGES) atomicAdd(&counts[nbrs[2 * e]], 1);
}

__global__ __launch_bounds__(1024) void scan_kernel(
    const int* __restrict__ counts, int* __restrict__ offs, int* __restrict__ cursor) {
  __shared__ int part[1024];
  const int t = threadIdx.x;
  int local[8];
  int s = 0;
  #pragma unroll
  for (int i = 0; i < 8; ++i) { local[i] = counts[t * 8 + i]; s += local[i]; }
  part[t] = s;
  __syncthreads();
  for (int off = 1; off < 1024; off <<= 1) {
    int v = part[t];
    int add = (t >= off) ? part[t - off] : 0;
    __syncthreads();
    part[t] = v + add;
    __syncthreads();
  }
  int excl = part[t] - s;
  #pragma unroll
  for (int i = 0; i < 8; ++i) {
    offs[t * 8 + i] = excl;
    cursor[t * 8 + i] = excl;
    excl += local[i];
  }
  if (t == 1023) offs[NATOMS] = excl;
}

__global__ void scatter_kernel(const int* __restrict__ nbrs, int* __restrict__ cursor,
                               int* __restrict__ sorted) {
  int e = blockIdx.x * blockDim.x + threadIdx.x;
  if (e < NEDGES) {
    int seg = nbrs[2 * e];
    int pos = atomicAdd(&cursor[seg], 1);
    sorted[pos] = e;
  }
}

// ---------------------------------------------------------------- edge MFMA v3
// One wave per atom, grid 2048. Fixes vs r5 (281us) / r3 (422us):
//  - B-frags staged once per block into LDS from frag-order global (no per-block
//    swizzle compute, no 96-VGPR hoist); ds_read_b128 per use.
//  - epilogue gathers are 2 x b128 per (ct,r) via Ppack/Vpack with imm offsets.
//  - rbf/A-frag entirely in lane-q registers (zero LDS broadcast).
// Per 16-edge tile: A[16x32pad] = basis (k<20: env*sin((k+1)ang)/d, k=20: env),
// 24 MFMAs (8 col-tiles x 3 sections). C map HW-verified: row=4g+reg, col=q.
__global__ __launch_bounds__(256) void edge_mfma3(
    const int* __restrict__ sorted, const int* __restrict__ offs,
    const int* __restrict__ nbrs, const float* __restrict__ r_ij,
    const uint4* __restrict__ Pp, const uint4* __restrict__ Vp,
    const ushort_t* __restrict__ wrs,
    float* __restrict__ out_s, float* __restrict__ out_v) {
  __shared__ short8 sW[24 * 64];   // 24576 B
  const int t = threadIdx.x;
  for (int i = t; i < 24 * 64; i += 256)
    sW[i] = *reinterpret_cast<const short8*>(wrs + (size_t)i * 8);
  __syncthreads();

  const int w = t >> 6, l = t & 63, g = l >> 4, q = l & 15;
  const int atom = blockIdx.x * 4 + w;
  const int start = offs[atom], end = offs[atom + 1];
  const float c1 = PI_F / CUTOFF_F;
  const bool odd = (q & 1);

  float ds[8] = {};
  float dv[8][3] = {};

  for (int eb = start; eb < end; eb += 16) {
    // ---- metadata: lane q owns edge eb+q (replicated across g)
    float ang = 0.f, ie = 0.f, env = 0.f, u0 = 0.f, u1 = 0.f, u2 = 0.f;
    int jn = 0;
    if (eb + q < end) {
      int e = sorted[eb + q];
      float x = r_ij[3 * e], y = r_ij[3 * e + 1], z = r_ij[3 * e + 2];
      jn = nbrs[2 * e + 1];
      float d = sqrtf(x * x + y * y + z * z);
      float inv = 1.f / d;
      ang = c1 * d;
      env = (d < CUTOFF_F) ? 0.5f * (__cosf(ang) + 1.f) : 0.f;
      ie = inv * env;
      u0 = x * inv; u1 = y * inv; u2 = z * inv;
    }
    // ---- A fragment: k = kmap(g,jj) = 4g+(jj&3)+16*(jj>>2)
    short8 af;
    #pragma unroll
    for (int jj = 0; jj < 8; ++jj) {
      int k = 4 * g + (jj & 3) + 16 * (jj >> 2);
      float v = (k < NRBF) ? ie * __sinf((float)(k + 1) * ang)
                           : (k == NRBF ? env : 0.f);
      af[jj] = (short)f2bf(v);
    }
    // ---- row (edge eb+4g+r) metadata broadcast + base pointers
    const uint4 *pbase[4], *vbase[4];
    float ub[4][3];
    #pragma unroll
    for (int r = 0; r < 4; ++r) {
      int src = 4 * g + r;
      int jr = __shfl(jn, src, 64);
      ub[r][0] = __shfl(u0, src, 64);
      ub[r][1] = __shfl(u1, src, 64);
      ub[r][2] = __shfl(u2, src, 64);
      pbase[r] = Pp + (size_t)jr * 64;
      vbase[r] = Vp + (size_t)jr * 64;
    }
    // ---- 8 col-tiles x 3 sections
    #pragma unroll
    for (int ct = 0; ct < 8; ++ct) {
      short8 b0 = sW[(0 * 8 + ct) * 64 + l];
      short8 b1 = sW[(1 * 8 + ct) * 64 + l];
      short8 b2 = sW[(2 * 8 + ct) * 64 + l];
      f32x4 z4 = {0.f, 0.f, 0.f, 0.f};
      f32x4 cs0 = __builtin_amdgcn_mfma_f32_16x16x32_bf16(af, b0, z4, 0, 0, 0);
      f32x4 cs1 = __builtin_amdgcn_mfma_f32_16x16x32_bf16(af, b1, z4, 0, 0, 0);
      f32x4 cs2 = __builtin_amdgcn_mfma_f32_16x16x32_bf16(af, b2, z4, 0, 0, 0);
      const int fp = 8 * ct + (q >> 1);   // (16ct+q)>>1
      #pragma unroll
      for (int r = 0; r < 4; ++r) {
        uint4 pu = pbase[r][fp];
        uint4 vu = vbase[r][fp];
        float p0 = odd ? bfhi(pu.x) : bflo(pu.x);
        float p1 = odd ? bfhi(pu.y) : bflo(pu.y);
        float p2 = odd ? bfhi(pu.z) : bflo(pu.z);
        float v0 = odd ? bfhi(vu.y) : bflo(vu.x);
        float v1 = odd ? bflo(vu.z) : bfhi(vu.x);
        float v2 = odd ? bfhi(vu.z) : bflo(vu.y);
        float pw0 = p0 * cs0[r];
        ds[ct] += p1 * cs1[r];
        float pw2 = p2 * cs2[r];
        dv[ct][0] += pw0 * v0 + pw2 * ub[r][0];
        dv[ct][1] += pw0 * v1 + pw2 * ub[r][1];
        dv[ct][2] += pw0 * v2 + pw2 * ub[r][2];
      }
    }
  }

  // ---- reduce the 4 g-copies (each accumulated different edge rows)
  #pragma unroll
  for (int ct = 0; ct < 8; ++ct) {
    float x = ds[ct];
    x += __shfl_xor(x, 16, 64); x += __shfl_xor(x, 32, 64);
    ds[ct] = x;
    #pragma unroll
    for (int c = 0; c < 3; ++c) {
      float y = dv[ct][c];
      y += __shfl_xor(y, 16, 64); y += __shfl_xor(y, 32, 64);
      dv[ct][c] = y;
    }
  }
  // ---- write: lane (g,q) owns ct = 2g, 2g+1 (compile-time picks)
  #pragma unroll
  for (int i2 = 0; i2 < 2; ++i2) {
    float sv = i2 ? pick4(ds[1], ds[3], ds[5], ds[7], g)
                  : pick4(ds[0], ds[2], ds[4], ds[6], g);
    float d0 = i2 ? pick4(dv[1][0], dv[3][0], dv[5][0], dv[7][0], g)
                  : pick4(dv[0][0], dv[2][0], dv[4][0], dv[6][0], g);
    float d1 = i2 ? pick4(dv[1][1], dv[3][1], dv[5][1], dv[7][1], g)
                  : pick4(dv[0][1], dv[2][1], dv[4][1], dv[6][1], g);
    float d2 = i2 ? pick4(dv[1][2], dv[3][2], dv[5][2], dv[7][2], g)
                  : pick4(dv[0][2], dv[2][2], dv[4][2], dv[6][2], g);
    int f = 16 * (2 * g + i2) + q;
    out_s[(size_t)atom * FEAT + f] = sv;
    float* ov = out_v + (size_t)atom * 384 + (size_t)f * 3;
    ov[0] = d0; ov[1] = d1; ov[2] = d2;
  }
}

// ---------------------------------------------------------------- attention
__device__ __forceinline__ float wave_max64(float v) {
  #pragma unroll
  for (int m = 32; m > 0; m >>= 1) v = fmaxf(v, __shfl_xor(v, m, 64));
  return v;
}
__device__ __forceinline__ float wave_sum64(float v) {
  #pragma unroll
  for (int m = 32; m > 0; m >>= 1) v += __shfl_xor(v, m, 64);
  return v;
}

__global__ __launch_bounds__(256) void attn_kernel(const float* __restrict__ Qf,
                                                   const ushort_t* __restrict__ kvbf,
                                                   float* __restrict__ out_s) {
  __shared__ float4 Ks4[64 * 32];
  __shared__ float  Vs[64][130];
  __shared__ float  Ps[4][4][64];
  const int b = blockIdx.x >> 1, half = blockIdx.x & 1;
  const int t = threadIdx.x;
  const float* qbase = Qf + (size_t)b * APG * 128;
  const ushort_t* kvb = kvbf + (size_t)b * APG * 256;

  for (int i = t; i < 64 * 32; i += 256) {
    int a = i >> 5, gg = i & 31;
    ushort4 k4 = *reinterpret_cast<const ushort4*>(kvb + a * 256 + 4 * gg);
    float4 kf = {bfus(k4.x), bfus(k4.y), bfus(k4.z), bfus(k4.w)};
    Ks4[a * 32 + (gg ^ (a & 7))] = kf;
  }
  for (int i = t; i < 64 * 32; i += 256) {
    int a = i >> 5, gg = i & 31;
    ushort4 v4 = *reinterpret_cast<const ushort4*>(kvb + a * 256 + 128 + 4 * gg);
    Vs[a][4 * gg + 0] = bfus(v4.x); Vs[a][4 * gg + 1] = bfus(v4.y);
    Vs[a][4 * gg + 2] = bfus(v4.z); Vs[a][4 * gg + 3] = bfus(v4.w);
  }
  __syncthreads();

  const int w = t >> 6, l = t & 63;
  const float scale = 0.08838834764831845f;

  for (int qq = 8 * half + w; qq < 8 * half + 8; qq += 4) {
    const float* q0p = qbase + (size_t)(4 * qq + 0) * 128;
    const float* q1p = qbase + (size_t)(4 * qq + 1) * 128;
    const float* q2p = qbase + (size_t)(4 * qq + 2) * 128;
    const float* q3p = qbase + (size_t)(4 * qq + 3) * 128;
    float s0 = 0.f, s1 = 0.f, s2 = 0.f, s3 = 0.f;
    #pragma unroll 8
    for (int i = 0; i < 32; ++i) {
      float4 k = Ks4[l * 32 + (i ^ (l & 7))];
      float4 q0 = *reinterpret_cast<const float4*>(q0p + 4 * i);
      float4 q1 = *reinterpret_cast<const float4*>(q1p + 4 * i);
      float4 q2 = *reinterpret_cast<const float4*>(q2p + 4 * i);
      float4 q3 = *reinterpret_cast<const float4*>(q3p + 4 * i);
      s0 += q0.x * k.x + q0.y * k.y + q0.z * k.z + q0.w * k.w;
      s1 += q1.x * k.x + q1.y * k.y + q1.z * k.z + q1.w * k.w;
      s2 += q2.x * k.x + q2.y * k.y + q2.z * k.z + q2.w * k.w;
      s3 += q3.x * k.x + q3.y * k.y + q3.z * k.z + q3.w * k.w;
    }
    s0 *= scale; s1 *= scale; s2 *= scale; s3 *= scale;

    float p0 = __expf(s0 - wave_max64(s0));
    float p1 = __expf(s1 - wave_max64(s1));
    float p2 = __expf(s2 - wave_max64(s2));
    float p3 = __expf(s3 - wave_max64(s3));
    p0 /= wave_sum64(p0); p1 /= wave_sum64(p1);
    p2 /= wave_sum64(p2); p3 /= wave_sum64(p3);

    Ps[w][0][l] = p0; Ps[w][1][l] = p1; Ps[w][2][l] = p2; Ps[w][3][l] = p3;
    __threadfence_block();

    float a00 = 0.f, a01 = 0.f, a10 = 0.f, a11 = 0.f;
    float a20 = 0.f, a21 = 0.f, a30 = 0.f, a31 = 0.f;
    for (int a = 0; a < 64; ++a) {
      float2 v = *reinterpret_cast<const float2*>(&Vs[a][2 * l]);
      float pa0 = Ps[w][0][a], pa1 = Ps[w][1][a];
      float pa2 = Ps[w][2][a], pa3 = Ps[w][3][a];
      a00 += pa0 * v.x; a01 += pa0 * v.y;
      a10 += pa1 * v.x; a11 += pa1 * v.y;
      a20 += pa2 * v.x; a21 += pa2 * v.y;
      a30 += pa3 * v.x; a31 += pa3 * v.y;
    }
    size_t row0 = (size_t)(b * APG + 4 * qq) * FEAT + 2 * l;
    float2* o0 = reinterpret_cast<float2*>(out_s + row0);
    float2* o1 = reinterpret_cast<float2*>(out_s + row0 + FEAT);
    float2* o2 = reinterpret_cast<float2*>(out_s + row0 + 2 * FEAT);
    float2* o3 = reinterpret_cast<float2*>(out_s + row0 + 3 * FEAT);
    float2 c0 = *o0; c0.x += a00; c0.y += a01; *o0 = c0;
    float2 c1 = *o1; c1.x += a10; c1.y += a11; *o1 = c1;
    float2 c2 = *o2; c2.x += a20; c2.y += a21; *o2 = c2;
    float2 c3 = *o3; c3.x += a30; c3.y += a31; *o3 = c3;
    __threadfence_block();
  }
}

// ---------------------------------------------------------------- launch
extern "C" void kernel_launch(void* const* d_in, const int* in_sizes, int n_in,
                              void* d_out, int out_size, void* d_ws, size_t ws_size,
                              hipStream_t stream) {
  const float* s_j  = (const float*)d_in[0];
  const float* v_j  = (const float*)d_in[1];
  const float* r_ij = (const float*)d_in[2];
  const int*   nbrs = (const int*)d_in[3];
  const float* W1   = (const float*)d_in[5];
  const float* b1   = (const float*)d_in[6];
  const float* W2   = (const float*)d_in[7];
  const float* b2   = (const float*)d_in[8];
  const float* Wr   = (const float*)d_in[9];
  const float* br   = (const float*)d_in[10];
  const float* Wd   = (const float*)d_in[11];
  const float* bd   = (const float*)d_in[12];

  float* out_s = (float*)d_out;
  float* out_v = out_s + (size_t)NATOMS * FEAT;

  // workspace: 26.4 MB (proven). wrs aliases dead h_bf tail (after sort buffers).
  float*    Qf    = (float*)d_ws;                        // 8192*128 f32   (4 MB)
  ushort_t* kvbf  = (ushort_t*)(Qf + NATOMS * FEAT);     // 8192*256 bf16  (4 MB)
  uint4*    Ppack = (uint4*)(kvbf + NATOMS * 256);       // 8192*64 uint4  (8 MB)
  uint4*    Vpack = Ppack + (size_t)NATOMS * 64;         // 8192*64 uint4  (8 MB)
  ushort_t* w1s   = (ushort_t*)(Vpack + (size_t)NATOMS * 64);  // 16384
  ushort_t* w2s   = w1s + 16384;                         // 49152
  ushort_t* wds   = w2s + 49152;                         // 49152
  ushort_t* h_bf  = wds + 49152;                         // 2 MB region (dead after gemm2)
  int* sorted = (int*)h_bf;                              // [0, 1.05 MB)
  int* offs   = sorted + NEDGES;
  int* cursor = offs + (NATOMS + 1);
  int* counts = cursor + NATOMS;                         // ends at 1,146,884 B
  ushort_t* wrs = (ushort_t*)((char*)h_bf + 1310720);    // 24576 B, 16-aligned, disjoint

  int prep_total = NATOMS * 64 + 16384 + 49152 + 49152;
  prep_kernel<<<(prep_total + 255) / 256, 256, 0, stream>>>(
      v_j, W1, W2, Wd, Vpack, w1s, w2s, wds);

  gemm_mfma<<<dim3(NATOMS / 64, 2), 256, 0, stream>>>(
      s_j, 1, w1s, b1, 128, 8, 1, 1, h_bf, nullptr);
  gemm_mfma<<<dim3(NATOMS / 64, 6), 256, 0, stream>>>(
      h_bf, 0, w2s, b2, 384, 24, 0, 2, Ppack, nullptr);

  prep2_kernel<<<48, 256, 0, stream>>>(Wr, br, wrs);     // after gemm2 (h_bf dead)
  zero_kernel<<<(NATOMS + 255) / 256, 256, 0, stream>>>(counts, NATOMS);
  hist_kernel<<<NEDGES / 256, 256, 0, stream>>>(nbrs, counts);
  scan_kernel<<<1, 1024, 0, stream>>>(counts, offs, cursor);
  scatter_kernel<<<NEDGES / 256, 256, 0, stream>>>(nbrs, cursor, sorted);

  gemm_mfma<<<dim3(NATOMS / 64, 6), 256, 0, stream>>>(
      s_j, 1, wds, bd, 384, 24, 0, 3, Qf, kvbf);

  edge_mfma3<<<NATOMS / 4, 256, 0, stream>>>(sorted, offs, nbrs, r_ij, Ppack,
                                             Vpack, wrs, out_s, out_v);
  attn_kernel<<<NGRAPH * 2, 256, 0, stream>>>(Qf, kvbf, out_s);
}

// Round 8
// 174.609 us; speedup vs baseline: 1.2723x; 1.2723x over previous
//
#include <hip/hip_runtime.h>
#include <hip/hip_bf16.h>
#include <cstdint>

#define FEAT    128
#define NRBF    20
#define NATOMS  8192
#define NEDGES  262144
#define NGRAPH  128
#define APG     64
#define PI_F    3.14159265358979323846f
#define CUTOFF_F 5.0f

typedef unsigned int uint_t;
typedef unsigned short ushort_t;
typedef __attribute__((ext_vector_type(4))) float f32x4;
typedef __attribute__((ext_vector_type(4))) short short4v;
typedef __attribute__((ext_vector_type(8))) short short8;
typedef __attribute__((ext_vector_type(3))) uint_t uint3v;

__device__ __forceinline__ float bflo(uint_t u) { return __uint_as_float(u << 16); }
__device__ __forceinline__ float bfhi(uint_t u) { return __uint_as_float(u & 0xffff0000u); }
__device__ __forceinline__ float bfus(ushort_t u) { return __uint_as_float((uint_t)u << 16); }
__device__ __forceinline__ ushort_t f2bf(float f) {
  uint_t u = __float_as_uint(f);
  return (ushort_t)((u + 0x7fffu + ((u >> 16) & 1u)) >> 16);
}
__device__ __forceinline__ float pick4(float a0, float a1, float a2, float a3, int g) {
  return (g == 0) ? a0 : (g == 1) ? a1 : (g == 2) ? a2 : a3;
}

// ---------------------------------------------------------------- prep
// PV record per (j,f): 8 ushorts {p0,p1,p2,v0,v1,v2,pad,pad} (16 B stride).
// prep writes V slots (3,4,5); gemm2's epilogue writes P slots (0,1,2).
// Plus frag-order swizzled bf16 weights for the three dense GEMMs.
__device__ __forceinline__ ushort_t swz_elem(const float* __restrict__ W, int N,
                                             int NT, int i) {
  int jj = i & 7, lane = (i >> 3) & 63, tile = i >> 9;
  int ks = tile / NT, ctg = tile - ks * NT;
  int g = lane >> 4, q = lane & 15;
  int k = 32 * ks + 4 * g + (jj & 3) + 16 * (jj >> 2);
  int c = 16 * ctg + q;
  return f2bf(W[(size_t)k * N + c]);
}

__global__ void prep_kernel(const float* __restrict__ v_j, const float* __restrict__ W1,
                            const float* __restrict__ W2, const float* __restrict__ Wd,
                            ushort_t* __restrict__ PV, ushort_t* __restrict__ w1s,
                            ushort_t* __restrict__ w2s, ushort_t* __restrict__ wds) {
  int i = blockIdx.x * 256 + threadIdx.x;
  if (i < NATOMS * FEAT) {                 // i = j*128+f
    const float* vp = v_j + (size_t)i * 3; // v_j[j][f][0..2]
    ushort_t* o = PV + (size_t)i * 8;
    o[3] = f2bf(vp[0]);
    o[4] = f2bf(vp[1]);
    o[5] = f2bf(vp[2]);
    return;
  }
  i -= NATOMS * FEAT;
  if (i < 16384) { w1s[i] = swz_elem(W1, 128, 8, i); return; }
  i -= 16384;
  if (i < 49152) { w2s[i] = swz_elem(W2, 384, 24, i); return; }
  i -= 49152;
  if (i < 49152) { wds[i] = swz_elem(Wd, 384, 24, i); return; }
}

// Wr/br -> frag-order bf16: 24 col-tiles x 64 lanes x 8 (k=20 row is br; k>20 zero).
__global__ void prep2_kernel(const float* __restrict__ Wr, const float* __restrict__ br,
                             ushort_t* __restrict__ wrs) {
  int i = blockIdx.x * 256 + threadIdx.x;
  if (i < 12288) {
    int jj = i & 7, lane = (i >> 3) & 63, ct = i >> 9;
    int g = lane >> 4, q = lane & 15;
    int k = 4 * g + (jj & 3) + 16 * (jj >> 2);
    int f = 16 * ct + q;
    float v = (k < NRBF) ? Wr[k * 384 + f] : (k == NRBF ? br[f] : 0.f);
    wrs[i] = f2bf(v);
  }
}

// ---------------------------------------------------------------- MFMA GEMM
// C[8192 x N] = act(A[8192 x 128] @ W + b). Tile 64x64, 4 waves, 16 MFMA/wave.
// omode: 1 = bf16 row out (p0), 2 = PV P-slots (p0, ushort slot s at (row*128+f)*8),
// 3 = qkv-split (p0 Qf f32, p1 kv bf16).
__global__ __launch_bounds__(256) void gemm_mfma(
    const void* __restrict__ Asrc, int a_f32, const ushort_t* __restrict__ Wswz,
    const float* __restrict__ bias, int N, int NT, int silu, int omode,
    void* __restrict__ p0, void* __restrict__ p1) {
  __shared__ ushort_t As[64][136];
  const int t = threadIdx.x;
  const int r0 = blockIdx.x * 64, c0 = blockIdx.y * 64;
  const int w = t >> 6, l = t & 63, g = l >> 4, q = l & 15;

  short8 bf[4][4];
  #pragma unroll
  for (int ks = 0; ks < 4; ++ks)
    #pragma unroll
    for (int ct = 0; ct < 4; ++ct)
      bf[ks][ct] = *reinterpret_cast<const short8*>(
          Wswz + ((size_t)(ks * NT + (c0 >> 4) + ct) * 64 + l) * 8);

  if (a_f32) {
    const float* Af = (const float*)Asrc;
    for (int i = t; i < 64 * 32; i += 256) {
      int r = i >> 5, k4 = i & 31;
      float4 v = *reinterpret_cast<const float4*>(Af + (size_t)(r0 + r) * 128 + 4 * k4);
      ushort4 o = {f2bf(v.x), f2bf(v.y), f2bf(v.z), f2bf(v.w)};
      *reinterpret_cast<ushort4*>(&As[r][4 * k4]) = o;
    }
  } else {
    const ushort_t* Ab = (const ushort_t*)Asrc;
    for (int i = t; i < 64 * 16; i += 256) {
      int r = i >> 4, g8 = i & 15;
      short8 v = *reinterpret_cast<const short8*>(Ab + (size_t)(r0 + r) * 128 + 8 * g8);
      *reinterpret_cast<short8*>(&As[r][8 * g8]) = v;
    }
  }
  __syncthreads();

  f32x4 acc[4] = {};
  #pragma unroll
  for (int ks = 0; ks < 4; ++ks) {
    const ushort_t* ap = &As[16 * w + q][32 * ks + 4 * g];
    short4v alo = *reinterpret_cast<const short4v*>(ap);
    short4v ahi = *reinterpret_cast<const short4v*>(ap + 16);
    short8 af;
    af[0] = alo[0]; af[1] = alo[1]; af[2] = alo[2]; af[3] = alo[3];
    af[4] = ahi[0]; af[5] = ahi[1]; af[6] = ahi[2]; af[7] = ahi[3];
    #pragma unroll
    for (int ct = 0; ct < 4; ++ct)
      acc[ct] = __builtin_amdgcn_mfma_f32_16x16x32_bf16(af, bf[ks][ct], acc[ct], 0, 0, 0);
  }

  #pragma unroll
  for (int ct = 0; ct < 4; ++ct) {
    int col = c0 + 16 * ct + q;
    float bb = bias[col];
    #pragma unroll
    for (int r = 0; r < 4; ++r) {
      float o = acc[ct][r] + bb;
      if (silu) o = o / (1.f + __expf(-o));
      int row = r0 + 16 * w + 4 * g + r;
      if (omode == 1) {
        ((ushort_t*)p0)[(size_t)row * N + col] = f2bf(o);
      } else if (omode == 2) {
        int f = col & 127, s = col >> 7;
        ((ushort_t*)p0)[((size_t)row * 128 + f) * 8 + s] = f2bf(o);
      } else {
        if (col < 128) ((float*)p0)[(size_t)row * 128 + col] = o;
        else           ((ushort_t*)p1)[(size_t)row * 256 + col - 128] = f2bf(o);
      }
    }
  }
}

// ---------------------------------------------------------------- sort helpers
__global__ void zero_kernel(int* __restrict__ p, int n) {
  int i = blockIdx.x * blockDim.x + threadIdx.x;
  if (i < n) p[i] = 0;
}

__global__ void hist_kernel(const int* __restrict__ nbrs, int* __restrict__ counts) {
  int e = blockIdx.x * blockDim.x + threadIdx.x;
  if (e < NEDGES) atomicAdd(&counts[nbrs[2 * e]], 1);
}

__global__ __launch_bounds__(1024) void scan_kernel(
    const int* __restrict__ counts, int* __restrict__ offs, int* __restrict__ cursor) {
  __shared__ int part[1024];
  const int t = threadIdx.x;
  int local[8];
  int s = 0;
  #pragma unroll
  for (int i = 0; i < 8; ++i) { local[i] = counts[t * 8 + i]; s += local[i]; }
  part[t] = s;
  __syncthreads();
  for (int off = 1; off < 1024; off <<= 1) {
    int v = part[t];
    int add = (t >= off) ? part[t - off] : 0;
    __syncthreads();
    part[t] = v + add;
    __syncthreads();
  }
  int excl = part[t] - s;
  #pragma unroll
  for (int i = 0; i < 8; ++i) {
    offs[t * 8 + i] = excl;
    cursor[t * 8 + i] = excl;
    excl += local[i];
  }
  if (t == 1023) offs[NATOMS] = excl;
}

__global__ void scatter_kernel(const int* __restrict__ nbrs, int* __restrict__ cursor,
                               int* __restrict__ sorted) {
  int e = blockIdx.x * blockDim.x + threadIdx.x;
  if (e < NEDGES) {
    int seg = nbrs[2 * e];
    int pos = atomicAdd(&cursor[seg], 1);
    sorted[pos] = e;
  }
}

// ---------------------------------------------------------------- edge MFMA v4
// TWO waves per atom (ct-halves); grid NATOMS/2, 4 waves/block. vs r7 (141us):
//  - combined PV record: ONE dwordx3 (12 B) gather per (ct,r), no parity selects
//  - per-wave work halved: 12 MFMA + 16 gathers + 4-ct epilogue -> VGPR ~<=130
//  - all 16 gathers issued before the 8-sinf A-frag computation (latency cover)
// A[16x32pad] basis (k<20: env*sin((k+1)ang)/d, k=20: env, br folded);
// C map HW-verified: row = 4g+reg = edge, col = q.
__global__ __launch_bounds__(256) void edge_mfma4(
    const int* __restrict__ sorted, const int* __restrict__ offs,
    const int* __restrict__ nbrs, const float* __restrict__ r_ij,
    const ushort_t* __restrict__ PV, const ushort_t* __restrict__ wrs,
    float* __restrict__ out_s, float* __restrict__ out_v) {
  __shared__ short8 sW[24 * 64];   // 24576 B
  const int t = threadIdx.x;
  for (int i = t; i < 24 * 64; i += 256)
    sW[i] = *reinterpret_cast<const short8*>(wrs + (size_t)i * 8);
  __syncthreads();

  const int w = t >> 6, l = t & 63, g = l >> 4, q = l & 15;
  const int atom = blockIdx.x * 2 + (w >> 1);
  const int h = w & 1;                    // ct-half: cts 4h..4h+3
  const int start = offs[atom], end = offs[atom + 1];
  const float c1 = PI_F / CUTOFF_F;

  float ds[4] = {};
  float dv[4][3] = {};

  for (int eb = start; eb < end; eb += 16) {
    // ---- metadata: lane q owns edge eb+q (replicated across g)
    float ang = 0.f, ie = 0.f, env = 0.f, u0 = 0.f, u1 = 0.f, u2 = 0.f;
    int jn = 0;
    if (eb + q < end) {
      int e = sorted[eb + q];
      float x = r_ij[3 * e], y = r_ij[3 * e + 1], z = r_ij[3 * e + 2];
      jn = nbrs[2 * e + 1];
      float d = sqrtf(x * x + y * y + z * z);
      float inv = 1.f / d;
      ang = c1 * d;
      env = (d < CUTOFF_F) ? 0.5f * (__cosf(ang) + 1.f) : 0.f;
      ie = inv * env;
      u0 = x * inv; u1 = y * inv; u2 = z * inv;
    }
    // ---- row (edge eb+4g+r) metadata broadcast + base pointers
    const ushort_t* pb[4];
    float ub[4][3];
    #pragma unroll
    for (int r = 0; r < 4; ++r) {
      int src = 4 * g + r;
      int jr = __shfl(jn, src, 64);
      ub[r][0] = __shfl(u0, src, 64);
      ub[r][1] = __shfl(u1, src, 64);
      ub[r][2] = __shfl(u2, src, 64);
      pb[r] = PV + ((size_t)jr * 128 + q) * 8;
    }
    // ---- issue ALL 16 gathers (12 B each) up front
    uint3v ld[4][4];
    #pragma unroll
    for (int c = 0; c < 4; ++c)
      #pragma unroll
      for (int r = 0; r < 4; ++r)
        ld[c][r] = *reinterpret_cast<const uint3v*>(pb[r] + (size_t)(16 * (4 * h + c)) * 8);
    // ---- A fragment: k = kmap(g,jj) = 4g+(jj&3)+16*(jj>>2)
    short8 af;
    #pragma unroll
    for (int jj = 0; jj < 8; ++jj) {
      int k = 4 * g + (jj & 3) + 16 * (jj >> 2);
      float v = (k < NRBF) ? ie * __sinf((float)(k + 1) * ang)
                           : (k == NRBF ? env : 0.f);
      af[jj] = (short)f2bf(v);
    }
    // ---- 4 col-tiles x 3 sections
    #pragma unroll
    for (int c = 0; c < 4; ++c) {
      int ctg = 4 * h + c;
      short8 b0 = sW[(0 * 8 + ctg) * 64 + l];
      short8 b1 = sW[(1 * 8 + ctg) * 64 + l];
      short8 b2 = sW[(2 * 8 + ctg) * 64 + l];
      f32x4 z4 = {0.f, 0.f, 0.f, 0.f};
      f32x4 cs0 = __builtin_amdgcn_mfma_f32_16x16x32_bf16(af, b0, z4, 0, 0, 0);
      f32x4 cs1 = __builtin_amdgcn_mfma_f32_16x16x32_bf16(af, b1, z4, 0, 0, 0);
      f32x4 cs2 = __builtin_amdgcn_mfma_f32_16x16x32_bf16(af, b2, z4, 0, 0, 0);
      #pragma unroll
      for (int r = 0; r < 4; ++r) {
        uint3v u = ld[c][r];
        float p0 = bflo(u.x), p1 = bfhi(u.x);
        float p2 = bflo(u.y), v0 = bfhi(u.y);
        float v1 = bflo(u.z), v2 = bfhi(u.z);
        float pw0 = p0 * cs0[r];
        ds[c] += p1 * cs1[r];
        float pw2 = p2 * cs2[r];
        dv[c][0] += pw0 * v0 + pw2 * ub[r][0];
        dv[c][1] += pw0 * v1 + pw2 * ub[r][1];
        dv[c][2] += pw0 * v2 + pw2 * ub[r][2];
      }
    }
  }

  // ---- reduce the 4 g-copies (each accumulated different edge rows)
  #pragma unroll
  for (int c = 0; c < 4; ++c) {
    float x = ds[c];
    x += __shfl_xor(x, 16, 64); x += __shfl_xor(x, 32, 64);
    ds[c] = x;
    #pragma unroll
    for (int cc = 0; cc < 3; ++cc) {
      float y = dv[c][cc];
      y += __shfl_xor(y, 16, 64); y += __shfl_xor(y, 32, 64);
      dv[c][cc] = y;
    }
  }
  // ---- write: lane (g,q) owns ctg = 4h+g, feature f = 16*ctg+q
  float sv = pick4(ds[0], ds[1], ds[2], ds[3], g);
  float d0 = pick4(dv[0][0], dv[1][0], dv[2][0], dv[3][0], g);
  float d1 = pick4(dv[0][1], dv[1][1], dv[2][1], dv[3][1], g);
  float d2 = pick4(dv[0][2], dv[1][2], dv[2][2], dv[3][2], g);
  int f = 16 * (4 * h + g) + q;
  out_s[(size_t)atom * FEAT + f] = sv;
  float* ov = out_v + (size_t)atom * 384 + (size_t)f * 3;
  ov[0] = d0; ov[1] = d1; ov[2] = d2;
}

// ---------------------------------------------------------------- attention
__device__ __forceinline__ float wave_max64(float v) {
  #pragma unroll
  for (int m = 32; m > 0; m >>= 1) v = fmaxf(v, __shfl_xor(v, m, 64));
  return v;
}
__device__ __forceinline__ float wave_sum64(float v) {
  #pragma unroll
  for (int m = 32; m > 0; m >>= 1) v += __shfl_xor(v, m, 64);
  return v;
}

__global__ __launch_bounds__(256) void attn_kernel(const float* __restrict__ Qf,
                                                   const ushort_t* __restrict__ kvbf,
                                                   float* __restrict__ out_s) {
  __shared__ float4 Ks4[64 * 32];
  __shared__ float  Vs[64][130];
  __shared__ float  Ps[4][4][64];
  const int b = blockIdx.x >> 1, half = blockIdx.x & 1;
  const int t = threadIdx.x;
  const float* qbase = Qf + (size_t)b * APG * 128;
  const ushort_t* kvb = kvbf + (size_t)b * APG * 256;

  for (int i = t; i < 64 * 32; i += 256) {
    int a = i >> 5, gg = i & 31;
    ushort4 k4 = *reinterpret_cast<const ushort4*>(kvb + a * 256 + 4 * gg);
    float4 kf = {bfus(k4.x), bfus(k4.y), bfus(k4.z), bfus(k4.w)};
    Ks4[a * 32 + (gg ^ (a & 7))] = kf;
  }
  for (int i = t; i < 64 * 32; i += 256) {
    int a = i >> 5, gg = i & 31;
    ushort4 v4 = *reinterpret_cast<const ushort4*>(kvb + a * 256 + 128 + 4 * gg);
    Vs[a][4 * gg + 0] = bfus(v4.x); Vs[a][4 * gg + 1] = bfus(v4.y);
    Vs[a][4 * gg + 2] = bfus(v4.z); Vs[a][4 * gg + 3] = bfus(v4.w);
  }
  __syncthreads();

  const int w = t >> 6, l = t & 63;
  const float scale = 0.08838834764831845f;

  for (int qq = 8 * half + w; qq < 8 * half + 8; qq += 4) {
    const float* q0p = qbase + (size_t)(4 * qq + 0) * 128;
    const float* q1p = qbase + (size_t)(4 * qq + 1) * 128;
    const float* q2p = qbase + (size_t)(4 * qq + 2) * 128;
    const float* q3p = qbase + (size_t)(4 * qq + 3) * 128;
    float s0 = 0.f, s1 = 0.f, s2 = 0.f, s3 = 0.f;
    #pragma unroll 8
    for (int i = 0; i < 32; ++i) {
      float4 k = Ks4[l * 32 + (i ^ (l & 7))];
      float4 q0 = *reinterpret_cast<const float4*>(q0p + 4 * i);
      float4 q1 = *reinterpret_cast<const float4*>(q1p + 4 * i);
      float4 q2 = *reinterpret_cast<const float4*>(q2p + 4 * i);
      float4 q3 = *reinterpret_cast<const float4*>(q3p + 4 * i);
      s0 += q0.x * k.x + q0.y * k.y + q0.z * k.z + q0.w * k.w;
      s1 += q1.x * k.x + q1.y * k.y + q1.z * k.z + q1.w * k.w;
      s2 += q2.x * k.x + q2.y * k.y + q2.z * k.z + q2.w * k.w;
      s3 += q3.x * k.x + q3.y * k.y + q3.z * k.z + q3.w * k.w;
    }
    s0 *= scale; s1 *= scale; s2 *= scale; s3 *= scale;

    float p0 = __expf(s0 - wave_max64(s0));
    float p1 = __expf(s1 - wave_max64(s1));
    float p2 = __expf(s2 - wave_max64(s2));
    float p3 = __expf(s3 - wave_max64(s3));
    p0 /= wave_sum64(p0); p1 /= wave_sum64(p1);
    p2 /= wave_sum64(p2); p3 /= wave_sum64(p3);

    Ps[w][0][l] = p0; Ps[w][1][l] = p1; Ps[w][2][l] = p2; Ps[w][3][l] = p3;
    __threadfence_block();

    float a00 = 0.f, a01 = 0.f, a10 = 0.f, a11 = 0.f;
    float a20 = 0.f, a21 = 0.f, a30 = 0.f, a31 = 0.f;
    for (int a = 0; a < 64; ++a) {
      float2 v = *reinterpret_cast<const float2*>(&Vs[a][2 * l]);
      float pa0 = Ps[w][0][a], pa1 = Ps[w][1][a];
      float pa2 = Ps[w][2][a], pa3 = Ps[w][3][a];
      a00 += pa0 * v.x; a01 += pa0 * v.y;
      a10 += pa1 * v.x; a11 += pa1 * v.y;
      a20 += pa2 * v.x; a21 += pa2 * v.y;
      a30 += pa3 * v.x; a31 += pa3 * v.y;
    }
    size_t row0 = (size_t)(b * APG + 4 * qq) * FEAT + 2 * l;
    float2* o0 = reinterpret_cast<float2*>(out_s + row0);
    float2* o1 = reinterpret_cast<float2*>(out_s + row0 + FEAT);
    float2* o2 = reinterpret_cast<float2*>(out_s + row0 + 2 * FEAT);
    float2* o3 = reinterpret_cast<float2*>(out_s + row0 + 3 * FEAT);
    float2 c0 = *o0; c0.x += a00; c0.y += a01; *o0 = c0;
    float2 c1 = *o1; c1.x += a10; c1.y += a11; *o1 = c1;
    float2 c2 = *o2; c2.x += a20; c2.y += a21; *o2 = c2;
    float2 c3 = *o3; c3.x += a30; c3.y += a31; *o3 = c3;
    __threadfence_block();
  }
}

// ---------------------------------------------------------------- launch
extern "C" void kernel_launch(void* const* d_in, const int* in_sizes, int n_in,
                              void* d_out, int out_size, void* d_ws, size_t ws_size,
                              hipStream_t stream) {
  const float* s_j  = (const float*)d_in[0];
  const float* v_j  = (const float*)d_in[1];
  const float* r_ij = (const float*)d_in[2];
  const int*   nbrs = (const int*)d_in[3];
  const float* W1   = (const float*)d_in[5];
  const float* b1   = (const float*)d_in[6];
  const float* W2   = (const float*)d_in[7];
  const float* b2   = (const float*)d_in[8];
  const float* Wr   = (const float*)d_in[9];
  const float* br   = (const float*)d_in[10];
  const float* Wd   = (const float*)d_in[11];
  const float* bd   = (const float*)d_in[12];

  float* out_s = (float*)d_out;
  float* out_v = out_s + (size_t)NATOMS * FEAT;

  // workspace: 26.4 MB (proven). wrs aliases dead h_bf tail (after sort buffers).
  float*    Qf   = (float*)d_ws;                         // 8192*128 f32   (4 MB)
  ushort_t* kvbf = (ushort_t*)(Qf + NATOMS * FEAT);      // 8192*256 bf16  (4 MB)
  ushort_t* PV   = kvbf + (size_t)NATOMS * 256;          // 8192*128*8 u16 (16 MB)
  ushort_t* w1s  = PV + (size_t)NATOMS * FEAT * 8;       // 16384
  ushort_t* w2s  = w1s + 16384;                          // 49152
  ushort_t* wds  = w2s + 49152;                          // 49152
  ushort_t* h_bf = wds + 49152;                          // 2 MB region (dead after gemm2)
  int* sorted = (int*)h_bf;                              // [0, 1.05 MB)
  int* offs   = sorted + NEDGES;
  int* cursor = offs + (NATOMS + 1);
  int* counts = cursor + NATOMS;                         // ends at 1,146,884 B
  ushort_t* wrs = (ushort_t*)((char*)h_bf + 1310720);    // 24576 B, disjoint

  int prep_total = NATOMS * FEAT + 16384 + 49152 + 49152;
  prep_kernel<<<(prep_total + 255) / 256, 256, 0, stream>>>(
      v_j, W1, W2, Wd, PV, w1s, w2s, wds);

  gemm_mfma<<<dim3(NATOMS / 64, 2), 256, 0, stream>>>(
      s_j, 1, w1s, b1, 128, 8, 1, 1, h_bf, nullptr);
  gemm_mfma<<<dim3(NATOMS / 64, 6), 256, 0, stream>>>(
      h_bf, 0, w2s, b2, 384, 24, 0, 2, PV, nullptr);

  prep2_kernel<<<48, 256, 0, stream>>>(Wr, br, wrs);     // after gemm2 (h_bf dead)
  zero_kernel<<<(NATOMS + 255) / 256, 256, 0, stream>>>(counts, NATOMS);
  hist_kernel<<<NEDGES / 256, 256, 0, stream>>>(nbrs, counts);
  scan_kernel<<<1, 1024, 0, stream>>>(counts, offs, cursor);
  scatter_kernel<<<NEDGES / 256, 256, 0, stream>>>(nbrs, cursor, sorted);

  gemm_mfma<<<dim3(NATOMS / 64, 6), 256, 0, stream>>>(
      s_j, 1, wds, bd, 384, 24, 0, 3, Qf, kvbf);

  edge_mfma4<<<NATOMS / 2, 256, 0, stream>>>(sorted, offs, nbrs, r_ij, PV,
                                             wrs, out_s, out_v);
  attn_kernel<<<NGRAPH * 2, 256, 0, stream>>>(Qf, kvbf, out_s);
}

// Round 9
// 164.349 us; speedup vs baseline: 1.3517x; 1.0624x over previous
//
#include <hip/hip_runtime.h>
#include <hip/hip_bf16.h>
#include <cstdint>

#define FEAT    128
#define NRBF    20
#define NATOMS  8192
#define NEDGES  262144
#define NGRAPH  128
#define APG     64
#define PI_F    3.14159265358979323846f
#define CUTOFF_F 5.0f

typedef unsigned int uint_t;
typedef unsigned short ushort_t;
typedef __attribute__((ext_vector_type(4))) float f32x4;
typedef __attribute__((ext_vector_type(4))) short short4v;
typedef __attribute__((ext_vector_type(8))) short short8;
struct U3 { uint_t x, y, z; };   // 12 B, 4 B aligned -> global_load_dwordx3

__device__ __forceinline__ float bflo(uint_t u) { return __uint_as_float(u << 16); }
__device__ __forceinline__ float bfhi(uint_t u) { return __uint_as_float(u & 0xffff0000u); }
__device__ __forceinline__ float bfus(ushort_t u) { return __uint_as_float((uint_t)u << 16); }
__device__ __forceinline__ ushort_t f2bf(float f) {
  uint_t u = __float_as_uint(f);
  return (ushort_t)((u + 0x7fffu + ((u >> 16) & 1u)) >> 16);
}
__device__ __forceinline__ uint_t pack2(float lo, float hi) {
  return (uint_t)f2bf(lo) | ((uint_t)f2bf(hi) << 16);
}
__device__ __forceinline__ float pick4(float a0, float a1, float a2, float a3, int g) {
  return (g == 0) ? a0 : (g == 1) ? a1 : (g == 2) ? a2 : a3;
}

// ---------------------------------------------------------------- prep
// PV record per (j,f): 6 ushorts {p0,p1,p2,v0,v1,v2} (12 B stride).
// prep writes FULL record pairs (24 B coalesced, P slots zeroed); gemm2's
// epilogue later scatters the P slots. Plus frag-order swizzled weights.
__device__ __forceinline__ ushort_t swz_elem(const float* __restrict__ W, int N,
                                             int NT, int i) {
  int jj = i & 7, lane = (i >> 3) & 63, tile = i >> 9;
  int ks = tile / NT, ctg = tile - ks * NT;
  int g = lane >> 4, q = lane & 15;
  int k = 32 * ks + 4 * g + (jj & 3) + 16 * (jj >> 2);
  int c = 16 * ctg + q;
  return f2bf(W[(size_t)k * N + c]);
}

__global__ void prep_kernel(const float* __restrict__ v_j, const float* __restrict__ W1,
                            const float* __restrict__ W2, const float* __restrict__ Wd,
                            ushort_t* __restrict__ PV, ushort_t* __restrict__ w1s,
                            ushort_t* __restrict__ w2s, ushort_t* __restrict__ wds) {
  int i = blockIdx.x * 256 + threadIdx.x;
  if (i < NATOMS * 64) {                   // i = j*64 + p; features 2p, 2p+1
    const float* vp = v_j + (size_t)i * 6; // 6 consecutive f32 (8 B aligned)
    float2 a = *reinterpret_cast<const float2*>(vp);
    float2 b = *reinterpret_cast<const float2*>(vp + 2);
    float2 c = *reinterpret_cast<const float2*>(vp + 4);
    uint_t* o = reinterpret_cast<uint_t*>(PV + (size_t)i * 12);  // 24 B, 8 B aligned
    uint2 w0 = {0u,                      pack2(0.f, a.x) };      // {p0,p1 | p2,v0}
    uint2 w1 = {pack2(a.y, b.x),         0u };                   // {v1,v2 | p0,p1}
    uint2 w2 = {pack2(0.f, b.y),         pack2(c.x, c.y) };      // {p2,v0 | v1,v2}
    *reinterpret_cast<uint2*>(o)     = w0;
    *reinterpret_cast<uint2*>(o + 2) = w1;
    *reinterpret_cast<uint2*>(o + 4) = w2;
    return;
  }
  i -= NATOMS * 64;
  if (i < 16384) { w1s[i] = swz_elem(W1, 128, 8, i); return; }
  i -= 16384;
  if (i < 49152) { w2s[i] = swz_elem(W2, 384, 24, i); return; }
  i -= 49152;
  if (i < 49152) { wds[i] = swz_elem(Wd, 384, 24, i); return; }
}

// Wr/br -> frag-order bf16: 24 col-tiles x 64 lanes x 8 (k=20 row is br; k>20 zero).
__global__ void prep2_kernel(const float* __restrict__ Wr, const float* __restrict__ br,
                             ushort_t* __restrict__ wrs) {
  int i = blockIdx.x * 256 + threadIdx.x;
  if (i < 12288) {
    int jj = i & 7, lane = (i >> 3) & 63, ct = i >> 9;
    int g = lane >> 4, q = lane & 15;
    int k = 4 * g + (jj & 3) + 16 * (jj >> 2);
    int f = 16 * ct + q;
    float v = (k < NRBF) ? Wr[k * 384 + f] : (k == NRBF ? br[f] : 0.f);
    wrs[i] = f2bf(v);
  }
}

// ---------------------------------------------------------------- MFMA GEMM
// C[8192 x N] = act(A[8192 x 128] @ W + b). Tile 64x64, 4 waves, 16 MFMA/wave.
// omode: 1 = bf16 row out (p0), 2 = PV P-slots (ushort slot s at (row*128+f)*6),
// 3 = qkv-split (p0 Qf f32, p1 kv bf16).
__global__ __launch_bounds__(256) void gemm_mfma(
    const void* __restrict__ Asrc, int a_f32, const ushort_t* __restrict__ Wswz,
    const float* __restrict__ bias, int N, int NT, int silu, int omode,
    void* __restrict__ p0, void* __restrict__ p1) {
  __shared__ ushort_t As[64][136];
  const int t = threadIdx.x;
  const int r0 = blockIdx.x * 64, c0 = blockIdx.y * 64;
  const int w = t >> 6, l = t & 63, g = l >> 4, q = l & 15;

  short8 bf[4][4];
  #pragma unroll
  for (int ks = 0; ks < 4; ++ks)
    #pragma unroll
    for (int ct = 0; ct < 4; ++ct)
      bf[ks][ct] = *reinterpret_cast<const short8*>(
          Wswz + ((size_t)(ks * NT + (c0 >> 4) + ct) * 64 + l) * 8);

  if (a_f32) {
    const float* Af = (const float*)Asrc;
    for (int i = t; i < 64 * 32; i += 256) {
      int r = i >> 5, k4 = i & 31;
      float4 v = *reinterpret_cast<const float4*>(Af + (size_t)(r0 + r) * 128 + 4 * k4);
      ushort4 o = {f2bf(v.x), f2bf(v.y), f2bf(v.z), f2bf(v.w)};
      *reinterpret_cast<ushort4*>(&As[r][4 * k4]) = o;
    }
  } else {
    const ushort_t* Ab = (const ushort_t*)Asrc;
    for (int i = t; i < 64 * 16; i += 256) {
      int r = i >> 4, g8 = i & 15;
      short8 v = *reinterpret_cast<const short8*>(Ab + (size_t)(r0 + r) * 128 + 8 * g8);
      *reinterpret_cast<short8*>(&As[r][8 * g8]) = v;
    }
  }
  __syncthreads();

  f32x4 acc[4] = {};
  #pragma unroll
  for (int ks = 0; ks < 4; ++ks) {
    const ushort_t* ap = &As[16 * w + q][32 * ks + 4 * g];
    short4v alo = *reinterpret_cast<const short4v*>(ap);
    short4v ahi = *reinterpret_cast<const short4v*>(ap + 16);
    short8 af;
    af[0] = alo[0]; af[1] = alo[1]; af[2] = alo[2]; af[3] = alo[3];
    af[4] = ahi[0]; af[5] = ahi[1]; af[6] = ahi[2]; af[7] = ahi[3];
    #pragma unroll
    for (int ct = 0; ct < 4; ++ct)
      acc[ct] = __builtin_amdgcn_mfma_f32_16x16x32_bf16(af, bf[ks][ct], acc[ct], 0, 0, 0);
  }

  #pragma unroll
  for (int ct = 0; ct < 4; ++ct) {
    int col = c0 + 16 * ct + q;
    float bb = bias[col];
    #pragma unroll
    for (int r = 0; r < 4; ++r) {
      float o = acc[ct][r] + bb;
      if (silu) o = o / (1.f + __expf(-o));
      int row = r0 + 16 * w + 4 * g + r;
      if (omode == 1) {
        ((ushort_t*)p0)[(size_t)row * N + col] = f2bf(o);
      } else if (omode == 2) {
        int f = col & 127, s = col >> 7;
        ((ushort_t*)p0)[((size_t)row * 128 + f) * 6 + s] = f2bf(o);
      } else {
        if (col < 128) ((float*)p0)[(size_t)row * 128 + col] = o;
        else           ((ushort_t*)p1)[(size_t)row * 256 + col - 128] = f2bf(o);
      }
    }
  }
}

// ---------------------------------------------------------------- sort helpers
__global__ void zero_kernel(int* __restrict__ p, int n) {
  int i = blockIdx.x * blockDim.x + threadIdx.x;
  if (i < n) p[i] = 0;
}

__global__ void hist_kernel(const int* __restrict__ nbrs, int* __restrict__ counts) {
  int e = blockIdx.x * blockDim.x + threadIdx.x;
  if (e < NEDGES) atomicAdd(&counts[nbrs[2 * e]], 1);
}

__global__ __launch_bounds__(1024) void scan_kernel(
    const int* __restrict__ counts, int* __restrict__ offs, int* __restrict__ cursor) {
  __shared__ int part[1024];
  const int t = threadIdx.x;
  int local[8];
  int s = 0;
  #pragma unroll
  for (int i = 0; i < 8; ++i) { local[i] = counts[t * 8 + i]; s += local[i]; }
  part[t] = s;
  __syncthreads();
  for (int off = 1; off < 1024; off <<= 1) {
    int v = part[t];
    int add = (t >= off) ? part[t - off] : 0;
    __syncthreads();
    part[t] = v + add;
    __syncthreads();
  }
  int excl = part[t] - s;
  #pragma unroll
  for (int i = 0; i < 8; ++i) {
    offs[t * 8 + i] = excl;
    cursor[t * 8 + i] = excl;
    excl += local[i];
  }
  if (t == 1023) offs[NATOMS] = excl;
}

__global__ void scatter_kernel(const int* __restrict__ nbrs, int* __restrict__ cursor,
                               int* __restrict__ sorted) {
  int e = blockIdx.x * blockDim.x + threadIdx.x;
  if (e < NEDGES) {
    int seg = nbrs[2 * e];
    int pos = atomicAdd(&cursor[seg], 1);
    sorted[pos] = e;
  }
}

// ---------------------------------------------------------------- edge MFMA v5
// Two waves per atom (ct-halves); 12 B PV records -> one dwordx3 per (ct,r),
// zero pad waste (per-edge fetch 1536 B vs 2048 B in r8).
// A[16x32pad] basis (k<20: env*sin((k+1)ang)/d, k=20: env, br folded);
// C map HW-verified: row = 4g+reg = edge, col = q.
__global__ __launch_bounds__(256) void edge_mfma5(
    const int* __restrict__ sorted, const int* __restrict__ offs,
    const int* __restrict__ nbrs, const float* __restrict__ r_ij,
    const ushort_t* __restrict__ PV, const ushort_t* __restrict__ wrs,
    float* __restrict__ out_s, float* __restrict__ out_v) {
  __shared__ short8 sW[24 * 64];   // 24576 B
  const int t = threadIdx.x;
  for (int i = t; i < 24 * 64; i += 256)
    sW[i] = *reinterpret_cast<const short8*>(wrs + (size_t)i * 8);
  __syncthreads();

  const int w = t >> 6, l = t & 63, g = l >> 4, q = l & 15;
  const int atom = blockIdx.x * 2 + (w >> 1);
  const int h = w & 1;                    // ct-half: cts 4h..4h+3
  const int start = offs[atom], end = offs[atom + 1];
  const float c1 = PI_F / CUTOFF_F;
  const char* PVb = reinterpret_cast<const char*>(PV);

  float ds[4] = {};
  float dv[4][3] = {};

  for (int eb = start; eb < end; eb += 16) {
    // ---- metadata: lane q owns edge eb+q (replicated across g)
    float ang = 0.f, ie = 0.f, env = 0.f, u0 = 0.f, u1 = 0.f, u2 = 0.f;
    int jn = 0;
    if (eb + q < end) {
      int e = sorted[eb + q];
      float x = r_ij[3 * e], y = r_ij[3 * e + 1], z = r_ij[3 * e + 2];
      jn = nbrs[2 * e + 1];
      float d = sqrtf(x * x + y * y + z * z);
      float inv = 1.f / d;
      ang = c1 * d;
      env = (d < CUTOFF_F) ? 0.5f * (__cosf(ang) + 1.f) : 0.f;
      ie = inv * env;
      u0 = x * inv; u1 = y * inv; u2 = z * inv;
    }
    // ---- row (edge eb+4g+r) metadata broadcast + base pointers
    const char* pb[4];
    float ub[4][3];
    #pragma unroll
    for (int r = 0; r < 4; ++r) {
      int src = 4 * g + r;
      int jr = __shfl(jn, src, 64);
      ub[r][0] = __shfl(u0, src, 64);
      ub[r][1] = __shfl(u1, src, 64);
      ub[r][2] = __shfl(u2, src, 64);
      pb[r] = PVb + (size_t)jr * 1536 + (size_t)q * 12;
    }
    // ---- issue ALL 16 gathers (12 B each) up front
    U3 ld[4][4];
    #pragma unroll
    for (int c = 0; c < 4; ++c)
      #pragma unroll
      for (int r = 0; r < 4; ++r)
        ld[c][r] = *reinterpret_cast<const U3*>(pb[r] + (size_t)(4 * h + c) * 192);
    // ---- A fragment: k = kmap(g,jj) = 4g+(jj&3)+16*(jj>>2)
    short8 af;
    #pragma unroll
    for (int jj = 0; jj < 8; ++jj) {
      int k = 4 * g + (jj & 3) + 16 * (jj >> 2);
      float v = (k < NRBF) ? ie * __sinf((float)(k + 1) * ang)
                           : (k == NRBF ? env : 0.f);
      af[jj] = (short)f2bf(v);
    }
    // ---- 4 col-tiles x 3 sections
    #pragma unroll
    for (int c = 0; c < 4; ++c) {
      int ctg = 4 * h + c;
      short8 b0 = sW[(0 * 8 + ctg) * 64 + l];
      short8 b1 = sW[(1 * 8 + ctg) * 64 + l];
      short8 b2 = sW[(2 * 8 + ctg) * 64 + l];
      f32x4 z4 = {0.f, 0.f, 0.f, 0.f};
      f32x4 cs0 = __builtin_amdgcn_mfma_f32_16x16x32_bf16(af, b0, z4, 0, 0, 0);
      f32x4 cs1 = __builtin_amdgcn_mfma_f32_16x16x32_bf16(af, b1, z4, 0, 0, 0);
      f32x4 cs2 = __builtin_amdgcn_mfma_f32_16x16x32_bf16(af, b2, z4, 0, 0, 0);
      #pragma unroll
      for (int r = 0; r < 4; ++r) {
        U3 u = ld[c][r];
        float p0 = bflo(u.x), p1 = bfhi(u.x);
        float p2 = bflo(u.y), v0 = bfhi(u.y);
        float v1 = bflo(u.z), v2 = bfhi(u.z);
        float pw0 = p0 * cs0[r];
        ds[c] += p1 * cs1[r];
        float pw2 = p2 * cs2[r];
        dv[c][0] += pw0 * v0 + pw2 * ub[r][0];
        dv[c][1] += pw0 * v1 + pw2 * ub[r][1];
        dv[c][2] += pw0 * v2 + pw2 * ub[r][2];
      }
    }
  }

  // ---- reduce the 4 g-copies (each accumulated different edge rows)
  #pragma unroll
  for (int c = 0; c < 4; ++c) {
    float x = ds[c];
    x += __shfl_xor(x, 16, 64); x += __shfl_xor(x, 32, 64);
    ds[c] = x;
    #pragma unroll
    for (int cc = 0; cc < 3; ++cc) {
      float y = dv[c][cc];
      y += __shfl_xor(y, 16, 64); y += __shfl_xor(y, 32, 64);
      dv[c][cc] = y;
    }
  }
  // ---- write: lane (g,q) owns ctg = 4h+g, feature f = 16*ctg+q
  float sv = pick4(ds[0], ds[1], ds[2], ds[3], g);
  float d0 = pick4(dv[0][0], dv[1][0], dv[2][0], dv[3][0], g);
  float d1 = pick4(dv[0][1], dv[1][1], dv[2][1], dv[3][1], g);
  float d2 = pick4(dv[0][2], dv[1][2], dv[2][2], dv[3][2], g);
  int f = 16 * (4 * h + g) + q;
  out_s[(size_t)atom * FEAT + f] = sv;
  float* ov = out_v + (size_t)atom * 384 + (size_t)f * 3;
  ov[0] = d0; ov[1] = d1; ov[2] = d2;
}

// ---------------------------------------------------------------- attention
__device__ __forceinline__ float wave_max64(float v) {
  #pragma unroll
  for (int m = 32; m > 0; m >>= 1) v = fmaxf(v, __shfl_xor(v, m, 64));
  return v;
}
__device__ __forceinline__ float wave_sum64(float v) {
  #pragma unroll
  for (int m = 32; m > 0; m >>= 1) v += __shfl_xor(v, m, 64);
  return v;
}

__global__ __launch_bounds__(256) void attn_kernel(const float* __restrict__ Qf,
                                                   const ushort_t* __restrict__ kvbf,
                                                   float* __restrict__ out_s) {
  __shared__ float4 Ks4[64 * 32];
  __shared__ float  Vs[64][130];
  __shared__ float  Ps[4][4][64];
  const int b = blockIdx.x >> 1, half = blockIdx.x & 1;
  const int t = threadIdx.x;
  const float* qbase = Qf + (size_t)b * APG * 128;
  const ushort_t* kvb = kvbf + (size_t)b * APG * 256;

  for (int i = t; i < 64 * 32; i += 256) {
    int a = i >> 5, gg = i & 31;
    ushort4 k4 = *reinterpret_cast<const ushort4*>(kvb + a * 256 + 4 * gg);
    float4 kf = {bfus(k4.x), bfus(k4.y), bfus(k4.z), bfus(k4.w)};
    Ks4[a * 32 + (gg ^ (a & 7))] = kf;
  }
  for (int i = t; i < 64 * 32; i += 256) {
    int a = i >> 5, gg = i & 31;
    ushort4 v4 = *reinterpret_cast<const ushort4*>(kvb + a * 256 + 128 + 4 * gg);
    Vs[a][4 * gg + 0] = bfus(v4.x); Vs[a][4 * gg + 1] = bfus(v4.y);
    Vs[a][4 * gg + 2] = bfus(v4.z); Vs[a][4 * gg + 3] = bfus(v4.w);
  }
  __syncthreads();

  const int w = t >> 6, l = t & 63;
  const float scale = 0.08838834764831845f;

  for (int qq = 8 * half + w; qq < 8 * half + 8; qq += 4) {
    const float* q0p = qbase + (size_t)(4 * qq + 0) * 128;
    const float* q1p = qbase + (size_t)(4 * qq + 1) * 128;
    const float* q2p = qbase + (size_t)(4 * qq + 2) * 128;
    const float* q3p = qbase + (size_t)(4 * qq + 3) * 128;
    float s0 = 0.f, s1 = 0.f, s2 = 0.f, s3 = 0.f;
    #pragma unroll 8
    for (int i = 0; i < 32; ++i) {
      float4 k = Ks4[l * 32 + (i ^ (l & 7))];
      float4 q0 = *reinterpret_cast<const float4*>(q0p + 4 * i);
      float4 q1 = *reinterpret_cast<const float4*>(q1p + 4 * i);
      float4 q2 = *reinterpret_cast<const float4*>(q2p + 4 * i);
      float4 q3 = *reinterpret_cast<const float4*>(q3p + 4 * i);
      s0 += q0.x * k.x + q0.y * k.y + q0.z * k.z + q0.w * k.w;
      s1 += q1.x * k.x + q1.y * k.y + q1.z * k.z + q1.w * k.w;
      s2 += q2.x * k.x + q2.y * k.y + q2.z * k.z + q2.w * k.w;
      s3 += q3.x * k.x + q3.y * k.y + q3.z * k.z + q3.w * k.w;
    }
    s0 *= scale; s1 *= scale; s2 *= scale; s3 *= scale;

    float p0 = __expf(s0 - wave_max64(s0));
    float p1 = __expf(s1 - wave_max64(s1));
    float p2 = __expf(s2 - wave_max64(s2));
    float p3 = __expf(s3 - wave_max64(s3));
    p0 /= wave_sum64(p0); p1 /= wave_sum64(p1);
    p2 /= wave_sum64(p2); p3 /= wave_sum64(p3);

    Ps[w][0][l] = p0; Ps[w][1][l] = p1; Ps[w][2][l] = p2; Ps[w][3][l] = p3;
    __threadfence_block();

    float a00 = 0.f, a01 = 0.f, a10 = 0.f, a11 = 0.f;
    float a20 = 0.f, a21 = 0.f, a30 = 0.f, a31 = 0.f;
    for (int a = 0; a < 64; ++a) {
      float2 v = *reinterpret_cast<const float2*>(&Vs[a][2 * l]);
      float pa0 = Ps[w][0][a], pa1 = Ps[w][1][a];
      float pa2 = Ps[w][2][a], pa3 = Ps[w][3][a];
      a00 += pa0 * v.x; a01 += pa0 * v.y;
      a10 += pa1 * v.x; a11 += pa1 * v.y;
      a20 += pa2 * v.x; a21 += pa2 * v.y;
      a30 += pa3 * v.x; a31 += pa3 * v.y;
    }
    size_t row0 = (size_t)(b * APG + 4 * qq) * FEAT + 2 * l;
    float2* o0 = reinterpret_cast<float2*>(out_s + row0);
    float2* o1 = reinterpret_cast<float2*>(out_s + row0 + FEAT);
    float2* o2 = reinterpret_cast<float2*>(out_s + row0 + 2 * FEAT);
    float2* o3 = reinterpret_cast<float2*>(out_s + row0 + 3 * FEAT);
    float2 c0 = *o0; c0.x += a00; c0.y += a01; *o0 = c0;
    float2 c1 = *o1; c1.x += a10; c1.y += a11; *o1 = c1;
    float2 c2 = *o2; c2.x += a20; c2.y += a21; *o2 = c2;
    float2 c3 = *o3; c3.x += a30; c3.y += a31; *o3 = c3;
    __threadfence_block();
  }
}

// ---------------------------------------------------------------- launch
extern "C" void kernel_launch(void* const* d_in, const int* in_sizes, int n_in,
                              void* d_out, int out_size, void* d_ws, size_t ws_size,
                              hipStream_t stream) {
  const float* s_j  = (const float*)d_in[0];
  const float* v_j  = (const float*)d_in[1];
  const float* r_ij = (const float*)d_in[2];
  const int*   nbrs = (const int*)d_in[3];
  const float* W1   = (const float*)d_in[5];
  const float* b1   = (const float*)d_in[6];
  const float* W2   = (const float*)d_in[7];
  const float* b2   = (const float*)d_in[8];
  const float* Wr   = (const float*)d_in[9];
  const float* br   = (const float*)d_in[10];
  const float* Wd   = (const float*)d_in[11];
  const float* bd   = (const float*)d_in[12];

  float* out_s = (float*)d_out;
  float* out_v = out_s + (size_t)NATOMS * FEAT;

  // workspace: ~23 MB (<= 26.4 MB proven). wrs aliases dead h_bf tail.
  float*    Qf   = (float*)d_ws;                         // 8192*128 f32   (4 MB)
  ushort_t* kvbf = (ushort_t*)(Qf + NATOMS * FEAT);      // 8192*256 bf16  (4 MB)
  ushort_t* PV   = kvbf + (size_t)NATOMS * 256;          // 8192*128*6 u16 (12.6 MB)
  ushort_t* w1s  = PV + (size_t)NATOMS * FEAT * 6;       // 16384
  ushort_t* w2s  = w1s + 16384;                          // 49152
  ushort_t* wds  = w2s + 49152;                          // 49152
  ushort_t* h_bf = wds + 49152;                          // 2 MB region (dead after gemm2)
  int* sorted = (int*)h_bf;                              // [0, 1.05 MB)
  int* offs   = sorted + NEDGES;
  int* cursor = offs + (NATOMS + 1);
  int* counts = cursor + NATOMS;                         // ends at 1,146,884 B
  ushort_t* wrs = (ushort_t*)((char*)h_bf + 1310720);    // 24576 B, disjoint

  int prep_total = NATOMS * 64 + 16384 + 49152 + 49152;
  prep_kernel<<<(prep_total + 255) / 256, 256, 0, stream>>>(
      v_j, W1, W2, Wd, PV, w1s, w2s, wds);

  gemm_mfma<<<dim3(NATOMS / 64, 2), 256, 0, stream>>>(
      s_j, 1, w1s, b1, 128, 8, 1, 1, h_bf, nullptr);
  gemm_mfma<<<dim3(NATOMS / 64, 6), 256, 0, stream>>>(
      h_bf, 0, w2s, b2, 384, 24, 0, 2, PV, nullptr);

  prep2_kernel<<<48, 256, 0, stream>>>(Wr, br, wrs);     // after gemm2 (h_bf dead)
  zero_kernel<<<(NATOMS + 255) / 256, 256, 0, stream>>>(counts, NATOMS);
  hist_kernel<<<NEDGES / 256, 256, 0, stream>>>(nbrs, counts);
  scan_kernel<<<1, 1024, 0, stream>>>(counts, offs, cursor);
  scatter_kernel<<<NEDGES / 256, 256, 0, stream>>>(nbrs, cursor, sorted);

  gemm_mfma<<<dim3(NATOMS / 64, 6), 256, 0, stream>>>(
      s_j, 1, wds, bd, 384, 24, 0, 3, Qf, kvbf);

  edge_mfma5<<<NATOMS / 2, 256, 0, stream>>>(sorted, offs, nbrs, r_ij, PV,
                                             wrs, out_s, out_v);
  attn_kernel<<<NGRAPH * 2, 256, 0, stream>>>(Qf, kvbf, out_s);
}

// Round 10
// 161.359 us; speedup vs baseline: 1.3767x; 1.0185x over previous
//
#include <hip/hip_runtime.h>
#include <hip/hip_bf16.h>
#include <cstdint>

#define FEAT    128
#define NRBF    20
#define NATOMS  8192
#define NEDGES  262144
#define NGRAPH  128
#define APG     64
#define PI_F    3.14159265358979323846f
#define CUTOFF_F 5.0f
#define TABUS   ((size_t)NATOMS * 64 * 6)   // ushorts per PV half-table (6.29 MB)

typedef unsigned int uint_t;
typedef unsigned short ushort_t;
typedef __attribute__((ext_vector_type(4))) float f32x4;
typedef __attribute__((ext_vector_type(4))) short short4v;
typedef __attribute__((ext_vector_type(8))) short short8;
struct U3 { uint_t x, y, z; };   // 12 B, 4 B aligned -> global_load_dwordx3

__device__ __forceinline__ float bflo(uint_t u) { return __uint_as_float(u << 16); }
__device__ __forceinline__ float bfhi(uint_t u) { return __uint_as_float(u & 0xffff0000u); }
__device__ __forceinline__ float bfus(ushort_t u) { return __uint_as_float((uint_t)u << 16); }
__device__ __forceinline__ ushort_t f2bf(float f) {
  uint_t u = __float_as_uint(f);
  return (ushort_t)((u + 0x7fffu + ((u >> 16) & 1u)) >> 16);
}
__device__ __forceinline__ uint_t pack2(float lo, float hi) {
  return (uint_t)f2bf(lo) | ((uint_t)f2bf(hi) << 16);
}
__device__ __forceinline__ float pick4(float a0, float a1, float a2, float a3, int g) {
  return (g == 0) ? a0 : (g == 1) ? a1 : (g == 2) ? a2 : a3;
}

// ---------------------------------------------------------------- prep
// PV record per (j,f): 6 ushorts {p0,p1,p2,v0,v1,v2}, 12 B stride, SPLIT into two
// half-tables by h = f>>6 (so single-h blocks touch a 6.3 MB working set).
// prep writes full records (P slots zeroed; gemm2 scatters P later), plus all
// frag-order swizzled weights (W1/W2/Wd/Wr+br).
__device__ __forceinline__ ushort_t swz_elem(const float* __restrict__ W, int N,
                                             int NT, int i) {
  int jj = i & 7, lane = (i >> 3) & 63, tile = i >> 9;
  int ks = tile / NT, ctg = tile - ks * NT;
  int g = lane >> 4, q = lane & 15;
  int k = 32 * ks + 4 * g + (jj & 3) + 16 * (jj >> 2);
  int c = 16 * ctg + q;
  return f2bf(W[(size_t)k * N + c]);
}

__global__ void prep_kernel(const float* __restrict__ v_j, const float* __restrict__ W1,
                            const float* __restrict__ W2, const float* __restrict__ Wd,
                            const float* __restrict__ Wr, const float* __restrict__ br,
                            ushort_t* __restrict__ PV, ushort_t* __restrict__ w1s,
                            ushort_t* __restrict__ w2s, ushort_t* __restrict__ wds,
                            ushort_t* __restrict__ wrs) {
  int i = blockIdx.x * 256 + threadIdx.x;
  if (i < NATOMS * FEAT) {                 // i = j*128 + f
    int j = i >> 7, f = i & 127;
    int h = f >> 6, fl = f & 63;
    const float* vp = v_j + (size_t)i * 3; // v_j[j][f][0..2]
    ushort_t* rp = PV + (size_t)h * TABUS + ((size_t)j * 64 + fl) * 6;
    uint_t* o = reinterpret_cast<uint_t*>(rp);
    o[0] = 0u;                     // p0,p1 (gemm2 fills)
    o[1] = pack2(0.f, vp[0]);      // p2,v0
    o[2] = pack2(vp[1], vp[2]);    // v1,v2
    return;
  }
  i -= NATOMS * FEAT;
  if (i < 16384) { w1s[i] = swz_elem(W1, 128, 8, i); return; }
  i -= 16384;
  if (i < 49152) { w2s[i] = swz_elem(W2, 384, 24, i); return; }
  i -= 49152;
  if (i < 49152) { wds[i] = swz_elem(Wd, 384, 24, i); return; }
  i -= 49152;
  if (i < 12288) {                 // Wr/br frag-order: 24 tiles, k=20 row is br
    int jj = i & 7, lane = (i >> 3) & 63, ct = i >> 9;
    int g = lane >> 4, q = lane & 15;
    int k = 4 * g + (jj & 3) + 16 * (jj >> 2);
    int f = 16 * ct + q;
    float v = (k < NRBF) ? Wr[k * 384 + f] : (k == NRBF ? br[f] : 0.f);
    wrs[i] = f2bf(v);
  }
}

// ---------------------------------------------------------------- MFMA GEMM
// C[8192 x N] = act(A[8192 x 128] @ W + b). Tile 64x64, 4 waves, 16 MFMA/wave.
// omode: 1 = bf16 row out (p0), 2 = PV P-slots (split-table scatter),
// 3 = qkv-split (p0 Qf f32, p1 kv bf16).
__global__ __launch_bounds__(256) void gemm_mfma(
    const void* __restrict__ Asrc, int a_f32, const ushort_t* __restrict__ Wswz,
    const float* __restrict__ bias, int N, int NT, int silu, int omode,
    void* __restrict__ p0, void* __restrict__ p1) {
  __shared__ ushort_t As[64][136];
  const int t = threadIdx.x;
  const int r0 = blockIdx.x * 64, c0 = blockIdx.y * 64;
  const int w = t >> 6, l = t & 63, g = l >> 4, q = l & 15;

  short8 bf[4][4];
  #pragma unroll
  for (int ks = 0; ks < 4; ++ks)
    #pragma unroll
    for (int ct = 0; ct < 4; ++ct)
      bf[ks][ct] = *reinterpret_cast<const short8*>(
          Wswz + ((size_t)(ks * NT + (c0 >> 4) + ct) * 64 + l) * 8);

  if (a_f32) {
    const float* Af = (const float*)Asrc;
    for (int i = t; i < 64 * 32; i += 256) {
      int r = i >> 5, k4 = i & 31;
      float4 v = *reinterpret_cast<const float4*>(Af + (size_t)(r0 + r) * 128 + 4 * k4);
      ushort4 o = {f2bf(v.x), f2bf(v.y), f2bf(v.z), f2bf(v.w)};
      *reinterpret_cast<ushort4*>(&As[r][4 * k4]) = o;
    }
  } else {
    const ushort_t* Ab = (const ushort_t*)Asrc;
    for (int i = t; i < 64 * 16; i += 256) {
      int r = i >> 4, g8 = i & 15;
      short8 v = *reinterpret_cast<const short8*>(Ab + (size_t)(r0 + r) * 128 + 8 * g8);
      *reinterpret_cast<short8*>(&As[r][8 * g8]) = v;
    }
  }
  __syncthreads();

  f32x4 acc[4] = {};
  #pragma unroll
  for (int ks = 0; ks < 4; ++ks) {
    const ushort_t* ap = &As[16 * w + q][32 * ks + 4 * g];
    short4v alo = *reinterpret_cast<const short4v*>(ap);
    short4v ahi = *reinterpret_cast<const short4v*>(ap + 16);
    short8 af;
    af[0] = alo[0]; af[1] = alo[1]; af[2] = alo[2]; af[3] = alo[3];
    af[4] = ahi[0]; af[5] = ahi[1]; af[6] = ahi[2]; af[7] = ahi[3];
    #pragma unroll
    for (int ct = 0; ct < 4; ++ct)
      acc[ct] = __builtin_amdgcn_mfma_f32_16x16x32_bf16(af, bf[ks][ct], acc[ct], 0, 0, 0);
  }

  #pragma unroll
  for (int ct = 0; ct < 4; ++ct) {
    int col = c0 + 16 * ct + q;
    float bb = bias[col];
    #pragma unroll
    for (int r = 0; r < 4; ++r) {
      float o = acc[ct][r] + bb;
      if (silu) o = o / (1.f + __expf(-o));
      int row = r0 + 16 * w + 4 * g + r;
      if (omode == 1) {
        ((ushort_t*)p0)[(size_t)row * N + col] = f2bf(o);
      } else if (omode == 2) {
        int f = col & 127, s = col >> 7;
        int hh = f >> 6, fl = f & 63;
        ((ushort_t*)p0)[(size_t)hh * TABUS + ((size_t)row * 64 + fl) * 6 + s] = f2bf(o);
      } else {
        if (col < 128) ((float*)p0)[(size_t)row * 128 + col] = o;
        else           ((ushort_t*)p1)[(size_t)row * 256 + col - 128] = f2bf(o);
      }
    }
  }
}

// ---------------------------------------------------------------- sort helpers
__global__ void hist_kernel(const int* __restrict__ nbrs, int* __restrict__ counts) {
  int e = blockIdx.x * blockDim.x + threadIdx.x;
  if (e < NEDGES) atomicAdd(&counts[nbrs[2 * e]], 1);
}

__global__ __launch_bounds__(1024) void scan_kernel(
    const int* __restrict__ counts, int* __restrict__ offs, int* __restrict__ cursor) {
  __shared__ int part[1024];
  const int t = threadIdx.x;
  int local[8];
  int s = 0;
  #pragma unroll
  for (int i = 0; i < 8; ++i) { local[i] = counts[t * 8 + i]; s += local[i]; }
  part[t] = s;
  __syncthreads();
  for (int off = 1; off < 1024; off <<= 1) {
    int v = part[t];
    int add = (t >= off) ? part[t - off] : 0;
    __syncthreads();
    part[t] = v + add;
    __syncthreads();
  }
  int excl = part[t] - s;
  #pragma unroll
  for (int i = 0; i < 8; ++i) {
    offs[t * 8 + i] = excl;
    cursor[t * 8 + i] = excl;
    excl += local[i];
  }
  if (t == 1023) offs[NATOMS] = excl;
}

__global__ void scatter_kernel(const int* __restrict__ nbrs, int* __restrict__ cursor,
                               int* __restrict__ sorted) {
  int e = blockIdx.x * blockDim.x + threadIdx.x;
  if (e < NEDGES) {
    int seg = nbrs[2 * e];
    int pos = atomicAdd(&cursor[seg], 1);
    sorted[pos] = e;
  }
}

// ---------------------------------------------------------------- edge MFMA v6
// Single-h blocks: h = blockIdx.x & 1, so (with bid%8 XCD round-robin) even XCDs
// touch only PV table 0 and odd XCDs only table 1 -> per-XCD L2 working set
// 12.6 -> 6.3 MB. Each of 4 waves owns one atom (ct-half h): 16-edge tiles,
// A = basis coeffs (k<20: env*sin((k+1)ang)/d, k=20: env, br folded),
// 12 MFMAs + 16 dwordx3 PV gathers per tile. C map HW-verified: row=4g+reg, col=q.
__global__ __launch_bounds__(256) void edge_mfma6(
    const int* __restrict__ sorted, const int* __restrict__ offs,
    const int* __restrict__ nbrs, const float* __restrict__ r_ij,
    const ushort_t* __restrict__ PV, const ushort_t* __restrict__ wrs,
    float* __restrict__ out_s, float* __restrict__ out_v) {
  __shared__ short8 sW[12 * 64];   // 12288 B (this h's 12 tiles only)
  const int t = threadIdx.x;
  const int h = blockIdx.x & 1;
  for (int i = t; i < 12 * 64; i += 256) {
    int tl = i >> 6, l2 = i & 63;
    int s = tl >> 2, c = tl & 3;
    sW[i] = *reinterpret_cast<const short8*>(
        wrs + ((size_t)(s * 8 + 4 * h + c) * 64 + l2) * 8);
  }
  __syncthreads();

  const int w = t >> 6, l = t & 63, g = l >> 4, q = l & 15;
  const int atom = (blockIdx.x >> 1) * 4 + w;
  const int start = offs[atom], end = offs[atom + 1];
  const float c1 = PI_F / CUTOFF_F;
  const char* PVb = reinterpret_cast<const char*>(PV) + (size_t)h * TABUS * 2;

  float ds[4] = {};
  float dv[4][3] = {};

  for (int eb = start; eb < end; eb += 16) {
    // ---- metadata: lane q owns edge eb+q (replicated across g)
    float ang = 0.f, ie = 0.f, env = 0.f, u0 = 0.f, u1 = 0.f, u2 = 0.f;
    int jn = 0;
    if (eb + q < end) {
      int e = sorted[eb + q];
      float x = r_ij[3 * e], y = r_ij[3 * e + 1], z = r_ij[3 * e + 2];
      jn = nbrs[2 * e + 1];
      float d = sqrtf(x * x + y * y + z * z);
      float inv = 1.f / d;
      ang = c1 * d;
      env = (d < CUTOFF_F) ? 0.5f * (__cosf(ang) + 1.f) : 0.f;
      ie = inv * env;
      u0 = x * inv; u1 = y * inv; u2 = z * inv;
    }
    // ---- row (edge eb+4g+r) metadata broadcast + base pointers
    const char* pb[4];
    float ub[4][3];
    #pragma unroll
    for (int r = 0; r < 4; ++r) {
      int src = 4 * g + r;
      int jr = __shfl(jn, src, 64);
      ub[r][0] = __shfl(u0, src, 64);
      ub[r][1] = __shfl(u1, src, 64);
      ub[r][2] = __shfl(u2, src, 64);
      pb[r] = PVb + (size_t)jr * 768 + (size_t)q * 12;
    }
    // ---- issue ALL 16 gathers (12 B each) up front
    U3 ld[4][4];
    #pragma unroll
    for (int c = 0; c < 4; ++c)
      #pragma unroll
      for (int r = 0; r < 4; ++r)
        ld[c][r] = *reinterpret_cast<const U3*>(pb[r] + (size_t)c * 192);
    // ---- A fragment: k = kmap(g,jj) = 4g+(jj&3)+16*(jj>>2)
    short8 af;
    #pragma unroll
    for (int jj = 0; jj < 8; ++jj) {
      int k = 4 * g + (jj & 3) + 16 * (jj >> 2);
      float v = (k < NRBF) ? ie * __sinf((float)(k + 1) * ang)
                           : (k == NRBF ? env : 0.f);
      af[jj] = (short)f2bf(v);
    }
    // ---- 4 col-tiles x 3 sections
    #pragma unroll
    for (int c = 0; c < 4; ++c) {
      short8 b0 = sW[(0 * 4 + c) * 64 + l];
      short8 b1 = sW[(1 * 4 + c) * 64 + l];
      short8 b2 = sW[(2 * 4 + c) * 64 + l];
      f32x4 z4 = {0.f, 0.f, 0.f, 0.f};
      f32x4 cs0 = __builtin_amdgcn_mfma_f32_16x16x32_bf16(af, b0, z4, 0, 0, 0);
      f32x4 cs1 = __builtin_amdgcn_mfma_f32_16x16x32_bf16(af, b1, z4, 0, 0, 0);
      f32x4 cs2 = __builtin_amdgcn_mfma_f32_16x16x32_bf16(af, b2, z4, 0, 0, 0);
      #pragma unroll
      for (int r = 0; r < 4; ++r) {
        U3 u = ld[c][r];
        float p0 = bflo(u.x), p1 = bfhi(u.x);
        float p2 = bflo(u.y), v0 = bfhi(u.y);
        float v1 = bflo(u.z), v2 = bfhi(u.z);
        float pw0 = p0 * cs0[r];
        ds[c] += p1 * cs1[r];
        float pw2 = p2 * cs2[r];
        dv[c][0] += pw0 * v0 + pw2 * ub[r][0];
        dv[c][1] += pw0 * v1 + pw2 * ub[r][1];
        dv[c][2] += pw0 * v2 + pw2 * ub[r][2];
      }
    }
  }

  // ---- reduce the 4 g-copies (each accumulated different edge rows)
  #pragma unroll
  for (int c = 0; c < 4; ++c) {
    float x = ds[c];
    x += __shfl_xor(x, 16, 64); x += __shfl_xor(x, 32, 64);
    ds[c] = x;
    #pragma unroll
    for (int cc = 0; cc < 3; ++cc) {
      float y = dv[c][cc];
      y += __shfl_xor(y, 16, 64); y += __shfl_xor(y, 32, 64);
      dv[c][cc] = y;
    }
  }
  // ---- write: lane (g,q) owns c = g, feature f = 64h + 16g + q
  float sv = pick4(ds[0], ds[1], ds[2], ds[3], g);
  float d0 = pick4(dv[0][0], dv[1][0], dv[2][0], dv[3][0], g);
  float d1 = pick4(dv[0][1], dv[1][1], dv[2][1], dv[3][1], g);
  float d2 = pick4(dv[0][2], dv[1][2], dv[2][2], dv[3][2], g);
  int f = 64 * h + 16 * g + q;
  out_s[(size_t)atom * FEAT + f] = sv;
  float* ov = out_v + (size_t)atom * 384 + (size_t)f * 3;
  ov[0] = d0; ov[1] = d1; ov[2] = d2;
}

// ---------------------------------------------------------------- attention
__device__ __forceinline__ float wave_max64(float v) {
  #pragma unroll
  for (int m = 32; m > 0; m >>= 1) v = fmaxf(v, __shfl_xor(v, m, 64));
  return v;
}
__device__ __forceinline__ float wave_sum64(float v) {
  #pragma unroll
  for (int m = 32; m > 0; m >>= 1) v += __shfl_xor(v, m, 64);
  return v;
}

__global__ __launch_bounds__(256) void attn_kernel(const float* __restrict__ Qf,
                                                   const ushort_t* __restrict__ kvbf,
                                                   float* __restrict__ out_s) {
  __shared__ float4 Ks4[64 * 32];
  __shared__ float  Vs[64][130];
  __shared__ float  Ps[4][4][64];
  const int b = blockIdx.x >> 1, half = blockIdx.x & 1;
  const int t = threadIdx.x;
  const float* qbase = Qf + (size_t)b * APG * 128;
  const ushort_t* kvb = kvbf + (size_t)b * APG * 256;

  for (int i = t; i < 64 * 32; i += 256) {
    int a = i >> 5, gg = i & 31;
    ushort4 k4 = *reinterpret_cast<const ushort4*>(kvb + a * 256 + 4 * gg);
    float4 kf = {bfus(k4.x), bfus(k4.y), bfus(k4.z), bfus(k4.w)};
    Ks4[a * 32 + (gg ^ (a & 7))] = kf;
  }
  for (int i = t; i < 64 * 32; i += 256) {
    int a = i >> 5, gg = i & 31;
    ushort4 v4 = *reinterpret_cast<const ushort4*>(kvb + a * 256 + 128 + 4 * gg);
    Vs[a][4 * gg + 0] = bfus(v4.x); Vs[a][4 * gg + 1] = bfus(v4.y);
    Vs[a][4 * gg + 2] = bfus(v4.z); Vs[a][4 * gg + 3] = bfus(v4.w);
  }
  __syncthreads();

  const int w = t >> 6, l = t & 63;
  const float scale = 0.08838834764831845f;

  for (int qq = 8 * half + w; qq < 8 * half + 8; qq += 4) {
    const float* q0p = qbase + (size_t)(4 * qq + 0) * 128;
    const float* q1p = qbase + (size_t)(4 * qq + 1) * 128;
    const float* q2p = qbase + (size_t)(4 * qq + 2) * 128;
    const float* q3p = qbase + (size_t)(4 * qq + 3) * 128;
    float s0 = 0.f, s1 = 0.f, s2 = 0.f, s3 = 0.f;
    #pragma unroll 8
    for (int i = 0; i < 32; ++i) {
      float4 k = Ks4[l * 32 + (i ^ (l & 7))];
      float4 q0 = *reinterpret_cast<const float4*>(q0p + 4 * i);
      float4 q1 = *reinterpret_cast<const float4*>(q1p + 4 * i);
      float4 q2 = *reinterpret_cast<const float4*>(q2p + 4 * i);
      float4 q3 = *reinterpret_cast<const float4*>(q3p + 4 * i);
      s0 += q0.x * k.x + q0.y * k.y + q0.z * k.z + q0.w * k.w;
      s1 += q1.x * k.x + q1.y * k.y + q1.z * k.z + q1.w * k.w;
      s2 += q2.x * k.x + q2.y * k.y + q2.z * k.z + q2.w * k.w;
      s3 += q3.x * k.x + q3.y * k.y + q3.z * k.z + q3.w * k.w;
    }
    s0 *= scale; s1 *= scale; s2 *= scale; s3 *= scale;

    float p0 = __expf(s0 - wave_max64(s0));
    float p1 = __expf(s1 - wave_max64(s1));
    float p2 = __expf(s2 - wave_max64(s2));
    float p3 = __expf(s3 - wave_max64(s3));
    p0 /= wave_sum64(p0); p1 /= wave_sum64(p1);
    p2 /= wave_sum64(p2); p3 /= wave_sum64(p3);

    Ps[w][0][l] = p0; Ps[w][1][l] = p1; Ps[w][2][l] = p2; Ps[w][3][l] = p3;
    __threadfence_block();

    float a00 = 0.f, a01 = 0.f, a10 = 0.f, a11 = 0.f;
    float a20 = 0.f, a21 = 0.f, a30 = 0.f, a31 = 0.f;
    for (int a = 0; a < 64; ++a) {
      float2 v = *reinterpret_cast<const float2*>(&Vs[a][2 * l]);
      float pa0 = Ps[w][0][a], pa1 = Ps[w][1][a];
      float pa2 = Ps[w][2][a], pa3 = Ps[w][3][a];
      a00 += pa0 * v.x; a01 += pa0 * v.y;
      a10 += pa1 * v.x; a11 += pa1 * v.y;
      a20 += pa2 * v.x; a21 += pa2 * v.y;
      a30 += pa3 * v.x; a31 += pa3 * v.y;
    }
    size_t row0 = (size_t)(b * APG + 4 * qq) * FEAT + 2 * l;
    float2* o0 = reinterpret_cast<float2*>(out_s + row0);
    float2* o1 = reinterpret_cast<float2*>(out_s + row0 + FEAT);
    float2* o2 = reinterpret_cast<float2*>(out_s + row0 + 2 * FEAT);
    float2* o3 = reinterpret_cast<float2*>(out_s + row0 + 3 * FEAT);
    float2 c0 = *o0; c0.x += a00; c0.y += a01; *o0 = c0;
    float2 c1 = *o1; c1.x += a10; c1.y += a11; *o1 = c1;
    float2 c2 = *o2; c2.x += a20; c2.y += a21; *o2 = c2;
    float2 c3 = *o3; c3.x += a30; c3.y += a31; *o3 = c3;
    __threadfence_block();
  }
}

// ---------------------------------------------------------------- launch
extern "C" void kernel_launch(void* const* d_in, const int* in_sizes, int n_in,
                              void* d_out, int out_size, void* d_ws, size_t ws_size,
                              hipStream_t stream) {
  const float* s_j  = (const float*)d_in[0];
  const float* v_j  = (const float*)d_in[1];
  const float* r_ij = (const float*)d_in[2];
  const int*   nbrs = (const int*)d_in[3];
  const float* W1   = (const float*)d_in[5];
  const float* b1   = (const float*)d_in[6];
  const float* W2   = (const float*)d_in[7];
  const float* b2   = (const float*)d_in[8];
  const float* Wr   = (const float*)d_in[9];
  const float* br   = (const float*)d_in[10];
  const float* Wd   = (const float*)d_in[11];
  const float* bd   = (const float*)d_in[12];

  float* out_s = (float*)d_out;
  float* out_v = out_s + (size_t)NATOMS * FEAT;

  // workspace: ~22.9 MB (<= 26.4 MB proven). Sort buffers alias dead h_bf.
  float*    Qf   = (float*)d_ws;                         // 8192*128 f32    (4 MB)
  ushort_t* kvbf = (ushort_t*)(Qf + NATOMS * FEAT);      // 8192*256 bf16   (4 MB)
  ushort_t* PV   = kvbf + (size_t)NATOMS * 256;          // 2 x 6.29 MB split tables
  ushort_t* w1s  = PV + 2 * TABUS;                       // 16384
  ushort_t* w2s  = w1s + 16384;                          // 49152
  ushort_t* wds  = w2s + 49152;                          // 49152
  ushort_t* wrs  = wds + 49152;                          // 12288 (own region now)
  ushort_t* h_bf = wrs + 12288;                          // 2 MB (dead after gemm2)
  int* sorted = (int*)h_bf;                              // 1 MB
  int* offs   = sorted + NEDGES;
  int* cursor = offs + (NATOMS + 1);
  int* counts = cursor + NATOMS;

  int prep_total = NATOMS * FEAT + 16384 + 49152 + 49152 + 12288;
  prep_kernel<<<(prep_total + 255) / 256, 256, 0, stream>>>(
      v_j, W1, W2, Wd, Wr, br, PV, w1s, w2s, wds, wrs);

  gemm_mfma<<<dim3(NATOMS / 64, 2), 256, 0, stream>>>(
      s_j, 1, w1s, b1, 128, 8, 1, 1, h_bf, nullptr);
  gemm_mfma<<<dim3(NATOMS / 64, 6), 256, 0, stream>>>(
      h_bf, 0, w2s, b2, 384, 24, 0, 2, PV, nullptr);

  hipMemsetAsync(counts, 0, NATOMS * sizeof(int), stream);
  hist_kernel<<<NEDGES / 256, 256, 0, stream>>>(nbrs, counts);
  scan_kernel<<<1, 1024, 0, stream>>>(counts, offs, cursor);
  scatter_kernel<<<NEDGES / 256, 256, 0, stream>>>(nbrs, cursor, sorted);

  gemm_mfma<<<dim3(NATOMS / 64, 6), 256, 0, stream>>>(
      s_j, 1, wds, bd, 384, 24, 0, 3, Qf, kvbf);

  edge_mfma6<<<NATOMS / 2, 256, 0, stream>>>(sorted, offs, nbrs, r_ij, PV,
                                             wrs, out_s, out_v);
  attn_kernel<<<NGRAPH * 2, 256, 0, stream>>>(Qf, kvbf, out_s);
}

// Round 11
// 146.592 us; speedup vs baseline: 1.5154x; 1.1007x over previous
//
#include <hip/hip_runtime.h>
#include <hip/hip_bf16.h>
#include <cstdint>

#define FEAT    128
#define NRBF    20
#define NATOMS  8192
#define NEDGES  262144
#define NGRAPH  128
#define APG     64
#define PI_F    3.14159265358979323846f
#define CUTOFF_F 5.0f
#define QTUS    ((size_t)NATOMS * 32 * 6)   // ushorts per PV quarter-table (3.15 MB)

typedef unsigned int uint_t;
typedef unsigned short ushort_t;
typedef __attribute__((ext_vector_type(4))) float f32x4;
typedef __attribute__((ext_vector_type(4))) short short4v;
typedef __attribute__((ext_vector_type(8))) short short8;
struct U3 { uint_t x, y, z; };   // 12 B -> global_load_dwordx3

__device__ __forceinline__ float bflo(uint_t u) { return __uint_as_float(u << 16); }
__device__ __forceinline__ float bfhi(uint_t u) { return __uint_as_float(u & 0xffff0000u); }
__device__ __forceinline__ float bfus(ushort_t u) { return __uint_as_float((uint_t)u << 16); }
__device__ __forceinline__ ushort_t f2bf(float f) {
  uint_t u = __float_as_uint(f);
  return (ushort_t)((u + 0x7fffu + ((u >> 16) & 1u)) >> 16);
}
__device__ __forceinline__ uint_t pack2(float lo, float hi) {
  return (uint_t)f2bf(lo) | ((uint_t)f2bf(hi) << 16);
}

// ---------------------------------------------------------------- prep
// PV record per (j,f): 6 ushorts {p0,p1,p2,v0,v1,v2}, 12 B stride, split into FOUR
// quarter-tables by f>>5 (3.15 MB each -> single-quarter blocks are L2-capacity-fit).
// prep writes full records (P slots zeroed; gemm2 scatters P later) + all swizzled weights.
__device__ __forceinline__ ushort_t swz_elem(const float* __restrict__ W, int N,
                                             int NT, int i) {
  int jj = i & 7, lane = (i >> 3) & 63, tile = i >> 9;
  int ks = tile / NT, ctg = tile - ks * NT;
  int g = lane >> 4, q = lane & 15;
  int k = 32 * ks + 4 * g + (jj & 3) + 16 * (jj >> 2);
  int c = 16 * ctg + q;
  return f2bf(W[(size_t)k * N + c]);
}

__global__ void prep_kernel(const float* __restrict__ v_j, const float* __restrict__ W1,
                            const float* __restrict__ W2, const float* __restrict__ Wd,
                            const float* __restrict__ Wr, const float* __restrict__ br,
                            ushort_t* __restrict__ PV, ushort_t* __restrict__ w1s,
                            ushort_t* __restrict__ w2s, ushort_t* __restrict__ wds,
                            ushort_t* __restrict__ wrs) {
  int i = blockIdx.x * 256 + threadIdx.x;
  if (i < NATOMS * FEAT) {                 // i = j*128 + f
    int j = i >> 7, f = i & 127;
    int tbl = f >> 5, fl = f & 31;
    const float* vp = v_j + (size_t)i * 3; // v_j[j][f][0..2]
    uint_t* o = reinterpret_cast<uint_t*>(PV + (size_t)tbl * QTUS + ((size_t)j * 32 + fl) * 6);
    o[0] = 0u;                     // p0,p1 (gemm2 fills)
    o[1] = pack2(0.f, vp[0]);      // p2,v0
    o[2] = pack2(vp[1], vp[2]);    // v1,v2
    return;
  }
  i -= NATOMS * FEAT;
  if (i < 16384) { w1s[i] = swz_elem(W1, 128, 8, i); return; }
  i -= 16384;
  if (i < 49152) { w2s[i] = swz_elem(W2, 384, 24, i); return; }
  i -= 49152;
  if (i < 49152) { wds[i] = swz_elem(Wd, 384, 24, i); return; }
  i -= 49152;
  if (i < 12288) {                 // Wr/br frag-order: 24 tiles, k=20 row is br
    int jj = i & 7, lane = (i >> 3) & 63, ct = i >> 9;
    int g = lane >> 4, q = lane & 15;
    int k = 4 * g + (jj & 3) + 16 * (jj >> 2);
    int f = 16 * ct + q;
    float v = (k < NRBF) ? Wr[k * 384 + f] : (k == NRBF ? br[f] : 0.f);
    wrs[i] = f2bf(v);
  }
}

// ---------------------------------------------------------------- MFMA GEMM
// omode: 1 = bf16 row out (p0), 2 = PV P-slots (quarter-table scatter),
// 3 = qkv-split (p0 Qf f32, p1 kv bf16).
__global__ __launch_bounds__(256) void gemm_mfma(
    const void* __restrict__ Asrc, int a_f32, const ushort_t* __restrict__ Wswz,
    const float* __restrict__ bias, int N, int NT, int silu, int omode,
    void* __restrict__ p0, void* __restrict__ p1) {
  __shared__ ushort_t As[64][136];
  const int t = threadIdx.x;
  const int r0 = blockIdx.x * 64, c0 = blockIdx.y * 64;
  const int w = t >> 6, l = t & 63, g = l >> 4, q = l & 15;

  short8 bf[4][4];
  #pragma unroll
  for (int ks = 0; ks < 4; ++ks)
    #pragma unroll
    for (int ct = 0; ct < 4; ++ct)
      bf[ks][ct] = *reinterpret_cast<const short8*>(
          Wswz + ((size_t)(ks * NT + (c0 >> 4) + ct) * 64 + l) * 8);

  if (a_f32) {
    const float* Af = (const float*)Asrc;
    for (int i = t; i < 64 * 32; i += 256) {
      int r = i >> 5, k4 = i & 31;
      float4 v = *reinterpret_cast<const float4*>(Af + (size_t)(r0 + r) * 128 + 4 * k4);
      ushort4 o = {f2bf(v.x), f2bf(v.y), f2bf(v.z), f2bf(v.w)};
      *reinterpret_cast<ushort4*>(&As[r][4 * k4]) = o;
    }
  } else {
    const ushort_t* Ab = (const ushort_t*)Asrc;
    for (int i = t; i < 64 * 16; i += 256) {
      int r = i >> 4, g8 = i & 15;
      short8 v = *reinterpret_cast<const short8*>(Ab + (size_t)(r0 + r) * 128 + 8 * g8);
      *reinterpret_cast<short8*>(&As[r][8 * g8]) = v;
    }
  }
  __syncthreads();

  f32x4 acc[4] = {};
  #pragma unroll
  for (int ks = 0; ks < 4; ++ks) {
    const ushort_t* ap = &As[16 * w + q][32 * ks + 4 * g];
    short4v alo = *reinterpret_cast<const short4v*>(ap);
    short4v ahi = *reinterpret_cast<const short4v*>(ap + 16);
    short8 af;
    af[0] = alo[0]; af[1] = alo[1]; af[2] = alo[2]; af[3] = alo[3];
    af[4] = ahi[0]; af[5] = ahi[1]; af[6] = ahi[2]; af[7] = ahi[3];
    #pragma unroll
    for (int ct = 0; ct < 4; ++ct)
      acc[ct] = __builtin_amdgcn_mfma_f32_16x16x32_bf16(af, bf[ks][ct], acc[ct], 0, 0, 0);
  }

  #pragma unroll
  for (int ct = 0; ct < 4; ++ct) {
    int col = c0 + 16 * ct + q;
    float bb = bias[col];
    #pragma unroll
    for (int r = 0; r < 4; ++r) {
      float o = acc[ct][r] + bb;
      if (silu) o = o / (1.f + __expf(-o));
      int row = r0 + 16 * w + 4 * g + r;
      if (omode == 1) {
        ((ushort_t*)p0)[(size_t)row * N + col] = f2bf(o);
      } else if (omode == 2) {
        int f = col & 127, s = col >> 7;
        int tbl = f >> 5, fl = f & 31;
        ((ushort_t*)p0)[(size_t)tbl * QTUS + ((size_t)row * 32 + fl) * 6 + s] = f2bf(o);
      } else {
        if (col < 128) ((float*)p0)[(size_t)row * 128 + col] = o;
        else           ((ushort_t*)p1)[(size_t)row * 256 + col - 128] = f2bf(o);
      }
    }
  }
}

// ---------------------------------------------------------------- sort helpers
__global__ void hist_kernel(const int* __restrict__ nbrs, int* __restrict__ counts) {
  int e = blockIdx.x * blockDim.x + threadIdx.x;
  if (e < NEDGES) atomicAdd(&counts[nbrs[2 * e]], 1);
}

__global__ __launch_bounds__(1024) void scan_kernel(
    const int* __restrict__ counts, int* __restrict__ offs, int* __restrict__ cursor) {
  __shared__ int part[1024];
  const int t = threadIdx.x;
  int local[8];
  int s = 0;
  #pragma unroll
  for (int i = 0; i < 8; ++i) { local[i] = counts[t * 8 + i]; s += local[i]; }
  part[t] = s;
  __syncthreads();
  for (int off = 1; off < 1024; off <<= 1) {
    int v = part[t];
    int add = (t >= off) ? part[t - off] : 0;
    __syncthreads();
    part[t] = v + add;
    __syncthreads();
  }
  int excl = part[t] - s;
  #pragma unroll
  for (int i = 0; i < 8; ++i) {
    offs[t * 8 + i] = excl;
    cursor[t * 8 + i] = excl;
    excl += local[i];
  }
  if (t == 1023) offs[NATOMS] = excl;
}

// Pre-joined 16 B edge records {j, x, y, z} in sorted (dest-atom) order:
// edge kernel metadata becomes ONE dwordx4 load (no dependent-gather chain).
__global__ void scatter_kernel(const int* __restrict__ nbrs, const float* __restrict__ r_ij,
                               int* __restrict__ cursor, uint4* __restrict__ erec) {
  int e = blockIdx.x * blockDim.x + threadIdx.x;
  if (e < NEDGES) {
    int2 nb = *reinterpret_cast<const int2*>(nbrs + 2 * e);
    int pos = atomicAdd(&cursor[nb.x], 1);
    const float* rp = r_ij + 3 * e;
    erec[pos] = make_uint4((uint_t)nb.y, __float_as_uint(rp[0]),
                           __float_as_uint(rp[1]), __float_as_uint(rp[2]));
  }
}

// ---------------------------------------------------------------- edge MFMA v7
// Single-QUARTER blocks: qtr = blockIdx.x & 3; with bid%8 XCD round-robin each XCD
// touches exactly one 3.15 MB quarter-table -> L2-capacity-fit gathers.
// Wave = (atom, quarter): per 16-edge tile ONE prefetched erec load, 8 dwordx3 PV
// gathers, 8 sinf, 6 MFMAs (2 ct x 3 sections). C map HW-verified: row=4g+reg, col=q.
__global__ __launch_bounds__(256) void edge_mfma7(
    const uint4* __restrict__ erec, const int* __restrict__ offs,
    const ushort_t* __restrict__ PV, const ushort_t* __restrict__ wrs,
    float* __restrict__ out_s, float* __restrict__ out_v) {
  __shared__ short8 sW[6 * 64];   // 6144 B: this quarter's 6 tiles (3 sec x 2 ct)
  const int t = threadIdx.x;
  const int qtr = blockIdx.x & 3;
  for (int i = t; i < 6 * 64; i += 256) {
    int tl = i >> 6, l2 = i & 63;
    int s = tl >> 1, c = tl & 1;
    sW[i] = *reinterpret_cast<const short8*>(
        wrs + ((size_t)(s * 8 + 2 * qtr + c) * 64 + l2) * 8);
  }
  __syncthreads();

  const int w = t >> 6, l = t & 63, g = l >> 4, q = l & 15;
  const int atom = (blockIdx.x >> 2) * 4 + w;
  const int start = offs[atom], end = offs[atom + 1];
  const float c1 = PI_F / CUTOFF_F;
  const char* PVb = reinterpret_cast<const char*>(PV) + (size_t)qtr * QTUS * 2;

  float ds[2] = {};
  float dv[2][3] = {};

  uint4 er = make_uint4(0u, 0u, 0u, 0u);
  if (start + q < end) er = erec[start + q];

  for (int eb = start; eb < end; eb += 16) {
    // ---- prefetch next tile's record (independent of this tile's compute)
    uint4 ern = make_uint4(0u, 0u, 0u, 0u);
    if (eb + 16 + q < end) ern = erec[eb + 16 + q];
    // ---- metadata from the pre-joined record (lane q owns edge eb+q)
    float ang = 0.f, ie = 0.f, env = 0.f, u0 = 0.f, u1 = 0.f, u2 = 0.f;
    int jn = 0;
    if (eb + q < end) {
      jn = (int)er.x;
      float x = __uint_as_float(er.y), y = __uint_as_float(er.z), z = __uint_as_float(er.w);
      float d = sqrtf(x * x + y * y + z * z);
      float inv = 1.f / d;
      ang = c1 * d;
      env = (d < CUTOFF_F) ? 0.5f * (__cosf(ang) + 1.f) : 0.f;
      ie = inv * env;
      u0 = x * inv; u1 = y * inv; u2 = z * inv;
    }
    // ---- row (edge eb+4g+r) metadata broadcast + base pointers
    const char* pb[4];
    float ub[4][3];
    #pragma unroll
    for (int r = 0; r < 4; ++r) {
      int src = 4 * g + r;
      int jr = __shfl(jn, src, 64);
      ub[r][0] = __shfl(u0, src, 64);
      ub[r][1] = __shfl(u1, src, 64);
      ub[r][2] = __shfl(u2, src, 64);
      pb[r] = PVb + (size_t)jr * 384 + (size_t)q * 12;
    }
    // ---- issue the 8 PV gathers (12 B each) up front
    U3 ld[2][4];
    #pragma unroll
    for (int c = 0; c < 2; ++c)
      #pragma unroll
      for (int r = 0; r < 4; ++r)
        ld[c][r] = *reinterpret_cast<const U3*>(pb[r] + (size_t)c * 192);
    // ---- A fragment: k = kmap(g,jj) = 4g+(jj&3)+16*(jj>>2)
    short8 af;
    #pragma unroll
    for (int jj = 0; jj < 8; ++jj) {
      int k = 4 * g + (jj & 3) + 16 * (jj >> 2);
      float v = (k < NRBF) ? ie * __sinf((float)(k + 1) * ang)
                           : (k == NRBF ? env : 0.f);
      af[jj] = (short)f2bf(v);
    }
    // ---- 2 col-tiles x 3 sections
    #pragma unroll
    for (int c = 0; c < 2; ++c) {
      short8 b0 = sW[(0 * 2 + c) * 64 + l];
      short8 b1 = sW[(1 * 2 + c) * 64 + l];
      short8 b2 = sW[(2 * 2 + c) * 64 + l];
      f32x4 z4 = {0.f, 0.f, 0.f, 0.f};
      f32x4 cs0 = __builtin_amdgcn_mfma_f32_16x16x32_bf16(af, b0, z4, 0, 0, 0);
      f32x4 cs1 = __builtin_amdgcn_mfma_f32_16x16x32_bf16(af, b1, z4, 0, 0, 0);
      f32x4 cs2 = __builtin_amdgcn_mfma_f32_16x16x32_bf16(af, b2, z4, 0, 0, 0);
      #pragma unroll
      for (int r = 0; r < 4; ++r) {
        U3 u = ld[c][r];
        float p0 = bflo(u.x), p1 = bfhi(u.x);
        float p2 = bflo(u.y), v0 = bfhi(u.y);
        float v1 = bflo(u.z), v2 = bfhi(u.z);
        float pw0 = p0 * cs0[r];
        ds[c] += p1 * cs1[r];
        float pw2 = p2 * cs2[r];
        dv[c][0] += pw0 * v0 + pw2 * ub[r][0];
        dv[c][1] += pw0 * v1 + pw2 * ub[r][1];
        dv[c][2] += pw0 * v2 + pw2 * ub[r][2];
      }
    }
    er = ern;
  }

  // ---- reduce the 4 g-copies (all lanes participate)
  #pragma unroll
  for (int c = 0; c < 2; ++c) {
    float x = ds[c];
    x += __shfl_xor(x, 16, 64); x += __shfl_xor(x, 32, 64);
    ds[c] = x;
    #pragma unroll
    for (int cc = 0; cc < 3; ++cc) {
      float y = dv[c][cc];
      y += __shfl_xor(y, 16, 64); y += __shfl_xor(y, 32, 64);
      dv[c][cc] = y;
    }
  }
  // ---- write: lanes g<2 write feature f = 32*qtr + 16*g + q
  if (g < 2) {
    float sv = (g == 0) ? ds[0] : ds[1];
    float d0 = (g == 0) ? dv[0][0] : dv[1][0];
    float d1 = (g == 0) ? dv[0][1] : dv[1][1];
    float d2 = (g == 0) ? dv[0][2] : dv[1][2];
    int f = 32 * qtr + 16 * g + q;
    out_s[(size_t)atom * FEAT + f] = sv;
    float* ov = out_v + (size_t)atom * 384 + (size_t)f * 3;
    ov[0] = d0; ov[1] = d1; ov[2] = d2;
  }
}

// ---------------------------------------------------------------- attention
__device__ __forceinline__ float wave_max64(float v) {
  #pragma unroll
  for (int m = 32; m > 0; m >>= 1) v = fmaxf(v, __shfl_xor(v, m, 64));
  return v;
}
__device__ __forceinline__ float wave_sum64(float v) {
  #pragma unroll
  for (int m = 32; m > 0; m >>= 1) v += __shfl_xor(v, m, 64);
  return v;
}

__global__ __launch_bounds__(256) void attn_kernel(const float* __restrict__ Qf,
                                                   const ushort_t* __restrict__ kvbf,
                                                   float* __restrict__ out_s) {
  __shared__ float4 Ks4[64 * 32];
  __shared__ float  Vs[64][130];
  __shared__ float  Ps[4][4][64];
  const int b = blockIdx.x >> 1, half = blockIdx.x & 1;
  const int t = threadIdx.x;
  const float* qbase = Qf + (size_t)b * APG * 128;
  const ushort_t* kvb = kvbf + (size_t)b * APG * 256;

  for (int i = t; i < 64 * 32; i += 256) {
    int a = i >> 5, gg = i & 31;
    ushort4 k4 = *reinterpret_cast<const ushort4*>(kvb + a * 256 + 4 * gg);
    float4 kf = {bfus(k4.x), bfus(k4.y), bfus(k4.z), bfus(k4.w)};
    Ks4[a * 32 + (gg ^ (a & 7))] = kf;
  }
  for (int i = t; i < 64 * 32; i += 256) {
    int a = i >> 5, gg = i & 31;
    ushort4 v4 = *reinterpret_cast<const ushort4*>(kvb + a * 256 + 128 + 4 * gg);
    Vs[a][4 * gg + 0] = bfus(v4.x); Vs[a][4 * gg + 1] = bfus(v4.y);
    Vs[a][4 * gg + 2] = bfus(v4.z); Vs[a][4 * gg + 3] = bfus(v4.w);
  }
  __syncthreads();

  const int w = t >> 6, l = t & 63;
  const float scale = 0.08838834764831845f;

  for (int qq = 8 * half + w; qq < 8 * half + 8; qq += 4) {
    const float* q0p = qbase + (size_t)(4 * qq + 0) * 128;
    const float* q1p = qbase + (size_t)(4 * qq + 1) * 128;
    const float* q2p = qbase + (size_t)(4 * qq + 2) * 128;
    const float* q3p = qbase + (size_t)(4 * qq + 3) * 128;
    float s0 = 0.f, s1 = 0.f, s2 = 0.f, s3 = 0.f;
    #pragma unroll 8
    for (int i = 0; i < 32; ++i) {
      float4 k = Ks4[l * 32 + (i ^ (l & 7))];
      float4 q0 = *reinterpret_cast<const float4*>(q0p + 4 * i);
      float4 q1 = *reinterpret_cast<const float4*>(q1p + 4 * i);
      float4 q2 = *reinterpret_cast<const float4*>(q2p + 4 * i);
      float4 q3 = *reinterpret_cast<const float4*>(q3p + 4 * i);
      s0 += q0.x * k.x + q0.y * k.y + q0.z * k.z + q0.w * k.w;
      s1 += q1.x * k.x + q1.y * k.y + q1.z * k.z + q1.w * k.w;
      s2 += q2.x * k.x + q2.y * k.y + q2.z * k.z + q2.w * k.w;
      s3 += q3.x * k.x + q3.y * k.y + q3.z * k.z + q3.w * k.w;
    }
    s0 *= scale; s1 *= scale; s2 *= scale; s3 *= scale;

    float p0 = __expf(s0 - wave_max64(s0));
    float p1 = __expf(s1 - wave_max64(s1));
    float p2 = __expf(s2 - wave_max64(s2));
    float p3 = __expf(s3 - wave_max64(s3));
    p0 /= wave_sum64(p0); p1 /= wave_sum64(p1);
    p2 /= wave_sum64(p2); p3 /= wave_sum64(p3);

    Ps[w][0][l] = p0; Ps[w][1][l] = p1; Ps[w][2][l] = p2; Ps[w][3][l] = p3;
    __threadfence_block();

    float a00 = 0.f, a01 = 0.f, a10 = 0.f, a11 = 0.f;
    float a20 = 0.f, a21 = 0.f, a30 = 0.f, a31 = 0.f;
    for (int a = 0; a < 64; ++a) {
      float2 v = *reinterpret_cast<const float2*>(&Vs[a][2 * l]);
      float pa0 = Ps[w][0][a], pa1 = Ps[w][1][a];
      float pa2 = Ps[w][2][a], pa3 = Ps[w][3][a];
      a00 += pa0 * v.x; a01 += pa0 * v.y;
      a10 += pa1 * v.x; a11 += pa1 * v.y;
      a20 += pa2 * v.x; a21 += pa2 * v.y;
      a30 += pa3 * v.x; a31 += pa3 * v.y;
    }
    size_t row0 = (size_t)(b * APG + 4 * qq) * FEAT + 2 * l;
    float2* o0 = reinterpret_cast<float2*>(out_s + row0);
    float2* o1 = reinterpret_cast<float2*>(out_s + row0 + FEAT);
    float2* o2 = reinterpret_cast<float2*>(out_s + row0 + 2 * FEAT);
    float2* o3 = reinterpret_cast<float2*>(out_s + row0 + 3 * FEAT);
    float2 c0 = *o0; c0.x += a00; c0.y += a01; *o0 = c0;
    float2 c1 = *o1; c1.x += a10; c1.y += a11; *o1 = c1;
    float2 c2 = *o2; c2.x += a20; c2.y += a21; *o2 = c2;
    float2 c3 = *o3; c3.x += a30; c3.y += a31; *o3 = c3;
    __threadfence_block();
  }
}

// ---------------------------------------------------------------- launch
extern "C" void kernel_launch(void* const* d_in, const int* in_sizes, int n_in,
                              void* d_out, int out_size, void* d_ws, size_t ws_size,
                              hipStream_t stream) {
  const float* s_j  = (const float*)d_in[0];
  const float* v_j  = (const float*)d_in[1];
  const float* r_ij = (const float*)d_in[2];
  const int*   nbrs = (const int*)d_in[3];
  const float* W1   = (const float*)d_in[5];
  const float* b1   = (const float*)d_in[6];
  const float* W2   = (const float*)d_in[7];
  const float* b2   = (const float*)d_in[8];
  const float* Wr   = (const float*)d_in[9];
  const float* br   = (const float*)d_in[10];
  const float* Wd   = (const float*)d_in[11];
  const float* bd   = (const float*)d_in[12];

  float* out_s = (float*)d_out;
  float* out_v = out_s + (size_t)NATOMS * FEAT;

  // workspace ~25.5 MB (<= 26.4 proven). erec (4 MB) aliases dead h_bf region.
  float*    Qf   = (float*)d_ws;                         // 4 MB
  ushort_t* kvbf = (ushort_t*)(Qf + NATOMS * FEAT);      // 4 MB
  ushort_t* PV   = kvbf + (size_t)NATOMS * 256;          // 4 x 3.15 MB quarter tables
  ushort_t* w1s  = PV + 4 * QTUS;                        // 16384
  ushort_t* w2s  = w1s + 16384;                          // 49152
  ushort_t* wds  = w2s + 49152;                          // 49152
  ushort_t* wrs  = wds + 49152;                          // 12288
  ushort_t* h_bf = wrs + 12288;                          // 2 MB (dead after gemm2)
  uint4*    erec = (uint4*)h_bf;                         // 4 MB (after gemm2)
  int* offs   = (int*)((char*)h_bf + 4194304);           // NATOMS+1
  int* cursor = offs + (NATOMS + 1);
  int* counts = cursor + NATOMS;

  int prep_total = NATOMS * FEAT + 16384 + 49152 + 49152 + 12288;
  prep_kernel<<<(prep_total + 255) / 256, 256, 0, stream>>>(
      v_j, W1, W2, Wd, Wr, br, PV, w1s, w2s, wds, wrs);

  gemm_mfma<<<dim3(NATOMS / 64, 2), 256, 0, stream>>>(
      s_j, 1, w1s, b1, 128, 8, 1, 1, h_bf, nullptr);
  gemm_mfma<<<dim3(NATOMS / 64, 6), 256, 0, stream>>>(
      h_bf, 0, w2s, b2, 384, 24, 0, 2, PV, nullptr);

  hipMemsetAsync(counts, 0, NATOMS * sizeof(int), stream);
  hist_kernel<<<NEDGES / 256, 256, 0, stream>>>(nbrs, counts);
  scan_kernel<<<1, 1024, 0, stream>>>(counts, offs, cursor);
  scatter_kernel<<<NEDGES / 256, 256, 0, stream>>>(nbrs, r_ij, cursor, erec);

  gemm_mfma<<<dim3(NATOMS / 64, 6), 256, 0, stream>>>(
      s_j, 1, wds, bd, 384, 24, 0, 3, Qf, kvbf);

  edge_mfma7<<<NATOMS, 256, 0, stream>>>(erec, offs, PV, wrs, out_s, out_v);
  attn_kernel<<<NGRAPH * 2, 256, 0, stream>>>(Qf, kvbf, out_s);
}

// Round 13
// 141.487 us; speedup vs baseline: 1.5701x; 1.0361x over previous
//
#include <hip/hip_runtime.h>
#include <hip/hip_bf16.h>
#include <cstdint>

#define FEAT    128
#define NRBF    20
#define NATOMS  8192
#define NEDGES  262144
#define NGRAPH  128
#define APG     64
#define PI_F    3.14159265358979323846f
#define CUTOFF_F 5.0f
#define QTUS    ((size_t)NATOMS * 32 * 6)   // ushorts per PV quarter-table (3.15 MB)
#define APW     8                           // atoms per wave (edge kernel)

typedef unsigned int uint_t;
typedef unsigned short ushort_t;
typedef __attribute__((ext_vector_type(4))) float f32x4;
typedef __attribute__((ext_vector_type(4))) short short4v;
typedef __attribute__((ext_vector_type(8))) short short8;
struct U3 { uint_t x, y, z; };   // 12 B -> global_load_dwordx3

__device__ __forceinline__ float bflo(uint_t u) { return __uint_as_float(u << 16); }
__device__ __forceinline__ float bfhi(uint_t u) { return __uint_as_float(u & 0xffff0000u); }
__device__ __forceinline__ float bfus(ushort_t u) { return __uint_as_float((uint_t)u << 16); }
__device__ __forceinline__ ushort_t f2bf(float f) {
  uint_t u = __float_as_uint(f);
  return (ushort_t)((u + 0x7fffu + ((u >> 16) & 1u)) >> 16);
}
__device__ __forceinline__ uint_t pack2(float lo, float hi) {
  return (uint_t)f2bf(lo) | ((uint_t)f2bf(hi) << 16);
}

// ---------------------------------------------------------------- prep
// PV record per (j,f): 6 ushorts {p0,p1,p2,v0,v1,v2}, 12 B stride, split into FOUR
// quarter-tables by f>>5 (3.15 MB each -> single-quarter blocks are L2-capacity-fit).
// prep writes full records (P slots zeroed; fused gemm scatters P later) + swizzled weights.
__device__ __forceinline__ ushort_t swz_elem(const float* __restrict__ W, int N,
                                             int NT, int i) {
  int jj = i & 7, lane = (i >> 3) & 63, tile = i >> 9;
  int ks = tile / NT, ctg = tile - ks * NT;
  int g = lane >> 4, q = lane & 15;
  int k = 32 * ks + 4 * g + (jj & 3) + 16 * (jj >> 2);
  int c = 16 * ctg + q;
  return f2bf(W[(size_t)k * N + c]);
}

__global__ void prep_kernel(const float* __restrict__ v_j, const float* __restrict__ W1,
                            const float* __restrict__ W2, const float* __restrict__ Wd,
                            const float* __restrict__ Wr, const float* __restrict__ br,
                            ushort_t* __restrict__ PV, ushort_t* __restrict__ w1s,
                            ushort_t* __restrict__ w2s, ushort_t* __restrict__ wds,
                            ushort_t* __restrict__ wrs) {
  int i = blockIdx.x * 256 + threadIdx.x;
  if (i < NATOMS * FEAT) {                 // i = j*128 + f
    int j = i >> 7, f = i & 127;
    int tbl = f >> 5, fl = f & 31;
    const float* vp = v_j + (size_t)i * 3; // v_j[j][f][0..2]
    uint_t* o = reinterpret_cast<uint_t*>(PV + (size_t)tbl * QTUS + ((size_t)j * 32 + fl) * 6);
    o[0] = 0u;                     // p0,p1 (gemm fills)
    o[1] = pack2(0.f, vp[0]);      // p2,v0
    o[2] = pack2(vp[1], vp[2]);    // v1,v2
    return;
  }
  i -= NATOMS * FEAT;
  if (i < 16384) { w1s[i] = swz_elem(W1, 128, 8, i); return; }
  i -= 16384;
  if (i < 49152) { w2s[i] = swz_elem(W2, 384, 24, i); return; }
  i -= 49152;
  if (i < 49152) { wds[i] = swz_elem(Wd, 384, 24, i); return; }
  i -= 49152;
  if (i < 12288) {                 // Wr/br frag-order: 24 tiles, k=20 row is br
    int jj = i & 7, lane = (i >> 3) & 63, ct = i >> 9;
    int g = lane >> 4, q = lane & 15;
    int k = 4 * g + (jj & 3) + 16 * (jj >> 2);
    int f = 16 * ct + q;
    float v = (k < NRBF) ? Wr[k * 384 + f] : (k == NRBF ? br[f] : 0.f);
    wrs[i] = f2bf(v);
  }
}

// ---------------------------------------------------------------- fused GEMM1+2
// One block = 64 rows. Stage 1: h = silu(s_j@W1+b1) -> LDS (never leaves block).
// Stage 2: phi = h@W2+b2 -> scattered into PV P-slots (quarter-table layout).
// Fragment maps HW-verified (rounds 3-11).
__global__ __launch_bounds__(256) void gemm_fused12(
    const float* __restrict__ s_j, const ushort_t* __restrict__ w1s,
    const float* __restrict__ b1, const ushort_t* __restrict__ w2s,
    const float* __restrict__ b2, ushort_t* __restrict__ PV) {
  __shared__ ushort_t As[64][136];
  __shared__ ushort_t Hs[64][136];
  const int t = threadIdx.x;
  const int r0 = blockIdx.x * 64;
  const int w = t >> 6, l = t & 63, g = l >> 4, q = l & 15;

  for (int i = t; i < 64 * 32; i += 256) {
    int r = i >> 5, k4 = i & 31;
    float4 v = *reinterpret_cast<const float4*>(s_j + (size_t)(r0 + r) * 128 + 4 * k4);
    ushort4 o = {f2bf(v.x), f2bf(v.y), f2bf(v.z), f2bf(v.w)};
    *reinterpret_cast<ushort4*>(&As[r][4 * k4]) = o;
  }
  __syncthreads();

  // ---- stage 1: wave computes 16 rows x 128 cols of h
  short8 afr[4];
  #pragma unroll
  for (int ks = 0; ks < 4; ++ks) {
    const ushort_t* ap = &As[16 * w + q][32 * ks + 4 * g];
    short4v alo = *reinterpret_cast<const short4v*>(ap);
    short4v ahi = *reinterpret_cast<const short4v*>(ap + 16);
    afr[ks] = short8{alo[0], alo[1], alo[2], alo[3], ahi[0], ahi[1], ahi[2], ahi[3]};
  }
  #pragma unroll
  for (int ct = 0; ct < 8; ++ct) {
    f32x4 acc = {};
    #pragma unroll
    for (int ks = 0; ks < 4; ++ks) {
      short8 bf = *reinterpret_cast<const short8*>(
          w1s + ((size_t)(ks * 8 + ct) * 64 + l) * 8);
      acc = __builtin_amdgcn_mfma_f32_16x16x32_bf16(afr[ks], bf, acc, 0, 0, 0);
    }
    float bb = b1[16 * ct + q];
    #pragma unroll
    for (int r = 0; r < 4; ++r) {
      float o = acc[r] + bb;
      o = o / (1.f + __expf(-o));
      Hs[16 * w + 4 * g + r][16 * ct + q] = f2bf(o);
    }
  }
  __syncthreads();

  // ---- stage 2: wave computes 16 rows x 384 cols of phi from Hs
  short8 hfr[4];
  #pragma unroll
  for (int ks = 0; ks < 4; ++ks) {
    const ushort_t* ap = &Hs[16 * w + q][32 * ks + 4 * g];
    short4v alo = *reinterpret_cast<const short4v*>(ap);
    short4v ahi = *reinterpret_cast<const short4v*>(ap + 16);
    hfr[ks] = short8{alo[0], alo[1], alo[2], alo[3], ahi[0], ahi[1], ahi[2], ahi[3]};
  }
  for (int cb = 0; cb < 6; ++cb) {
    #pragma unroll
    for (int ct = 0; ct < 4; ++ct) {
      f32x4 acc = {};
      #pragma unroll
      for (int ks = 0; ks < 4; ++ks) {
        short8 bf = *reinterpret_cast<const short8*>(
            w2s + ((size_t)(ks * 24 + cb * 4 + ct) * 64 + l) * 8);
        acc = __builtin_amdgcn_mfma_f32_16x16x32_bf16(hfr[ks], bf, acc, 0, 0, 0);
      }
      int col = cb * 64 + 16 * ct + q;
      float bb = b2[col];
      int f = col & 127, s = col >> 7;
      int tbl = f >> 5, fl = f & 31;
      #pragma unroll
      for (int r = 0; r < 4; ++r) {
        float o = acc[r] + bb;
        int row = r0 + 16 * w + 4 * g + r;
        PV[(size_t)tbl * QTUS + ((size_t)row * 32 + fl) * 6 + s] = f2bf(o);
      }
    }
  }
}

// ---------------------------------------------------------------- MFMA GEMM (qkv)
// omode 3 = qkv-split (p0 Qf f32, p1 kv bf16)
__global__ __launch_bounds__(256) void gemm_mfma(
    const void* __restrict__ Asrc, int a_f32, const ushort_t* __restrict__ Wswz,
    const float* __restrict__ bias, int N, int NT, int silu, int omode,
    void* __restrict__ p0, void* __restrict__ p1) {
  __shared__ ushort_t As[64][136];
  const int t = threadIdx.x;
  const int r0 = blockIdx.x * 64, c0 = blockIdx.y * 64;
  const int w = t >> 6, l = t & 63, g = l >> 4, q = l & 15;

  short8 bf[4][4];
  #pragma unroll
  for (int ks = 0; ks < 4; ++ks)
    #pragma unroll
    for (int ct = 0; ct < 4; ++ct)
      bf[ks][ct] = *reinterpret_cast<const short8*>(
          Wswz + ((size_t)(ks * NT + (c0 >> 4) + ct) * 64 + l) * 8);

  if (a_f32) {
    const float* Af = (const float*)Asrc;
    for (int i = t; i < 64 * 32; i += 256) {
      int r = i >> 5, k4 = i & 31;
      float4 v = *reinterpret_cast<const float4*>(Af + (size_t)(r0 + r) * 128 + 4 * k4);
      ushort4 o = {f2bf(v.x), f2bf(v.y), f2bf(v.z), f2bf(v.w)};
      *reinterpret_cast<ushort4*>(&As[r][4 * k4]) = o;
    }
  } else {
    const ushort_t* Ab = (const ushort_t*)Asrc;
    for (int i = t; i < 64 * 16; i += 256) {
      int r = i >> 4, g8 = i & 15;
      short8 v = *reinterpret_cast<const short8*>(Ab + (size_t)(r0 + r) * 128 + 8 * g8);
      *reinterpret_cast<short8*>(&As[r][8 * g8]) = v;
    }
  }
  __syncthreads();

  f32x4 acc[4] = {};
  #pragma unroll
  for (int ks = 0; ks < 4; ++ks) {
    const ushort_t* ap = &As[16 * w + q][32 * ks + 4 * g];
    short4v alo = *reinterpret_cast<const short4v*>(ap);
    short4v ahi = *reinterpret_cast<const short4v*>(ap + 16);
    short8 af;
    af[0] = alo[0]; af[1] = alo[1]; af[2] = alo[2]; af[3] = alo[3];
    af[4] = ahi[0]; af[5] = ahi[1]; af[6] = ahi[2]; af[7] = ahi[3];
    #pragma unroll
    for (int ct = 0; ct < 4; ++ct)
      acc[ct] = __builtin_amdgcn_mfma_f32_16x16x32_bf16(af, bf[ks][ct], acc[ct], 0, 0, 0);
  }

  #pragma unroll
  for (int ct = 0; ct < 4; ++ct) {
    int col = c0 + 16 * ct + q;
    float bb = bias[col];
    #pragma unroll
    for (int r = 0; r < 4; ++r) {
      float o = acc[ct][r] + bb;
      if (silu) o = o / (1.f + __expf(-o));
      int row = r0 + 16 * w + 4 * g + r;
      if (omode == 1) {
        ((ushort_t*)p0)[(size_t)row * N + col] = f2bf(o);
      } else {
        if (col < 128) ((float*)p0)[(size_t)row * 128 + col] = o;
        else           ((ushort_t*)p1)[(size_t)row * 256 + col - 128] = f2bf(o);
      }
    }
  }
}

// ---------------------------------------------------------------- sort helpers
__global__ void hist_kernel(const int* __restrict__ nbrs, int* __restrict__ counts) {
  int e = blockIdx.x * blockDim.x + threadIdx.x;
  if (e < NEDGES) atomicAdd(&counts[nbrs[2 * e]], 1);
}

__global__ __launch_bounds__(1024) void scan_kernel(
    const int* __restrict__ counts, int* __restrict__ offs, int* __restrict__ cursor) {
  __shared__ int part[1024];
  const int t = threadIdx.x;
  int local[8];
  int s = 0;
  #pragma unroll
  for (int i = 0; i < 8; ++i) { local[i] = counts[t * 8 + i]; s += local[i]; }
  part[t] = s;
  __syncthreads();
  for (int off = 1; off < 1024; off <<= 1) {
    int v = part[t];
    int add = (t >= off) ? part[t - off] : 0;
    __syncthreads();
    part[t] = v + add;
    __syncthreads();
  }
  int excl = part[t] - s;
  #pragma unroll
  for (int i = 0; i < 8; ++i) {
    offs[t * 8 + i] = excl;
    cursor[t * 8 + i] = excl;
    excl += local[i];
  }
  if (t == 1023) offs[NATOMS] = excl;
}

// Pre-joined 16 B edge records {j, x, y, z} in sorted (dest-atom) order.
__global__ void scatter_kernel(const int* __restrict__ nbrs, const float* __restrict__ r_ij,
                               int* __restrict__ cursor, uint4* __restrict__ erec) {
  int e = blockIdx.x * blockDim.x + threadIdx.x;
  if (e < NEDGES) {
    int2 nb = *reinterpret_cast<const int2*>(nbrs + 2 * e);
    int pos = atomicAdd(&cursor[nb.x], 1);
    const float* rp = r_ij + 3 * e;
    erec[pos] = make_uint4((uint_t)nb.y, __float_as_uint(rp[0]),
                           __float_as_uint(rp[1]), __float_as_uint(rp[2]));
  }
}

// ---------------------------------------------------------------- edge MFMA v8
// 8 atoms per WAVE (one quarter each). Grid = NATOMS/APW = 1024 blocks x 4 waves
// = 4096 waves = 8192 atoms x 4 quarters (r12 bug: launched /4 of this).
// erec prefetch streams ACROSS atom boundaries (records contiguous in sorted
// order). qtr = blockIdx&3 keeps the r11 L2-capacity-fit XCD mapping.
__global__ __launch_bounds__(256) void edge_mfma8(
    const uint4* __restrict__ erec, const int* __restrict__ offs,
    const ushort_t* __restrict__ PV, const ushort_t* __restrict__ wrs,
    float* __restrict__ out_s, float* __restrict__ out_v) {
  __shared__ short8 sW[6 * 64];   // 6144 B: this quarter's 6 tiles (3 sec x 2 ct)
  const int t = threadIdx.x;
  const int qtr = blockIdx.x & 3;
  for (int i = t; i < 6 * 64; i += 256) {
    int tl = i >> 6, l2 = i & 63;
    int s = tl >> 1, c = tl & 1;
    sW[i] = *reinterpret_cast<const short8*>(
        wrs + ((size_t)(s * 8 + 2 * qtr + c) * 64 + l2) * 8);
  }
  __syncthreads();

  const int w = t >> 6, l = t & 63, g = l >> 4, q = l & 15;
  const int a0 = ((blockIdx.x >> 2) * 4 + w) * APW;
  const float c1 = PI_F / CUTOFF_F;
  const char* PVb = reinterpret_cast<const char*>(PV) + (size_t)qtr * QTUS * 2;

  int eb = offs[a0];
  int end = offs[a0 + 1];
  uint4 er = make_uint4(0u, 0u, 0u, 0u);
  if (eb + q < end) er = erec[eb + q];

  for (int aidx = 0; aidx < APW; ++aidx) {
    const int end_next = (aidx + 1 < APW) ? offs[a0 + aidx + 2] : 0;
    float ds0 = 0.f, ds1 = 0.f;
    float dv[2][3] = {};

    for (;;) {
      const bool last = (eb + 16 >= end);
      const int neb = last ? end : (eb + 16);
      const int nend = last ? ((aidx + 1 < APW) ? end_next : neb) : end;
      uint4 ern = make_uint4(0u, 0u, 0u, 0u);
      if (neb + q < nend) ern = erec[neb + q];

      // ---- metadata from pre-joined record (lane q owns edge eb+q)
      float ang = 0.f, ie = 0.f, env = 0.f, u0 = 0.f, u1 = 0.f, u2 = 0.f;
      int jn = 0;
      if (eb + q < end) {
        jn = (int)er.x;
        float x = __uint_as_float(er.y), y = __uint_as_float(er.z), z = __uint_as_float(er.w);
        float d = sqrtf(x * x + y * y + z * z);
        float inv = 1.f / d;
        ang = c1 * d;
        env = (d < CUTOFF_F) ? 0.5f * (__cosf(ang) + 1.f) : 0.f;
        ie = inv * env;
        u0 = x * inv; u1 = y * inv; u2 = z * inv;
      }
      // ---- row (edge eb+4g+r) metadata broadcast + base pointers
      const char* pb[4];
      float ub[4][3];
      #pragma unroll
      for (int r = 0; r < 4; ++r) {
        int src = 4 * g + r;
        int jr = __shfl(jn, src, 64);
        ub[r][0] = __shfl(u0, src, 64);
        ub[r][1] = __shfl(u1, src, 64);
        ub[r][2] = __shfl(u2, src, 64);
        pb[r] = PVb + (size_t)jr * 384 + (size_t)q * 12;
      }
      // ---- 8 PV gathers (12 B each) up front
      U3 ld[2][4];
      #pragma unroll
      for (int c = 0; c < 2; ++c)
        #pragma unroll
        for (int r = 0; r < 4; ++r)
          ld[c][r] = *reinterpret_cast<const U3*>(pb[r] + (size_t)c * 192);
      // ---- A fragment: k = kmap(g,jj) = 4g+(jj&3)+16*(jj>>2)
      short8 af;
      #pragma unroll
      for (int jj = 0; jj < 8; ++jj) {
        int k = 4 * g + (jj & 3) + 16 * (jj >> 2);
        float v = (k < NRBF) ? ie * __sinf((float)(k + 1) * ang)
                             : (k == NRBF ? env : 0.f);
        af[jj] = (short)f2bf(v);
      }
      // ---- 2 col-tiles x 3 sections
      #pragma unroll
      for (int c = 0; c < 2; ++c) {
        short8 b0 = sW[(0 * 2 + c) * 64 + l];
        short8 b1 = sW[(1 * 2 + c) * 64 + l];
        short8 b2 = sW[(2 * 2 + c) * 64 + l];
        f32x4 z4 = {0.f, 0.f, 0.f, 0.f};
        f32x4 cs0 = __builtin_amdgcn_mfma_f32_16x16x32_bf16(af, b0, z4, 0, 0, 0);
        f32x4 cs1 = __builtin_amdgcn_mfma_f32_16x16x32_bf16(af, b1, z4, 0, 0, 0);
        f32x4 cs2 = __builtin_amdgcn_mfma_f32_16x16x32_bf16(af, b2, z4, 0, 0, 0);
        #pragma unroll
        for (int r = 0; r < 4; ++r) {
          U3 u = ld[c][r];
          float p0 = bflo(u.x), p1 = bfhi(u.x);
          float p2 = bflo(u.y), v0 = bfhi(u.y);
          float v1 = bflo(u.z), v2 = bfhi(u.z);
          float pw0 = p0 * cs0[r];
          if (c == 0) ds0 += p1 * cs1[r]; else ds1 += p1 * cs1[r];
          float pw2 = p2 * cs2[r];
          dv[c][0] += pw0 * v0 + pw2 * ub[r][0];
          dv[c][1] += pw0 * v1 + pw2 * ub[r][1];
          dv[c][2] += pw0 * v2 + pw2 * ub[r][2];
        }
      }
      er = ern;
      eb = neb;
      if (last) break;
    }

    // ---- reduce the 4 g-copies and write atom a0+aidx
    float r0v = ds0, r1v = ds1;
    r0v += __shfl_xor(r0v, 16, 64); r0v += __shfl_xor(r0v, 32, 64);
    r1v += __shfl_xor(r1v, 16, 64); r1v += __shfl_xor(r1v, 32, 64);
    float dvr[2][3];
    #pragma unroll
    for (int c = 0; c < 2; ++c)
      #pragma unroll
      for (int cc = 0; cc < 3; ++cc) {
        float y = dv[c][cc];
        y += __shfl_xor(y, 16, 64); y += __shfl_xor(y, 32, 64);
        dvr[c][cc] = y;
      }
    if (g < 2) {
      int atom = a0 + aidx;
      float sv = (g == 0) ? r0v : r1v;
      float d0 = (g == 0) ? dvr[0][0] : dvr[1][0];
      float d1 = (g == 0) ? dvr[0][1] : dvr[1][1];
      float d2 = (g == 0) ? dvr[0][2] : dvr[1][2];
      int f = 32 * qtr + 16 * g + q;
      out_s[(size_t)atom * FEAT + f] = sv;
      float* ov = out_v + (size_t)atom * 384 + (size_t)f * 3;
      ov[0] = d0; ov[1] = d1; ov[2] = d2;
    }
    end = end_next;
  }
}

// ---------------------------------------------------------------- attention
__device__ __forceinline__ float wave_max64(float v) {
  #pragma unroll
  for (int m = 32; m > 0; m >>= 1) v = fmaxf(v, __shfl_xor(v, m, 64));
  return v;
}
__device__ __forceinline__ float wave_sum64(float v) {
  #pragma unroll
  for (int m = 32; m > 0; m >>= 1) v += __shfl_xor(v, m, 64);
  return v;
}

__global__ __launch_bounds__(256) void attn_kernel(const float* __restrict__ Qf,
                                                   const ushort_t* __restrict__ kvbf,
                                                   float* __restrict__ out_s) {
  __shared__ float4 Ks4[64 * 32];
  __shared__ float  Vs[64][130];
  __shared__ float  Ps[4][4][64];
  const int b = blockIdx.x >> 1, half = blockIdx.x & 1;
  const int t = threadIdx.x;
  const float* qbase = Qf + (size_t)b * APG * 128;
  const ushort_t* kvb = kvbf + (size_t)b * APG * 256;

  for (int i = t; i < 64 * 32; i += 256) {
    int a = i >> 5, gg = i & 31;
    ushort4 k4 = *reinterpret_cast<const ushort4*>(kvb + a * 256 + 4 * gg);
    float4 kf = {bfus(k4.x), bfus(k4.y), bfus(k4.z), bfus(k4.w)};
    Ks4[a * 32 + (gg ^ (a & 7))] = kf;
  }
  for (int i = t; i < 64 * 32; i += 256) {
    int a = i >> 5, gg = i & 31;
    ushort4 v4 = *reinterpret_cast<const ushort4*>(kvb + a * 256 + 128 + 4 * gg);
    Vs[a][4 * gg + 0] = bfus(v4.x); Vs[a][4 * gg + 1] = bfus(v4.y);
    Vs[a][4 * gg + 2] = bfus(v4.z); Vs[a][4 * gg + 3] = bfus(v4.w);
  }
  __syncthreads();

  const int w = t >> 6, l = t & 63;
  const float scale = 0.08838834764831845f;

  for (int qq = 8 * half + w; qq < 8 * half + 8; qq += 4) {
    const float* q0p = qbase + (size_t)(4 * qq + 0) * 128;
    const float* q1p = qbase + (size_t)(4 * qq + 1) * 128;
    const float* q2p = qbase + (size_t)(4 * qq + 2) * 128;
    const float* q3p = qbase + (size_t)(4 * qq + 3) * 128;
    float s0 = 0.f, s1 = 0.f, s2 = 0.f, s3 = 0.f;
    #pragma unroll 8
    for (int i = 0; i < 32; ++i) {
      float4 k = Ks4[l * 32 + (i ^ (l & 7))];
      float4 q0 = *reinterpret_cast<const float4*>(q0p + 4 * i);
      float4 q1 = *reinterpret_cast<const float4*>(q1p + 4 * i);
      float4 q2 = *reinterpret_cast<const float4*>(q2p + 4 * i);
      float4 q3 = *reinterpret_cast<const float4*>(q3p + 4 * i);
      s0 += q0.x * k.x + q0.y * k.y + q0.z * k.z + q0.w * k.w;
      s1 += q1.x * k.x + q1.y * k.y + q1.z * k.z + q1.w * k.w;
      s2 += q2.x * k.x + q2.y * k.y + q2.z * k.z + q2.w * k.w;
      s3 += q3.x * k.x + q3.y * k.y + q3.z * k.z + q3.w * k.w;
    }
    s0 *= scale; s1 *= scale; s2 *= scale; s3 *= scale;

    float p0 = __expf(s0 - wave_max64(s0));
    float p1 = __expf(s1 - wave_max64(s1));
    float p2 = __expf(s2 - wave_max64(s2));
    float p3 = __expf(s3 - wave_max64(s3));
    p0 /= wave_sum64(p0); p1 /= wave_sum64(p1);
    p2 /= wave_sum64(p2); p3 /= wave_sum64(p3);

    Ps[w][0][l] = p0; Ps[w][1][l] = p1; Ps[w][2][l] = p2; Ps[w][3][l] = p3;
    __threadfence_block();

    float a00 = 0.f, a01 = 0.f, a10 = 0.f, a11 = 0.f;
    float a20 = 0.f, a21 = 0.f, a30 = 0.f, a31 = 0.f;
    for (int a = 0; a < 64; ++a) {
      float2 v = *reinterpret_cast<const float2*>(&Vs[a][2 * l]);
      float pa0 = Ps[w][0][a], pa1 = Ps[w][1][a];
      float pa2 = Ps[w][2][a], pa3 = Ps[w][3][a];
      a00 += pa0 * v.x; a01 += pa0 * v.y;
      a10 += pa1 * v.x; a11 += pa1 * v.y;
      a20 += pa2 * v.x; a21 += pa2 * v.y;
      a30 += pa3 * v.x; a31 += pa3 * v.y;
    }
    size_t row0 = (size_t)(b * APG + 4 * qq) * FEAT + 2 * l;
    float2* o0 = reinterpret_cast<float2*>(out_s + row0);
    float2* o1 = reinterpret_cast<float2*>(out_s + row0 + FEAT);
    float2* o2 = reinterpret_cast<float2*>(out_s + row0 + 2 * FEAT);
    float2* o3 = reinterpret_cast<float2*>(out_s + row0 + 3 * FEAT);
    float2 c0 = *o0; c0.x += a00; c0.y += a01; *o0 = c0;
    float2 c1 = *o1; c1.x += a10; c1.y += a11; *o1 = c1;
    float2 c2 = *o2; c2.x += a20; c2.y += a21; *o2 = c2;
    float2 c3 = *o3; c3.x += a30; c3.y += a31; *o3 = c3;
    __threadfence_block();
  }
}

// ---------------------------------------------------------------- launch
extern "C" void kernel_launch(void* const* d_in, const int* in_sizes, int n_in,
                              void* d_out, int out_size, void* d_ws, size_t ws_size,
                              hipStream_t stream) {
  const float* s_j  = (const float*)d_in[0];
  const float* v_j  = (const float*)d_in[1];
  const float* r_ij = (const float*)d_in[2];
  const int*   nbrs = (const int*)d_in[3];
  const float* W1   = (const float*)d_in[5];
  const float* b1   = (const float*)d_in[6];
  const float* W2   = (const float*)d_in[7];
  const float* b2   = (const float*)d_in[8];
  const float* Wr   = (const float*)d_in[9];
  const float* br   = (const float*)d_in[10];
  const float* Wd   = (const float*)d_in[11];
  const float* bd   = (const float*)d_in[12];

  float* out_s = (float*)d_out;
  float* out_v = out_s + (size_t)NATOMS * FEAT;

  // workspace ~25.5 MB (<= 26.4 proven).
  float*    Qf   = (float*)d_ws;                         // 4 MB
  ushort_t* kvbf = (ushort_t*)(Qf + NATOMS * FEAT);      // 4 MB
  ushort_t* PV   = kvbf + (size_t)NATOMS * 256;          // 4 x 3.15 MB quarter tables
  ushort_t* w1s  = PV + 4 * QTUS;                        // 16384
  ushort_t* w2s  = w1s + 16384;                          // 49152
  ushort_t* wds  = w2s + 49152;                          // 49152
  ushort_t* wrs  = wds + 49152;                          // 12288
  uint4*    erec = (uint4*)(wrs + 12288);                // 4 MB
  int* offs   = (int*)(erec + NEDGES);                   // NATOMS+1
  int* cursor = offs + (NATOMS + 1);
  int* counts = cursor + NATOMS;

  int prep_total = NATOMS * FEAT + 16384 + 49152 + 49152 + 12288;
  prep_kernel<<<(prep_total + 255) / 256, 256, 0, stream>>>(
      v_j, W1, W2, Wd, Wr, br, PV, w1s, w2s, wds, wrs);

  gemm_fused12<<<NATOMS / 64, 256, 0, stream>>>(s_j, w1s, b1, w2s, b2, PV);

  hipMemsetAsync(counts, 0, NATOMS * sizeof(int), stream);
  hist_kernel<<<NEDGES / 256, 256, 0, stream>>>(nbrs, counts);
  scan_kernel<<<1, 1024, 0, stream>>>(counts, offs, cursor);
  scatter_kernel<<<NEDGES / 256, 256, 0, stream>>>(nbrs, r_ij, cursor, erec);

  gemm_mfma<<<dim3(NATOMS / 64, 6), 256, 0, stream>>>(
      s_j, 1, wds, bd, 384, 24, 0, 3, Qf, kvbf);

  edge_mfma8<<<NATOMS / APW, 256, 0, stream>>>(erec, offs, PV, wrs, out_s, out_v);
  attn_kernel<<<NGRAPH * 2, 256, 0, stream>>>(Qf, kvbf, out_s);
}

// Round 14
// 131.105 us; speedup vs baseline: 1.6944x; 1.0792x over previous
//
#include <hip/hip_runtime.h>
#include <hip/hip_bf16.h>
#include <cstdint>

#define FEAT    128
#define NRBF    20
#define NATOMS  8192
#define NEDGES  262144
#define NGRAPH  128
#define APG     64
#define PI_F    3.14159265358979323846f
#define CUTOFF_F 5.0f
#define QTUS    ((size_t)NATOMS * 32 * 6)   // ushorts per PV quarter-table (3.15 MB)
#define APW     4                           // atoms per wave (edge kernel)

typedef unsigned int uint_t;
typedef unsigned short ushort_t;
typedef __attribute__((ext_vector_type(4))) float f32x4;
typedef __attribute__((ext_vector_type(4))) short short4v;
typedef __attribute__((ext_vector_type(8))) short short8;
struct U3 { uint_t x, y, z; };   // 12 B -> global_load_dwordx3

__device__ __forceinline__ float bflo(uint_t u) { return __uint_as_float(u << 16); }
__device__ __forceinline__ float bfhi(uint_t u) { return __uint_as_float(u & 0xffff0000u); }
__device__ __forceinline__ float bfus(ushort_t u) { return __uint_as_float((uint_t)u << 16); }
__device__ __forceinline__ ushort_t f2bf(float f) {
  uint_t u = __float_as_uint(f);
  return (ushort_t)((u + 0x7fffu + ((u >> 16) & 1u)) >> 16);
}
__device__ __forceinline__ uint_t pack2(float lo, float hi) {
  return (uint_t)f2bf(lo) | ((uint_t)f2bf(hi) << 16);
}

// ---------------------------------------------------------------- prep (+hist fused)
// PV record per (j,f): 6 ushorts {p0,p1,p2,v0,v1,v2}, 12 B stride, FOUR quarter-tables
// by f>>5 (3.15 MB each -> L2-capacity-fit). prep writes V slots (P zeroed; gemm_big
// scatters P later), all swizzled weights, and the histogram (counts pre-zeroed).
__device__ __forceinline__ ushort_t swz_elem(const float* __restrict__ W, int N,
                                             int NT, int i) {
  int jj = i & 7, lane = (i >> 3) & 63, tile = i >> 9;
  int ks = tile / NT, ctg = tile - ks * NT;
  int g = lane >> 4, q = lane & 15;
  int k = 32 * ks + 4 * g + (jj & 3) + 16 * (jj >> 2);
  int c = 16 * ctg + q;
  return f2bf(W[(size_t)k * N + c]);
}

__global__ void prep_kernel(const float* __restrict__ v_j, const float* __restrict__ W1,
                            const float* __restrict__ W2, const float* __restrict__ Wd,
                            const float* __restrict__ Wr, const float* __restrict__ br,
                            const int* __restrict__ nbrs,
                            ushort_t* __restrict__ PV, ushort_t* __restrict__ w1s,
                            ushort_t* __restrict__ w2s, ushort_t* __restrict__ wds,
                            ushort_t* __restrict__ wrs, int* __restrict__ counts) {
  int i = blockIdx.x * 256 + threadIdx.x;
  if (i < NATOMS * FEAT) {                 // i = j*128 + f
    int j = i >> 7, f = i & 127;
    int tbl = f >> 5, fl = f & 31;
    const float* vp = v_j + (size_t)i * 3; // v_j[j][f][0..2]
    uint_t* o = reinterpret_cast<uint_t*>(PV + (size_t)tbl * QTUS + ((size_t)j * 32 + fl) * 6);
    o[0] = 0u;                     // p0,p1 (gemm fills)
    o[1] = pack2(0.f, vp[0]);      // p2,v0
    o[2] = pack2(vp[1], vp[2]);    // v1,v2
    return;
  }
  i -= NATOMS * FEAT;
  if (i < 16384) { w1s[i] = swz_elem(W1, 128, 8, i); return; }
  i -= 16384;
  if (i < 49152) { w2s[i] = swz_elem(W2, 384, 24, i); return; }
  i -= 49152;
  if (i < 49152) { wds[i] = swz_elem(Wd, 384, 24, i); return; }
  i -= 49152;
  if (i < 12288) {                 // Wr/br frag-order: 24 tiles, k=20 row is br
    int jj = i & 7, lane = (i >> 3) & 63, ct = i >> 9;
    int g = lane >> 4, q = lane & 15;
    int k = 4 * g + (jj & 3) + 16 * (jj >> 2);
    int f = 16 * ct + q;
    float v = (k < NRBF) ? Wr[k * 384 + f] : (k == NRBF ? br[f] : 0.f);
    wrs[i] = f2bf(v);
    return;
  }
  i -= 12288;
  if (i < NEDGES) atomicAdd(&counts[nbrs[2 * i]], 1);   // fused histogram
}

// ---------------------------------------------------------------- big GEMM
// Grid (128, 12). All blocks stage their 64-row s_j tile (bf16 in Buf) and extract
// A-frags. y>=6: qkv slice cols [64(y-6), 64(y-6)+64) -> Qf/kvbf. y<6: recompute
// h = silu(s_j@W1+b1) into Buf (aliases As, dead after frag extraction), then one
// 64-col phi slice -> PV P-slots. Fragment maps HW-verified (rounds 3-13).
__global__ __launch_bounds__(256) void gemm_big(
    const float* __restrict__ s_j, const ushort_t* __restrict__ w1s,
    const float* __restrict__ b1, const ushort_t* __restrict__ w2s,
    const float* __restrict__ b2, const ushort_t* __restrict__ wds,
    const float* __restrict__ bd, ushort_t* __restrict__ PV,
    float* __restrict__ Qf, ushort_t* __restrict__ kvbf) {
  __shared__ ushort_t Buf[64][136];
  const int t = threadIdx.x;
  const int r0 = blockIdx.x * 64;
  const int y = blockIdx.y;
  const int w = t >> 6, l = t & 63, g = l >> 4, q = l & 15;

  for (int i = t; i < 64 * 32; i += 256) {
    int r = i >> 5, k4 = i & 31;
    float4 v = *reinterpret_cast<const float4*>(s_j + (size_t)(r0 + r) * 128 + 4 * k4);
    ushort4 o = {f2bf(v.x), f2bf(v.y), f2bf(v.z), f2bf(v.w)};
    *reinterpret_cast<ushort4*>(&Buf[r][4 * k4]) = o;
  }
  __syncthreads();

  short8 afr[4];
  #pragma unroll
  for (int ks = 0; ks < 4; ++ks) {
    const ushort_t* ap = &Buf[16 * w + q][32 * ks + 4 * g];
    short4v alo = *reinterpret_cast<const short4v*>(ap);
    short4v ahi = *reinterpret_cast<const short4v*>(ap + 16);
    afr[ks] = short8{alo[0], alo[1], alo[2], alo[3], ahi[0], ahi[1], ahi[2], ahi[3]};
  }

  if (y >= 6) {
    // ---- qkv slice
    const int yy = y - 6;
    #pragma unroll
    for (int ct = 0; ct < 4; ++ct) {
      f32x4 acc = {};
      #pragma unroll
      for (int ks = 0; ks < 4; ++ks) {
        short8 bf = *reinterpret_cast<const short8*>(
            wds + ((size_t)(ks * 24 + yy * 4 + ct) * 64 + l) * 8);
        acc = __builtin_amdgcn_mfma_f32_16x16x32_bf16(afr[ks], bf, acc, 0, 0, 0);
      }
      int col = yy * 64 + 16 * ct + q;
      float bb = bd[col];
      #pragma unroll
      for (int r = 0; r < 4; ++r) {
        float o = acc[r] + bb;
        int row = r0 + 16 * w + 4 * g + r;
        if (col < 128) Qf[(size_t)row * 128 + col] = o;
        else           kvbf[(size_t)row * 256 + col - 128] = f2bf(o);
      }
    }
    return;
  }

  // ---- phi path: recompute h into Buf (As dead after afr extraction)
  __syncthreads();
  #pragma unroll
  for (int ct = 0; ct < 8; ++ct) {
    f32x4 acc = {};
    #pragma unroll
    for (int ks = 0; ks < 4; ++ks) {
      short8 bf = *reinterpret_cast<const short8*>(
          w1s + ((size_t)(ks * 8 + ct) * 64 + l) * 8);
      acc = __builtin_amdgcn_mfma_f32_16x16x32_bf16(afr[ks], bf, acc, 0, 0, 0);
    }
    float bb = b1[16 * ct + q];
    #pragma unroll
    for (int r = 0; r < 4; ++r) {
      float o = acc[r] + bb;
      o = o / (1.f + __expf(-o));
      Buf[16 * w + 4 * g + r][16 * ct + q] = f2bf(o);
    }
  }
  __syncthreads();

  short8 hfr[4];
  #pragma unroll
  for (int ks = 0; ks < 4; ++ks) {
    const ushort_t* ap = &Buf[16 * w + q][32 * ks + 4 * g];
    short4v alo = *reinterpret_cast<const short4v*>(ap);
    short4v ahi = *reinterpret_cast<const short4v*>(ap + 16);
    hfr[ks] = short8{alo[0], alo[1], alo[2], alo[3], ahi[0], ahi[1], ahi[2], ahi[3]};
  }
  #pragma unroll
  for (int ct = 0; ct < 4; ++ct) {
    f32x4 acc = {};
    #pragma unroll
    for (int ks = 0; ks < 4; ++ks) {
      short8 bf = *reinterpret_cast<const short8*>(
          w2s + ((size_t)(ks * 24 + y * 4 + ct) * 64 + l) * 8);
      acc = __builtin_amdgcn_mfma_f32_16x16x32_bf16(hfr[ks], bf, acc, 0, 0, 0);
    }
    int col = y * 64 + 16 * ct + q;
    float bb = b2[col];
    int f = col & 127, s = col >> 7;
    int tbl = f >> 5, fl = f & 31;
    #pragma unroll
    for (int r = 0; r < 4; ++r) {
      float o = acc[r] + bb;
      int row = r0 + 16 * w + 4 * g + r;
      PV[(size_t)tbl * QTUS + ((size_t)row * 32 + fl) * 6 + s] = f2bf(o);
    }
  }
}

// ---------------------------------------------------------------- sort helpers
__global__ __launch_bounds__(1024) void scan_kernel(
    const int* __restrict__ counts, int* __restrict__ offs, int* __restrict__ cursor) {
  __shared__ int part[1024];
  const int t = threadIdx.x;
  int local[8];
  int s = 0;
  #pragma unroll
  for (int i = 0; i < 8; ++i) { local[i] = counts[t * 8 + i]; s += local[i]; }
  part[t] = s;
  __syncthreads();
  for (int off = 1; off < 1024; off <<= 1) {
    int v = part[t];
    int add = (t >= off) ? part[t - off] : 0;
    __syncthreads();
    part[t] = v + add;
    __syncthreads();
  }
  int excl = part[t] - s;
  #pragma unroll
  for (int i = 0; i < 8; ++i) {
    offs[t * 8 + i] = excl;
    cursor[t * 8 + i] = excl;
    excl += local[i];
  }
  if (t == 1023) offs[NATOMS] = excl;
}

// Pre-joined 16 B edge records {j, x, y, z} in sorted (dest-atom) order.
__global__ void scatter_kernel(const int* __restrict__ nbrs, const float* __restrict__ r_ij,
                               int* __restrict__ cursor, uint4* __restrict__ erec) {
  int e = blockIdx.x * blockDim.x + threadIdx.x;
  if (e < NEDGES) {
    int2 nb = *reinterpret_cast<const int2*>(nbrs + 2 * e);
    int pos = atomicAdd(&cursor[nb.x], 1);
    const float* rp = r_ij + 3 * e;
    erec[pos] = make_uint4((uint_t)nb.y, __float_as_uint(rp[0]),
                           __float_as_uint(rp[1]), __float_as_uint(rp[2]));
  }
}

// ---------------------------------------------------------------- edge MFMA v8
// APW=4 atoms per wave (one quarter each). Grid = NATOMS/APW = 2048 blocks x 4
// waves = 8192 waves (6/SIMD VGPR cap vs 4 at APW=8). erec prefetch streams
// across atom boundaries. qtr = blockIdx&3 keeps the L2-capacity-fit XCD map.
__global__ __launch_bounds__(256) void edge_mfma8(
    const uint4* __restrict__ erec, const int* __restrict__ offs,
    const ushort_t* __restrict__ PV, const ushort_t* __restrict__ wrs,
    float* __restrict__ out_s, float* __restrict__ out_v) {
  __shared__ short8 sW[6 * 64];   // 6144 B: this quarter's 6 tiles (3 sec x 2 ct)
  const int t = threadIdx.x;
  const int qtr = blockIdx.x & 3;
  for (int i = t; i < 6 * 64; i += 256) {
    int tl = i >> 6, l2 = i & 63;
    int s = tl >> 1, c = tl & 1;
    sW[i] = *reinterpret_cast<const short8*>(
        wrs + ((size_t)(s * 8 + 2 * qtr + c) * 64 + l2) * 8);
  }
  __syncthreads();

  const int w = t >> 6, l = t & 63, g = l >> 4, q = l & 15;
  const int a0 = ((blockIdx.x >> 2) * 4 + w) * APW;
  const float c1 = PI_F / CUTOFF_F;
  const char* PVb = reinterpret_cast<const char*>(PV) + (size_t)qtr * QTUS * 2;

  int eb = offs[a0];
  int end = offs[a0 + 1];
  uint4 er = make_uint4(0u, 0u, 0u, 0u);
  if (eb + q < end) er = erec[eb + q];

  for (int aidx = 0; aidx < APW; ++aidx) {
    const int end_next = (aidx + 1 < APW) ? offs[a0 + aidx + 2] : 0;
    float ds0 = 0.f, ds1 = 0.f;
    float dv[2][3] = {};

    for (;;) {
      const bool last = (eb + 16 >= end);
      const int neb = last ? end : (eb + 16);
      const int nend = last ? ((aidx + 1 < APW) ? end_next : neb) : end;
      uint4 ern = make_uint4(0u, 0u, 0u, 0u);
      if (neb + q < nend) ern = erec[neb + q];

      // ---- metadata from pre-joined record (lane q owns edge eb+q)
      float ang = 0.f, ie = 0.f, env = 0.f, u0 = 0.f, u1 = 0.f, u2 = 0.f;
      int jn = 0;
      if (eb + q < end) {
        jn = (int)er.x;
        float x = __uint_as_float(er.y), y = __uint_as_float(er.z), z = __uint_as_float(er.w);
        float d = sqrtf(x * x + y * y + z * z);
        float inv = 1.f / d;
        ang = c1 * d;
        env = (d < CUTOFF_F) ? 0.5f * (__cosf(ang) + 1.f) : 0.f;
        ie = inv * env;
        u0 = x * inv; u1 = y * inv; u2 = z * inv;
      }
      // ---- row (edge eb+4g+r) metadata broadcast + base pointers
      const char* pb[4];
      float ub[4][3];
      #pragma unroll
      for (int r = 0; r < 4; ++r) {
        int src = 4 * g + r;
        int jr = __shfl(jn, src, 64);
        ub[r][0] = __shfl(u0, src, 64);
        ub[r][1] = __shfl(u1, src, 64);
        ub[r][2] = __shfl(u2, src, 64);
        pb[r] = PVb + (size_t)jr * 384 + (size_t)q * 12;
      }
      // ---- 8 PV gathers (12 B each) up front
      U3 ld[2][4];
      #pragma unroll
      for (int c = 0; c < 2; ++c)
        #pragma unroll
        for (int r = 0; r < 4; ++r)
          ld[c][r] = *reinterpret_cast<const U3*>(pb[r] + (size_t)c * 192);
      // ---- A fragment: k = kmap(g,jj) = 4g+(jj&3)+16*(jj>>2)
      short8 af;
      #pragma unroll
      for (int jj = 0; jj < 8; ++jj) {
        int k = 4 * g + (jj & 3) + 16 * (jj >> 2);
        float v = (k < NRBF) ? ie * __sinf((float)(k + 1) * ang)
                             : (k == NRBF ? env : 0.f);
        af[jj] = (short)f2bf(v);
      }
      // ---- 2 col-tiles x 3 sections
      #pragma unroll
      for (int c = 0; c < 2; ++c) {
        short8 b0 = sW[(0 * 2 + c) * 64 + l];
        short8 b1 = sW[(1 * 2 + c) * 64 + l];
        short8 b2 = sW[(2 * 2 + c) * 64 + l];
        f32x4 z4 = {0.f, 0.f, 0.f, 0.f};
        f32x4 cs0 = __builtin_amdgcn_mfma_f32_16x16x32_bf16(af, b0, z4, 0, 0, 0);
        f32x4 cs1 = __builtin_amdgcn_mfma_f32_16x16x32_bf16(af, b1, z4, 0, 0, 0);
        f32x4 cs2 = __builtin_amdgcn_mfma_f32_16x16x32_bf16(af, b2, z4, 0, 0, 0);
        #pragma unroll
        for (int r = 0; r < 4; ++r) {
          U3 u = ld[c][r];
          float p0 = bflo(u.x), p1 = bfhi(u.x);
          float p2 = bflo(u.y), v0 = bfhi(u.y);
          float v1 = bflo(u.z), v2 = bfhi(u.z);
          float pw0 = p0 * cs0[r];
          if (c == 0) ds0 += p1 * cs1[r]; else ds1 += p1 * cs1[r];
          float pw2 = p2 * cs2[r];
          dv[c][0] += pw0 * v0 + pw2 * ub[r][0];
          dv[c][1] += pw0 * v1 + pw2 * ub[r][1];
          dv[c][2] += pw0 * v2 + pw2 * ub[r][2];
        }
      }
      er = ern;
      eb = neb;
      if (last) break;
    }

    // ---- reduce the 4 g-copies and write atom a0+aidx
    float r0v = ds0, r1v = ds1;
    r0v += __shfl_xor(r0v, 16, 64); r0v += __shfl_xor(r0v, 32, 64);
    r1v += __shfl_xor(r1v, 16, 64); r1v += __shfl_xor(r1v, 32, 64);
    float dvr[2][3];
    #pragma unroll
    for (int c = 0; c < 2; ++c)
      #pragma unroll
      for (int cc = 0; cc < 3; ++cc) {
        float y = dv[c][cc];
        y += __shfl_xor(y, 16, 64); y += __shfl_xor(y, 32, 64);
        dvr[c][cc] = y;
      }
    if (g < 2) {
      int atom = a0 + aidx;
      float sv = (g == 0) ? r0v : r1v;
      float d0 = (g == 0) ? dvr[0][0] : dvr[1][0];
      float d1 = (g == 0) ? dvr[0][1] : dvr[1][1];
      float d2 = (g == 0) ? dvr[0][2] : dvr[1][2];
      int f = 32 * qtr + 16 * g + q;
      out_s[(size_t)atom * FEAT + f] = sv;
      float* ov = out_v + (size_t)atom * 384 + (size_t)f * 3;
      ov[0] = d0; ov[1] = d1; ov[2] = d2;
    }
    end = end_next;
  }
}

// ---------------------------------------------------------------- attention
__device__ __forceinline__ float wave_max64(float v) {
  #pragma unroll
  for (int m = 32; m > 0; m >>= 1) v = fmaxf(v, __shfl_xor(v, m, 64));
  return v;
}
__device__ __forceinline__ float wave_sum64(float v) {
  #pragma unroll
  for (int m = 32; m > 0; m >>= 1) v += __shfl_xor(v, m, 64);
  return v;
}

// 4 blocks per graph (quad = bid&3); each wave handles one group of 4 queries.
__global__ __launch_bounds__(256) void attn_kernel(const float* __restrict__ Qf,
                                                   const ushort_t* __restrict__ kvbf,
                                                   float* __restrict__ out_s) {
  __shared__ float4 Ks4[64 * 32];
  __shared__ float  Vs[64][130];
  __shared__ float  Ps[4][4][64];
  const int b = blockIdx.x >> 2, quad = blockIdx.x & 3;
  const int t = threadIdx.x;
  const float* qbase = Qf + (size_t)b * APG * 128;
  const ushort_t* kvb = kvbf + (size_t)b * APG * 256;

  for (int i = t; i < 64 * 32; i += 256) {
    int a = i >> 5, gg = i & 31;
    ushort4 k4 = *reinterpret_cast<const ushort4*>(kvb + a * 256 + 4 * gg);
    float4 kf = {bfus(k4.x), bfus(k4.y), bfus(k4.z), bfus(k4.w)};
    Ks4[a * 32 + (gg ^ (a & 7))] = kf;
  }
  for (int i = t; i < 64 * 32; i += 256) {
    int a = i >> 5, gg = i & 31;
    ushort4 v4 = *reinterpret_cast<const ushort4*>(kvb + a * 256 + 128 + 4 * gg);
    Vs[a][4 * gg + 0] = bfus(v4.x); Vs[a][4 * gg + 1] = bfus(v4.y);
    Vs[a][4 * gg + 2] = bfus(v4.z); Vs[a][4 * gg + 3] = bfus(v4.w);
  }
  __syncthreads();

  const int w = t >> 6, l = t & 63;
  const int qq = 4 * quad + w;
  const float scale = 0.08838834764831845f;

  const float* q0p = qbase + (size_t)(4 * qq + 0) * 128;
  const float* q1p = qbase + (size_t)(4 * qq + 1) * 128;
  const float* q2p = qbase + (size_t)(4 * qq + 2) * 128;
  const float* q3p = qbase + (size_t)(4 * qq + 3) * 128;
  float s0 = 0.f, s1 = 0.f, s2 = 0.f, s3 = 0.f;
  #pragma unroll 8
  for (int i = 0; i < 32; ++i) {
    float4 k = Ks4[l * 32 + (i ^ (l & 7))];
    float4 q0 = *reinterpret_cast<const float4*>(q0p + 4 * i);
    float4 q1 = *reinterpret_cast<const float4*>(q1p + 4 * i);
    float4 q2 = *reinterpret_cast<const float4*>(q2p + 4 * i);
    float4 q3 = *reinterpret_cast<const float4*>(q3p + 4 * i);
    s0 += q0.x * k.x + q0.y * k.y + q0.z * k.z + q0.w * k.w;
    s1 += q1.x * k.x + q1.y * k.y + q1.z * k.z + q1.w * k.w;
    s2 += q2.x * k.x + q2.y * k.y + q2.z * k.z + q2.w * k.w;
    s3 += q3.x * k.x + q3.y * k.y + q3.z * k.z + q3.w * k.w;
  }
  s0 *= scale; s1 *= scale; s2 *= scale; s3 *= scale;

  float p0 = __expf(s0 - wave_max64(s0));
  float p1 = __expf(s1 - wave_max64(s1));
  float p2 = __expf(s2 - wave_max64(s2));
  float p3 = __expf(s3 - wave_max64(s3));
  p0 /= wave_sum64(p0); p1 /= wave_sum64(p1);
  p2 /= wave_sum64(p2); p3 /= wave_sum64(p3);

  Ps[w][0][l] = p0; Ps[w][1][l] = p1; Ps[w][2][l] = p2; Ps[w][3][l] = p3;
  __threadfence_block();

  float a00 = 0.f, a01 = 0.f, a10 = 0.f, a11 = 0.f;
  float a20 = 0.f, a21 = 0.f, a30 = 0.f, a31 = 0.f;
  for (int a = 0; a < 64; ++a) {
    float2 v = *reinterpret_cast<const float2*>(&Vs[a][2 * l]);
    float pa0 = Ps[w][0][a], pa1 = Ps[w][1][a];
    float pa2 = Ps[w][2][a], pa3 = Ps[w][3][a];
    a00 += pa0 * v.x; a01 += pa0 * v.y;
    a10 += pa1 * v.x; a11 += pa1 * v.y;
    a20 += pa2 * v.x; a21 += pa2 * v.y;
    a30 += pa3 * v.x; a31 += pa3 * v.y;
  }
  size_t row0 = (size_t)(b * APG + 4 * qq) * FEAT + 2 * l;
  float2* o0 = reinterpret_cast<float2*>(out_s + row0);
  float2* o1 = reinterpret_cast<float2*>(out_s + row0 + FEAT);
  float2* o2 = reinterpret_cast<float2*>(out_s + row0 + 2 * FEAT);
  float2* o3 = reinterpret_cast<float2*>(out_s + row0 + 3 * FEAT);
  float2 c0 = *o0; c0.x += a00; c0.y += a01; *o0 = c0;
  float2 c1 = *o1; c1.x += a10; c1.y += a11; *o1 = c1;
  float2 c2 = *o2; c2.x += a20; c2.y += a21; *o2 = c2;
  float2 c3 = *o3; c3.x += a30; c3.y += a31; *o3 = c3;
}

// ---------------------------------------------------------------- launch
extern "C" void kernel_launch(void* const* d_in, const int* in_sizes, int n_in,
                              void* d_out, int out_size, void* d_ws, size_t ws_size,
                              hipStream_t stream) {
  const float* s_j  = (const float*)d_in[0];
  const float* v_j  = (const float*)d_in[1];
  const float* r_ij = (const float*)d_in[2];
  const int*   nbrs = (const int*)d_in[3];
  const float* W1   = (const float*)d_in[5];
  const float* b1   = (const float*)d_in[6];
  const float* W2   = (const float*)d_in[7];
  const float* b2   = (const float*)d_in[8];
  const float* Wr   = (const float*)d_in[9];
  const float* br   = (const float*)d_in[10];
  const float* Wd   = (const float*)d_in[11];
  const float* bd   = (const float*)d_in[12];

  float* out_s = (float*)d_out;
  float* out_v = out_s + (size_t)NATOMS * FEAT;

  // workspace ~25.5 MB (<= 26.4 proven).
  float*    Qf   = (float*)d_ws;                         // 4 MB
  ushort_t* kvbf = (ushort_t*)(Qf + NATOMS * FEAT);      // 4 MB
  ushort_t* PV   = kvbf + (size_t)NATOMS * 256;          // 4 x 3.15 MB quarter tables
  ushort_t* w1s  = PV + 4 * QTUS;                        // 16384
  ushort_t* w2s  = w1s + 16384;                          // 49152
  ushort_t* wds  = w2s + 49152;                          // 49152
  ushort_t* wrs  = wds + 49152;                          // 12288
  uint4*    erec = (uint4*)(wrs + 12288);                // 4 MB
  int* offs   = (int*)(erec + NEDGES);                   // NATOMS+1
  int* cursor = offs + (NATOMS + 1);
  int* counts = cursor + NATOMS;

  hipMemsetAsync(counts, 0, NATOMS * sizeof(int), stream);

  int prep_total = NATOMS * FEAT + 16384 + 49152 + 49152 + 12288 + NEDGES;
  prep_kernel<<<(prep_total + 255) / 256, 256, 0, stream>>>(
      v_j, W1, W2, Wd, Wr, br, nbrs, PV, w1s, w2s, wds, wrs, counts);

  scan_kernel<<<1, 1024, 0, stream>>>(counts, offs, cursor);
  scatter_kernel<<<NEDGES / 256, 256, 0, stream>>>(nbrs, r_ij, cursor, erec);

  gemm_big<<<dim3(NATOMS / 64, 12), 256, 0, stream>>>(
      s_j, w1s, b1, w2s, b2, wds, bd, PV, Qf, kvbf);

  edge_mfma8<<<NATOMS / APW, 256, 0, stream>>>(erec, offs, PV, wrs, out_s, out_v);
  attn_kernel<<<NGRAPH * 4, 256, 0, stream>>>(Qf, kvbf, out_s);
}

// Round 15
// 129.353 us; speedup vs baseline: 1.7174x; 1.0135x over previous
//
#include <hip/hip_runtime.h>
#include <hip/hip_bf16.h>
#include <cstdint>

#define FEAT    128
#define NRBF    20
#define NATOMS  8192
#define NEDGES  262144
#define NGRAPH  128
#define APG     64
#define PI_F    3.14159265358979323846f
#define CUTOFF_F 5.0f
#define QTUS    ((size_t)NATOMS * 32 * 6)   // ushorts per PV quarter-table (3.15 MB)
#define APW     4                           // atoms per wave (edge kernel)

typedef unsigned int uint_t;
typedef unsigned short ushort_t;
typedef __attribute__((ext_vector_type(4))) float f32x4;
typedef __attribute__((ext_vector_type(4))) short short4v;
typedef __attribute__((ext_vector_type(8))) short short8;
struct U3 { uint_t x, y, z; };   // 12 B -> global_load_dwordx3

__device__ __forceinline__ float bflo(uint_t u) { return __uint_as_float(u << 16); }
__device__ __forceinline__ float bfhi(uint_t u) { return __uint_as_float(u & 0xffff0000u); }
__device__ __forceinline__ float bfus(ushort_t u) { return __uint_as_float((uint_t)u << 16); }
__device__ __forceinline__ ushort_t f2bf(float f) {
  uint_t u = __float_as_uint(f);
  return (ushort_t)((u + 0x7fffu + ((u >> 16) & 1u)) >> 16);
}
__device__ __forceinline__ uint_t pack2(float lo, float hi) {
  return (uint_t)f2bf(lo) | ((uint_t)f2bf(hi) << 16);
}

// ---------------------------------------------------------------- prep (+hist fused)
// PV record per (j,f): 6 ushorts {p0,p1,p2,v0,v1,v2}, 12 B stride, FOUR quarter-tables
// by f>>5 (3.15 MB each -> L2-capacity-fit). prep writes full records (P zeroed;
// gemm_big scatters P later), all swizzled weights, and the histogram.
__device__ __forceinline__ ushort_t swz_elem(const float* __restrict__ W, int N,
                                             int NT, int i) {
  int jj = i & 7, lane = (i >> 3) & 63, tile = i >> 9;
  int ks = tile / NT, ctg = tile - ks * NT;
  int g = lane >> 4, q = lane & 15;
  int k = 32 * ks + 4 * g + (jj & 3) + 16 * (jj >> 2);
  int c = 16 * ctg + q;
  return f2bf(W[(size_t)k * N + c]);
}

__global__ void prep_kernel(const float* __restrict__ v_j, const float* __restrict__ W1,
                            const float* __restrict__ W2, const float* __restrict__ Wd,
                            const float* __restrict__ Wr, const float* __restrict__ br,
                            const int* __restrict__ nbrs,
                            ushort_t* __restrict__ PV, ushort_t* __restrict__ w1s,
                            ushort_t* __restrict__ w2s, ushort_t* __restrict__ wds,
                            ushort_t* __restrict__ wrs, int* __restrict__ counts) {
  int i = blockIdx.x * 256 + threadIdx.x;
  if (i < NATOMS * FEAT) {                 // i = j*128 + f
    int j = i >> 7, f = i & 127;
    int tbl = f >> 5, fl = f & 31;
    const float* vp = v_j + (size_t)i * 3; // v_j[j][f][0..2]
    uint_t* o = reinterpret_cast<uint_t*>(PV + (size_t)tbl * QTUS + ((size_t)j * 32 + fl) * 6);
    o[0] = 0u;                     // p0,p1 (gemm fills)
    o[1] = pack2(0.f, vp[0]);      // p2,v0
    o[2] = pack2(vp[1], vp[2]);    // v1,v2
    return;
  }
  i -= NATOMS * FEAT;
  if (i < 16384) { w1s[i] = swz_elem(W1, 128, 8, i); return; }
  i -= 16384;
  if (i < 49152) { w2s[i] = swz_elem(W2, 384, 24, i); return; }
  i -= 49152;
  if (i < 49152) { wds[i] = swz_elem(Wd, 384, 24, i); return; }
  i -= 49152;
  if (i < 12288) {                 // Wr/br frag-order: 24 tiles, k=20 row is br
    int jj = i & 7, lane = (i >> 3) & 63, ct = i >> 9;
    int g = lane >> 4, q = lane & 15;
    int k = 4 * g + (jj & 3) + 16 * (jj >> 2);
    int f = 16 * ct + q;
    float v = (k < NRBF) ? Wr[k * 384 + f] : (k == NRBF ? br[f] : 0.f);
    wrs[i] = f2bf(v);
    return;
  }
  i -= 12288;
  if (i < NEDGES) atomicAdd(&counts[nbrs[2 * i]], 1);   // fused histogram
}

// ---------------------------------------------------------------- big GEMM
// Grid (128, 6). Each block: stage 64-row s_j tile once, extract A-frags, then
// BOTH the qkv slice y (cols 64y..64y+64 of Wd) and the phi slice y (h recomputed
// into Buf -- 32 redundant MFMAs amortized by the halved staging).
// Fragment maps HW-verified (rounds 3-14).
__global__ __launch_bounds__(256) void gemm_big(
    const float* __restrict__ s_j, const ushort_t* __restrict__ w1s,
    const float* __restrict__ b1, const ushort_t* __restrict__ w2s,
    const float* __restrict__ b2, const ushort_t* __restrict__ wds,
    const float* __restrict__ bd, ushort_t* __restrict__ PV,
    float* __restrict__ Qf, ushort_t* __restrict__ kvbf) {
  __shared__ ushort_t Buf[64][136];
  const int t = threadIdx.x;
  const int r0 = blockIdx.x * 64;
  const int y = blockIdx.y;                // 0..5
  const int w = t >> 6, l = t & 63, g = l >> 4, q = l & 15;

  for (int i = t; i < 64 * 32; i += 256) {
    int r = i >> 5, k4 = i & 31;
    float4 v = *reinterpret_cast<const float4*>(s_j + (size_t)(r0 + r) * 128 + 4 * k4);
    ushort4 o = {f2bf(v.x), f2bf(v.y), f2bf(v.z), f2bf(v.w)};
    *reinterpret_cast<ushort4*>(&Buf[r][4 * k4]) = o;
  }
  __syncthreads();

  short8 afr[4];
  #pragma unroll
  for (int ks = 0; ks < 4; ++ks) {
    const ushort_t* ap = &Buf[16 * w + q][32 * ks + 4 * g];
    short4v alo = *reinterpret_cast<const short4v*>(ap);
    short4v ahi = *reinterpret_cast<const short4v*>(ap + 16);
    afr[ks] = short8{alo[0], alo[1], alo[2], alo[3], ahi[0], ahi[1], ahi[2], ahi[3]};
  }
  __syncthreads();   // all Buf reads done before the h overwrite below

  // ---- qkv slice y (no Buf access)
  #pragma unroll
  for (int ct = 0; ct < 4; ++ct) {
    f32x4 acc = {};
    #pragma unroll
    for (int ks = 0; ks < 4; ++ks) {
      short8 bf = *reinterpret_cast<const short8*>(
          wds + ((size_t)(ks * 24 + y * 4 + ct) * 64 + l) * 8);
      acc = __builtin_amdgcn_mfma_f32_16x16x32_bf16(afr[ks], bf, acc, 0, 0, 0);
    }
    int col = y * 64 + 16 * ct + q;
    float bb = bd[col];
    #pragma unroll
    for (int r = 0; r < 4; ++r) {
      float o = acc[r] + bb;
      int row = r0 + 16 * w + 4 * g + r;
      if (col < 128) Qf[(size_t)row * 128 + col] = o;
      else           kvbf[(size_t)row * 256 + col - 128] = f2bf(o);
    }
  }

  // ---- h = silu(s@W1+b1) recomputed into Buf
  #pragma unroll
  for (int ct = 0; ct < 8; ++ct) {
    f32x4 acc = {};
    #pragma unroll
    for (int ks = 0; ks < 4; ++ks) {
      short8 bf = *reinterpret_cast<const short8*>(
          w1s + ((size_t)(ks * 8 + ct) * 64 + l) * 8);
      acc = __builtin_amdgcn_mfma_f32_16x16x32_bf16(afr[ks], bf, acc, 0, 0, 0);
    }
    float bb = b1[16 * ct + q];
    #pragma unroll
    for (int r = 0; r < 4; ++r) {
      float o = acc[r] + bb;
      o = o / (1.f + __expf(-o));
      Buf[16 * w + 4 * g + r][16 * ct + q] = f2bf(o);
    }
  }
  __syncthreads();

  // ---- phi slice y from Buf
  short8 hfr[4];
  #pragma unroll
  for (int ks = 0; ks < 4; ++ks) {
    const ushort_t* ap = &Buf[16 * w + q][32 * ks + 4 * g];
    short4v alo = *reinterpret_cast<const short4v*>(ap);
    short4v ahi = *reinterpret_cast<const short4v*>(ap + 16);
    hfr[ks] = short8{alo[0], alo[1], alo[2], alo[3], ahi[0], ahi[1], ahi[2], ahi[3]};
  }
  #pragma unroll
  for (int ct = 0; ct < 4; ++ct) {
    f32x4 acc = {};
    #pragma unroll
    for (int ks = 0; ks < 4; ++ks) {
      short8 bf = *reinterpret_cast<const short8*>(
          w2s + ((size_t)(ks * 24 + y * 4 + ct) * 64 + l) * 8);
      acc = __builtin_amdgcn_mfma_f32_16x16x32_bf16(hfr[ks], bf, acc, 0, 0, 0);
    }
    int col = y * 64 + 16 * ct + q;
    float bb = b2[col];
    int f = col & 127, s = col >> 7;
    int tbl = f >> 5, fl = f & 31;
    #pragma unroll
    for (int r = 0; r < 4; ++r) {
      float o = acc[r] + bb;
      int row = r0 + 16 * w + 4 * g + r;
      PV[(size_t)tbl * QTUS + ((size_t)row * 32 + fl) * 6 + s] = f2bf(o);
    }
  }
}

// ---------------------------------------------------------------- sort helpers
__global__ __launch_bounds__(1024) void scan_kernel(
    const int* __restrict__ counts, int* __restrict__ offs, int* __restrict__ cursor) {
  __shared__ int part[1024];
  const int t = threadIdx.x;
  int local[8];
  int s = 0;
  #pragma unroll
  for (int i = 0; i < 8; ++i) { local[i] = counts[t * 8 + i]; s += local[i]; }
  part[t] = s;
  __syncthreads();
  for (int off = 1; off < 1024; off <<= 1) {
    int v = part[t];
    int add = (t >= off) ? part[t - off] : 0;
    __syncthreads();
    part[t] = v + add;
    __syncthreads();
  }
  int excl = part[t] - s;
  #pragma unroll
  for (int i = 0; i < 8; ++i) {
    offs[t * 8 + i] = excl;
    cursor[t * 8 + i] = excl;
    excl += local[i];
  }
  if (t == 1023) offs[NATOMS] = excl;
}

// Pre-joined 16 B edge records {j, x, y, z} in sorted (dest-atom) order.
__global__ void scatter_kernel(const int* __restrict__ nbrs, const float* __restrict__ r_ij,
                               int* __restrict__ cursor, uint4* __restrict__ erec) {
  int e = blockIdx.x * blockDim.x + threadIdx.x;
  if (e < NEDGES) {
    int2 nb = *reinterpret_cast<const int2*>(nbrs + 2 * e);
    int pos = atomicAdd(&cursor[nb.x], 1);
    const float* rp = r_ij + 3 * e;
    erec[pos] = make_uint4((uint_t)nb.y, __float_as_uint(rp[0]),
                           __float_as_uint(rp[1]), __float_as_uint(rp[2]));
  }
}

// ---------------------------------------------------------------- edge MFMA v9
// APW=4 atoms per wave (one quarter each), 2048 blocks x 4 waves. ZERO LDS:
// the 6 loop-invariant B-frags are hoisted into registers (one-time L2 reads),
// removing 6 ds_reads + lgkm waits per tile (LDS pipe left to the bpermutes).
// erec prefetch streams across atom boundaries; qtr = bid&3 keeps the
// L2-capacity-fit XCD map. C map HW-verified: row = 4g+reg = edge, col = q.
__global__ __launch_bounds__(256) void edge_mfma9(
    const uint4* __restrict__ erec, const int* __restrict__ offs,
    const ushort_t* __restrict__ PV, const ushort_t* __restrict__ wrs,
    float* __restrict__ out_s, float* __restrict__ out_v) {
  const int t = threadIdx.x;
  const int qtr = blockIdx.x & 3;
  const int w = t >> 6, l = t & 63, g = l >> 4, q = l & 15;

  // loop-invariant B-frags: [section][ct]
  short8 Bf[3][2];
  #pragma unroll
  for (int s = 0; s < 3; ++s)
    #pragma unroll
    for (int c = 0; c < 2; ++c)
      Bf[s][c] = *reinterpret_cast<const short8*>(
          wrs + ((size_t)(s * 8 + 2 * qtr + c) * 64 + l) * 8);

  const int a0 = ((blockIdx.x >> 2) * 4 + w) * APW;
  const float c1 = PI_F / CUTOFF_F;
  const char* PVb = reinterpret_cast<const char*>(PV) + (size_t)qtr * QTUS * 2;

  int eb = offs[a0];
  int end = offs[a0 + 1];
  uint4 er = make_uint4(0u, 0u, 0u, 0u);
  if (eb + q < end) er = erec[eb + q];

  for (int aidx = 0; aidx < APW; ++aidx) {
    const int end_next = (aidx + 1 < APW) ? offs[a0 + aidx + 2] : 0;
    float ds0 = 0.f, ds1 = 0.f;
    float dv[2][3] = {};

    for (;;) {
      const bool last = (eb + 16 >= end);
      const int neb = last ? end : (eb + 16);
      const int nend = last ? ((aidx + 1 < APW) ? end_next : neb) : end;
      uint4 ern = make_uint4(0u, 0u, 0u, 0u);
      if (neb + q < nend) ern = erec[neb + q];

      // ---- metadata from pre-joined record (lane q owns edge eb+q)
      float ang = 0.f, ie = 0.f, env = 0.f, u0 = 0.f, u1 = 0.f, u2 = 0.f;
      int jn = 0;
      if (eb + q < end) {
        jn = (int)er.x;
        float x = __uint_as_float(er.y), y = __uint_as_float(er.z), z = __uint_as_float(er.w);
        float d = sqrtf(x * x + y * y + z * z);
        float inv = 1.f / d;
        ang = c1 * d;
        env = (d < CUTOFF_F) ? 0.5f * (__cosf(ang) + 1.f) : 0.f;
        ie = inv * env;
        u0 = x * inv; u1 = y * inv; u2 = z * inv;
      }
      // ---- row (edge eb+4g+r) metadata broadcast + base pointers
      const char* pb[4];
      float ub[4][3];
      #pragma unroll
      for (int r = 0; r < 4; ++r) {
        int src = 4 * g + r;
        int jr = __shfl(jn, src, 64);
        ub[r][0] = __shfl(u0, src, 64);
        ub[r][1] = __shfl(u1, src, 64);
        ub[r][2] = __shfl(u2, src, 64);
        pb[r] = PVb + (size_t)jr * 384 + (size_t)q * 12;
      }
      // ---- 8 PV gathers (12 B each) up front
      U3 ld[2][4];
      #pragma unroll
      for (int c = 0; c < 2; ++c)
        #pragma unroll
        for (int r = 0; r < 4; ++r)
          ld[c][r] = *reinterpret_cast<const U3*>(pb[r] + (size_t)c * 192);
      // ---- A fragment: k = kmap(g,jj) = 4g+(jj&3)+16*(jj>>2)
      short8 af;
      #pragma unroll
      for (int jj = 0; jj < 8; ++jj) {
        int k = 4 * g + (jj & 3) + 16 * (jj >> 2);
        float v = (k < NRBF) ? ie * __sinf((float)(k + 1) * ang)
                             : (k == NRBF ? env : 0.f);
        af[jj] = (short)f2bf(v);
      }
      // ---- 2 col-tiles x 3 sections
      #pragma unroll
      for (int c = 0; c < 2; ++c) {
        f32x4 z4 = {0.f, 0.f, 0.f, 0.f};
        f32x4 cs0 = __builtin_amdgcn_mfma_f32_16x16x32_bf16(af, Bf[0][c], z4, 0, 0, 0);
        f32x4 cs1 = __builtin_amdgcn_mfma_f32_16x16x32_bf16(af, Bf[1][c], z4, 0, 0, 0);
        f32x4 cs2 = __builtin_amdgcn_mfma_f32_16x16x32_bf16(af, Bf[2][c], z4, 0, 0, 0);
        #pragma unroll
        for (int r = 0; r < 4; ++r) {
          U3 u = ld[c][r];
          float p0 = bflo(u.x), p1 = bfhi(u.x);
          float p2 = bflo(u.y), v0 = bfhi(u.y);
          float v1 = bflo(u.z), v2 = bfhi(u.z);
          float pw0 = p0 * cs0[r];
          if (c == 0) ds0 += p1 * cs1[r]; else ds1 += p1 * cs1[r];
          float pw2 = p2 * cs2[r];
          dv[c][0] += pw0 * v0 + pw2 * ub[r][0];
          dv[c][1] += pw0 * v1 + pw2 * ub[r][1];
          dv[c][2] += pw0 * v2 + pw2 * ub[r][2];
        }
      }
      er = ern;
      eb = neb;
      if (last) break;
    }

    // ---- reduce the 4 g-copies and write atom a0+aidx
    float r0v = ds0, r1v = ds1;
    r0v += __shfl_xor(r0v, 16, 64); r0v += __shfl_xor(r0v, 32, 64);
    r1v += __shfl_xor(r1v, 16, 64); r1v += __shfl_xor(r1v, 32, 64);
    float dvr[2][3];
    #pragma unroll
    for (int c = 0; c < 2; ++c)
      #pragma unroll
      for (int cc = 0; cc < 3; ++cc) {
        float y = dv[c][cc];
        y += __shfl_xor(y, 16, 64); y += __shfl_xor(y, 32, 64);
        dvr[c][cc] = y;
      }
    if (g < 2) {
      int atom = a0 + aidx;
      float sv = (g == 0) ? r0v : r1v;
      float d0 = (g == 0) ? dvr[0][0] : dvr[1][0];
      float d1 = (g == 0) ? dvr[0][1] : dvr[1][1];
      float d2 = (g == 0) ? dvr[0][2] : dvr[1][2];
      int f = 32 * qtr + 16 * g + q;
      out_s[(size_t)atom * FEAT + f] = sv;
      float* ov = out_v + (size_t)atom * 384 + (size_t)f * 3;
      ov[0] = d0; ov[1] = d1; ov[2] = d2;
    }
    end = end_next;
  }
}

// ---------------------------------------------------------------- attention
__device__ __forceinline__ float wave_max64(float v) {
  #pragma unroll
  for (int m = 32; m > 0; m >>= 1) v = fmaxf(v, __shfl_xor(v, m, 64));
  return v;
}
__device__ __forceinline__ float wave_sum64(float v) {
  #pragma unroll
  for (int m = 32; m > 0; m >>= 1) v += __shfl_xor(v, m, 64);
  return v;
}

// 4 blocks per graph (quad = bid&3); each wave handles one group of 4 queries.
__global__ __launch_bounds__(256) void attn_kernel(const float* __restrict__ Qf,
                                                   const ushort_t* __restrict__ kvbf,
                                                   float* __restrict__ out_s) {
  __shared__ float4 Ks4[64 * 32];
  __shared__ float  Vs[64][130];
  __shared__ float  Ps[4][4][64];
  const int b = blockIdx.x >> 2, quad = blockIdx.x & 3;
  const int t = threadIdx.x;
  const float* qbase = Qf + (size_t)b * APG * 128;
  const ushort_t* kvb = kvbf + (size_t)b * APG * 256;

  for (int i = t; i < 64 * 32; i += 256) {
    int a = i >> 5, gg = i & 31;
    ushort4 k4 = *reinterpret_cast<const ushort4*>(kvb + a * 256 + 4 * gg);
    float4 kf = {bfus(k4.x), bfus(k4.y), bfus(k4.z), bfus(k4.w)};
    Ks4[a * 32 + (gg ^ (a & 7))] = kf;
  }
  for (int i = t; i < 64 * 32; i += 256) {
    int a = i >> 5, gg = i & 31;
    ushort4 v4 = *reinterpret_cast<const ushort4*>(kvb + a * 256 + 128 + 4 * gg);
    Vs[a][4 * gg + 0] = bfus(v4.x); Vs[a][4 * gg + 1] = bfus(v4.y);
    Vs[a][4 * gg + 2] = bfus(v4.z); Vs[a][4 * gg + 3] = bfus(v4.w);
  }
  __syncthreads();

  const int w = t >> 6, l = t & 63;
  const int qq = 4 * quad + w;
  const float scale = 0.08838834764831845f;

  const float* q0p = qbase + (size_t)(4 * qq + 0) * 128;
  const float* q1p = qbase + (size_t)(4 * qq + 1) * 128;
  const float* q2p = qbase + (size_t)(4 * qq + 2) * 128;
  const float* q3p = qbase + (size_t)(4 * qq + 3) * 128;
  float s0 = 0.f, s1 = 0.f, s2 = 0.f, s3 = 0.f;
  #pragma unroll 8
  for (int i = 0; i < 32; ++i) {
    float4 k = Ks4[l * 32 + (i ^ (l & 7))];
    float4 q0 = *reinterpret_cast<const float4*>(q0p + 4 * i);
    float4 q1 = *reinterpret_cast<const float4*>(q1p + 4 * i);
    float4 q2 = *reinterpret_cast<const float4*>(q2p + 4 * i);
    float4 q3 = *reinterpret_cast<const float4*>(q3p + 4 * i);
    s0 += q0.x * k.x + q0.y * k.y + q0.z * k.z + q0.w * k.w;
    s1 += q1.x * k.x + q1.y * k.y + q1.z * k.z + q1.w * k.w;
    s2 += q2.x * k.x + q2.y * k.y + q2.z * k.z + q2.w * k.w;
    s3 += q3.x * k.x + q3.y * k.y + q3.z * k.z + q3.w * k.w;
  }
  s0 *= scale; s1 *= scale; s2 *= scale; s3 *= scale;

  float p0 = __expf(s0 - wave_max64(s0));
  float p1 = __expf(s1 - wave_max64(s1));
  float p2 = __expf(s2 - wave_max64(s2));
  float p3 = __expf(s3 - wave_max64(s3));
  p0 /= wave_sum64(p0); p1 /= wave_sum64(p1);
  p2 /= wave_sum64(p2); p3 /= wave_sum64(p3);

  Ps[w][0][l] = p0; Ps[w][1][l] = p1; Ps[w][2][l] = p2; Ps[w][3][l] = p3;
  __threadfence_block();

  float a00 = 0.f, a01 = 0.f, a10 = 0.f, a11 = 0.f;
  float a20 = 0.f, a21 = 0.f, a30 = 0.f, a31 = 0.f;
  for (int a = 0; a < 64; ++a) {
    float2 v = *reinterpret_cast<const float2*>(&Vs[a][2 * l]);
    float pa0 = Ps[w][0][a], pa1 = Ps[w][1][a];
    float pa2 = Ps[w][2][a], pa3 = Ps[w][3][a];
    a00 += pa0 * v.x; a01 += pa0 * v.y;
    a10 += pa1 * v.x; a11 += pa1 * v.y;
    a20 += pa2 * v.x; a21 += pa2 * v.y;
    a30 += pa3 * v.x; a31 += pa3 * v.y;
  }
  size_t row0 = (size_t)(b * APG + 4 * qq) * FEAT + 2 * l;
  float2* o0 = reinterpret_cast<float2*>(out_s + row0);
  float2* o1 = reinterpret_cast<float2*>(out_s + row0 + FEAT);
  float2* o2 = reinterpret_cast<float2*>(out_s + row0 + 2 * FEAT);
  float2* o3 = reinterpret_cast<float2*>(out_s + row0 + 3 * FEAT);
  float2 c0 = *o0; c0.x += a00; c0.y += a01; *o0 = c0;
  float2 c1 = *o1; c1.x += a10; c1.y += a11; *o1 = c1;
  float2 c2 = *o2; c2.x += a20; c2.y += a21; *o2 = c2;
  float2 c3 = *o3; c3.x += a30; c3.y += a31; *o3 = c3;
}

// ---------------------------------------------------------------- launch
extern "C" void kernel_launch(void* const* d_in, const int* in_sizes, int n_in,
                              void* d_out, int out_size, void* d_ws, size_t ws_size,
                              hipStream_t stream) {
  const float* s_j  = (const float*)d_in[0];
  const float* v_j  = (const float*)d_in[1];
  const float* r_ij = (const float*)d_in[2];
  const int*   nbrs = (const int*)d_in[3];
  const float* W1   = (const float*)d_in[5];
  const float* b1   = (const float*)d_in[6];
  const float* W2   = (const float*)d_in[7];
  const float* b2   = (const float*)d_in[8];
  const float* Wr   = (const float*)d_in[9];
  const float* br   = (const float*)d_in[10];
  const float* Wd   = (const float*)d_in[11];
  const float* bd   = (const float*)d_in[12];

  float* out_s = (float*)d_out;
  float* out_v = out_s + (size_t)NATOMS * FEAT;

  // workspace ~25 MB (<= 26.4 proven).
  float*    Qf   = (float*)d_ws;                         // 4 MB
  ushort_t* kvbf = (ushort_t*)(Qf + NATOMS * FEAT);      // 4 MB
  ushort_t* PV   = kvbf + (size_t)NATOMS * 256;          // 4 x 3.15 MB quarter tables
  ushort_t* w1s  = PV + 4 * QTUS;                        // 16384
  ushort_t* w2s  = w1s + 16384;                          // 49152
  ushort_t* wds  = w2s + 49152;                          // 49152
  ushort_t* wrs  = wds + 49152;                          // 12288
  uint4*    erec = (uint4*)(wrs + 12288);                // 4 MB
  int* offs   = (int*)(erec + NEDGES);                   // NATOMS+1
  int* cursor = offs + (NATOMS + 1);
  int* counts = cursor + NATOMS;

  hipMemsetAsync(counts, 0, NATOMS * sizeof(int), stream);

  int prep_total = NATOMS * FEAT + 16384 + 49152 + 49152 + 12288 + NEDGES;
  prep_kernel<<<(prep_total + 255) / 256, 256, 0, stream>>>(
      v_j, W1, W2, Wd, Wr, br, nbrs, PV, w1s, w2s, wds, wrs, counts);

  scan_kernel<<<1, 1024, 0, stream>>>(counts, offs, cursor);
  scatter_kernel<<<NEDGES / 256, 256, 0, stream>>>(nbrs, r_ij, cursor, erec);

  gemm_big<<<dim3(NATOMS / 64, 6), 256, 0, stream>>>(
      s_j, w1s, b1, w2s, b2, wds, bd, PV, Qf, kvbf);

  edge_mfma9<<<NATOMS / APW, 256, 0, stream>>>(erec, offs, PV, wrs, out_s, out_v);
  attn_kernel<<<NGRAPH * 4, 256, 0, stream>>>(Qf, kvbf, out_s);
}